// Round 1
// baseline (194.106 us; speedup 1.0000x reference)
//
#include <hip/hip_runtime.h>
#include <cstdint>
#include <cstddef>

namespace {

constexpr int BATCH = 4;
constexpr int LQ = 2048;
constexpr int LK = 2048;
constexpr int D = 512;
constexpr int MQ = BATCH * LQ;  // 8192 rows for the stacked transforms

using f16 = _Float16;
typedef _Float16 f16x8 __attribute__((ext_vector_type(8)));
typedef float f32x4 __attribute__((ext_vector_type(4)));

__device__ inline f16x8 cvt8(const float4 a, const float4 b) {
  f16x8 h;
  h[0] = (f16)a.x; h[1] = (f16)a.y; h[2] = (f16)a.z; h[3] = (f16)a.w;
  h[4] = (f16)b.x; h[5] = (f16)b.y; h[6] = (f16)b.z; h[7] = (f16)b.w;
  return h;
}

// ---------------------------------------------------------------------------
// Kernel 1: out = tanh(X @ W^T + b), X:[8192,512] f32, W:[512,512] f32,
// out fp16. 128x128 tile, 4 waves (2x2), 4x4 16x16x32 MFMA frags per wave.
// B^T pattern: both A and W are row-major along the contraction dim.
// ---------------------------------------------------------------------------
__global__ __launch_bounds__(256) void transform_kernel(
    const float* __restrict__ X, const float* __restrict__ W,
    const float* __restrict__ bias, f16* __restrict__ out) {
  const int bid = blockIdx.x;
  const int tm = bid & 63;   // 8192/128
  const int tn = bid >> 6;   // 512/128
  const int brow = tm * 128, bcol = tn * 128;
  const int t = threadIdx.x;
  const int lane = t & 63;
  const int wid = t >> 6;
  const int wr = (wid >> 1) * 64, wc = (wid & 1) * 64;
  const int lr = lane & 15;
  const int lk = (lane >> 4) << 3;  // A/B frag k-offset
  const int l4 = (lane >> 4) << 2;  // C/D row group

  __shared__ f16 As[128][40];
  __shared__ f16 Bs[128][40];

  f32x4 acc[4][4] = {};

  for (int k0 = 0; k0 < D; k0 += 32) {
#pragma unroll
    for (int i = 0; i < 2; ++i) {
      const int u = t + i * 256;      // 512 units of 8 elems
      const int r = u >> 2;
      const int c8 = (u & 3) << 3;
      const float4* pa =
          reinterpret_cast<const float4*>(X + (size_t)(brow + r) * D + k0 + c8);
      *reinterpret_cast<f16x8*>(&As[r][c8]) = cvt8(pa[0], pa[1]);
      const float4* pb =
          reinterpret_cast<const float4*>(W + (size_t)(bcol + r) * D + k0 + c8);
      *reinterpret_cast<f16x8*>(&Bs[r][c8]) = cvt8(pb[0], pb[1]);
    }
    __syncthreads();
    f16x8 af[4], bf[4];
#pragma unroll
    for (int m = 0; m < 4; ++m)
      af[m] = *reinterpret_cast<const f16x8*>(&As[wr + m * 16 + lr][lk]);
#pragma unroll
    for (int n = 0; n < 4; ++n)
      bf[n] = *reinterpret_cast<const f16x8*>(&Bs[wc + n * 16 + lr][lk]);
#pragma unroll
    for (int m = 0; m < 4; ++m)
#pragma unroll
      for (int n = 0; n < 4; ++n)
        acc[m][n] =
            __builtin_amdgcn_mfma_f32_16x16x32_f16(af[m], bf[n], acc[m][n], 0, 0, 0);
    __syncthreads();
  }

#pragma unroll
  for (int n = 0; n < 4; ++n) {
    const int col = bcol + wc + n * 16 + lr;
    const float bv = bias[col];
#pragma unroll
    for (int m = 0; m < 4; ++m)
#pragma unroll
      for (int r = 0; r < 4; ++r) {
        const int row = brow + wr + m * 16 + l4 + r;
        out[(size_t)row * D + col] = (f16)tanhf(acc[m][n][r] + bv);
      }
  }
}

// ---------------------------------------------------------------------------
// Row sum-of-squares of fp16 rows of length 512 (one wave per row).
// ---------------------------------------------------------------------------
__global__ __launch_bounds__(256) void rownorm_kernel(const f16* __restrict__ x,
                                                      float* __restrict__ nsq) {
  const int row = blockIdx.x * 4 + (threadIdx.x >> 6);
  const int lane = threadIdx.x & 63;
  f16x8 h = *reinterpret_cast<const f16x8*>(x + (size_t)row * D + lane * 8);
  float s = 0.f;
#pragma unroll
  for (int j = 0; j < 8; ++j) {
    float v = (float)h[j];
    s += v * v;
  }
#pragma unroll
  for (int off = 32; off; off >>= 1) s += __shfl_xor(s, off);
  if (lane == 0) nsq[row] = s;
}

// ---------------------------------------------------------------------------
// value [B,LK,D] f32 -> vt [B,D,LK] fp16 (so PV GEMM is B^T-pattern).
// ---------------------------------------------------------------------------
__global__ __launch_bounds__(256) void transpose_v_kernel(
    const float* __restrict__ v, f16* __restrict__ vt) {
  const int bid = blockIdx.x;
  const int kt = bid & 31;         // LK/64
  const int dt = (bid >> 5) & 7;   // D/64
  const int b = bid >> 8;
  const int k0 = kt * 64, d0 = dt * 64;
  const int t = threadIdx.x;
  __shared__ f16 T[64][72];
#pragma unroll
  for (int i = 0; i < 4; ++i) {
    const int u = t + i * 256;  // 1024 units of 4 f32
    const int k = u >> 4;
    const int d4 = (u & 15) << 2;
    float4 x = *reinterpret_cast<const float4*>(
        v + (size_t)(b * LK + k0 + k) * D + d0 + d4);
    T[d4 + 0][k] = (f16)x.x;
    T[d4 + 1][k] = (f16)x.y;
    T[d4 + 2][k] = (f16)x.z;
    T[d4 + 3][k] = (f16)x.w;
  }
  __syncthreads();
#pragma unroll
  for (int i = 0; i < 2; ++i) {
    const int u = t + i * 256;  // 512 units of 8 f16
    const int d = u >> 3;
    const int k8 = (u & 7) << 3;
    f16x8 h = *reinterpret_cast<const f16x8*>(&T[d][k8]);
    *reinterpret_cast<f16x8*>(vt + (size_t)(b * D + d0 + d) * LK + k0 + k8) = h;
  }
}

// ---------------------------------------------------------------------------
// Scores: s = w0*dot + w1*cos + w2*(-sqrt(max(qn^2+kn^2-2dot,0)))
// dot = qh[b] @ kh[b]^T (fp16 MFMA).  Writes raw scores f32 into attn region.
// ---------------------------------------------------------------------------
__global__ __launch_bounds__(256) void scores_kernel(
    const f16* __restrict__ qh, const f16* __restrict__ kh,
    const float* __restrict__ qnsq, const float* __restrict__ knsq,
    const float* __restrict__ sw, float* __restrict__ attn) {
  const int bid = blockIdx.x;
  const int tm = bid & 15;
  const int tn = (bid >> 4) & 15;
  const int b = bid >> 8;
  const int brow = tm * 128, bcol = tn * 128;
  const int t = threadIdx.x;
  const int lane = t & 63;
  const int wid = t >> 6;
  const int wr = (wid >> 1) * 64, wc = (wid & 1) * 64;
  const int lr = lane & 15;
  const int lk = (lane >> 4) << 3;
  const int l4 = (lane >> 4) << 2;

  __shared__ f16 As[128][40];
  __shared__ f16 Bs[128][40];

  f32x4 acc[4][4] = {};

  for (int k0 = 0; k0 < D; k0 += 32) {
#pragma unroll
    for (int i = 0; i < 2; ++i) {
      const int u = t + i * 256;
      const int r = u >> 2;
      const int c8 = (u & 3) << 3;
      *reinterpret_cast<f16x8*>(&As[r][c8]) = *reinterpret_cast<const f16x8*>(
          qh + (size_t)(b * LQ + brow + r) * D + k0 + c8);
      *reinterpret_cast<f16x8*>(&Bs[r][c8]) = *reinterpret_cast<const f16x8*>(
          kh + (size_t)(b * LK + bcol + r) * D + k0 + c8);
    }
    __syncthreads();
    f16x8 af[4], bf[4];
#pragma unroll
    for (int m = 0; m < 4; ++m)
      af[m] = *reinterpret_cast<const f16x8*>(&As[wr + m * 16 + lr][lk]);
#pragma unroll
    for (int n = 0; n < 4; ++n)
      bf[n] = *reinterpret_cast<const f16x8*>(&Bs[wc + n * 16 + lr][lk]);
#pragma unroll
    for (int m = 0; m < 4; ++m)
#pragma unroll
      for (int n = 0; n < 4; ++n)
        acc[m][n] =
            __builtin_amdgcn_mfma_f32_16x16x32_f16(af[m], bf[n], acc[m][n], 0, 0, 0);
    __syncthreads();
  }

  // softmax of the 3 scoring weights (uniform scalars)
  const float s0 = sw[0], s1 = sw[1], s2 = sw[2];
  const float smx = fmaxf(s0, fmaxf(s1, s2));
  float w0 = __expf(s0 - smx), w1 = __expf(s1 - smx), w2 = __expf(s2 - smx);
  const float winv = 1.f / (w0 + w1 + w2);
  w0 *= winv; w1 *= winv; w2 *= winv;

  float qn_[4][4];
#pragma unroll
  for (int m = 0; m < 4; ++m)
#pragma unroll
    for (int r = 0; r < 4; ++r)
      qn_[m][r] = sqrtf(qnsq[b * LQ + brow + wr + m * 16 + l4 + r]);
  float kn_[4];
#pragma unroll
  for (int n = 0; n < 4; ++n)
    kn_[n] = sqrtf(knsq[b * LK + bcol + wc + n * 16 + lr]);

#pragma unroll
  for (int m = 0; m < 4; ++m)
#pragma unroll
    for (int n = 0; n < 4; ++n)
#pragma unroll
      for (int r = 0; r < 4; ++r) {
        const int row = brow + wr + m * 16 + l4 + r;
        const int col = bcol + wc + n * 16 + lr;
        const float dot = acc[m][n][r];
        const float qn = qn_[m][r], kn = kn_[n];
        const float cosv = dot / fmaxf(qn * kn, 1e-8f);
        const float sq = fmaxf(qn * qn + kn * kn - 2.f * dot, 0.f);
        const float s = w0 * dot + w1 * cosv - w2 * sqrtf(sq);
        attn[(size_t)(b * LQ + row) * LK + col] = s;
      }
}

// ---------------------------------------------------------------------------
// In-place row softmax over [8192, 2048] f32. One block per row.
// ---------------------------------------------------------------------------
__global__ __launch_bounds__(256) void softmax_kernel(float* __restrict__ attn) {
  float* row = attn + (size_t)blockIdx.x * LK;
  const int t = threadIdx.x;
  float4 v0 = *reinterpret_cast<const float4*>(row + t * 4);
  float4 v1 = *reinterpret_cast<const float4*>(row + 1024 + t * 4);
  float m = fmaxf(fmaxf(fmaxf(v0.x, v0.y), fmaxf(v0.z, v0.w)),
                  fmaxf(fmaxf(v1.x, v1.y), fmaxf(v1.z, v1.w)));
#pragma unroll
  for (int off = 32; off; off >>= 1) m = fmaxf(m, __shfl_xor(m, off));
  __shared__ float red[4];
  const int wid = t >> 6;
  if ((t & 63) == 0) red[wid] = m;
  __syncthreads();
  m = fmaxf(fmaxf(red[0], red[1]), fmaxf(red[2], red[3]));
  __syncthreads();
  float e[8];
  e[0] = __expf(v0.x - m); e[1] = __expf(v0.y - m);
  e[2] = __expf(v0.z - m); e[3] = __expf(v0.w - m);
  e[4] = __expf(v1.x - m); e[5] = __expf(v1.y - m);
  e[6] = __expf(v1.z - m); e[7] = __expf(v1.w - m);
  float s = ((e[0] + e[1]) + (e[2] + e[3])) + ((e[4] + e[5]) + (e[6] + e[7]));
#pragma unroll
  for (int off = 32; off; off >>= 1) s += __shfl_xor(s, off);
  if ((t & 63) == 0) red[wid] = s;
  __syncthreads();
  s = (red[0] + red[1]) + (red[2] + red[3]);
  const float inv = 1.f / s;
  v0.x = e[0] * inv; v0.y = e[1] * inv; v0.z = e[2] * inv; v0.w = e[3] * inv;
  v1.x = e[4] * inv; v1.y = e[5] * inv; v1.z = e[6] * inv; v1.w = e[7] * inv;
  *reinterpret_cast<float4*>(row + t * 4) = v0;
  *reinterpret_cast<float4*>(row + 1024 + t * 4) = v1;
}

// ---------------------------------------------------------------------------
// context = attn @ value:  A = attn f32 (converted in staging), B = vt fp16
// (value pre-transposed -> B^T pattern). 128x128 tile, K = 2048.
// ---------------------------------------------------------------------------
__global__ __launch_bounds__(256) void pv_kernel(const float* __restrict__ attn,
                                                 const f16* __restrict__ vt,
                                                 float* __restrict__ ctx) {
  const int bid = blockIdx.x;
  const int tm = bid & 15;        // 2048/128
  const int tn = (bid >> 4) & 3;  // 512/128
  const int b = bid >> 6;
  const int brow = tm * 128, bcol = tn * 128;
  const int t = threadIdx.x;
  const int lane = t & 63;
  const int wid = t >> 6;
  const int wr = (wid >> 1) * 64, wc = (wid & 1) * 64;
  const int lr = lane & 15;
  const int lk = (lane >> 4) << 3;
  const int l4 = (lane >> 4) << 2;

  __shared__ f16 As[128][40];
  __shared__ f16 Bs[128][40];

  f32x4 acc[4][4] = {};

  for (int k0 = 0; k0 < LK; k0 += 32) {
#pragma unroll
    for (int i = 0; i < 2; ++i) {
      const int u = t + i * 256;
      const int r = u >> 2;
      const int c8 = (u & 3) << 3;
      const float4* pa = reinterpret_cast<const float4*>(
          attn + (size_t)(b * LQ + brow + r) * LK + k0 + c8);
      *reinterpret_cast<f16x8*>(&As[r][c8]) = cvt8(pa[0], pa[1]);
      *reinterpret_cast<f16x8*>(&Bs[r][c8]) = *reinterpret_cast<const f16x8*>(
          vt + (size_t)(b * D + bcol + r) * LK + k0 + c8);
    }
    __syncthreads();
    f16x8 af[4], bf[4];
#pragma unroll
    for (int m = 0; m < 4; ++m)
      af[m] = *reinterpret_cast<const f16x8*>(&As[wr + m * 16 + lr][lk]);
#pragma unroll
    for (int n = 0; n < 4; ++n)
      bf[n] = *reinterpret_cast<const f16x8*>(&Bs[wc + n * 16 + lr][lk]);
#pragma unroll
    for (int m = 0; m < 4; ++m)
#pragma unroll
      for (int n = 0; n < 4; ++n)
        acc[m][n] =
            __builtin_amdgcn_mfma_f32_16x16x32_f16(af[m], bf[n], acc[m][n], 0, 0, 0);
    __syncthreads();
  }

#pragma unroll
  for (int m = 0; m < 4; ++m)
#pragma unroll
    for (int n = 0; n < 4; ++n)
#pragma unroll
      for (int r = 0; r < 4; ++r) {
        const int row = brow + wr + m * 16 + l4 + r;
        const int col = bcol + wc + n * 16 + lr;
        ctx[(size_t)(b * LQ + row) * D + col] = acc[m][n][r];
      }
}

}  // namespace

extern "C" void kernel_launch(void* const* d_in, const int* in_sizes, int n_in,
                              void* d_out, int out_size, void* d_ws,
                              size_t ws_size, hipStream_t stream) {
  const float* query = (const float*)d_in[0];
  const float* key = (const float*)d_in[1];
  const float* value = (const float*)d_in[2];
  const float* Wq = (const float*)d_in[3];
  const float* bq = (const float*)d_in[4];
  const float* Wk = (const float*)d_in[5];
  const float* bk = (const float*)d_in[6];
  const float* sw = (const float*)d_in[7];

  float* ctx = (float*)d_out;                          // [B,LQ,D]
  float* attn = (float*)d_out + (size_t)BATCH * LQ * D;  // [B,LQ,LK]

  char* ws = (char*)d_ws;
  f16* qh = (f16*)ws;                           // 8 MiB
  f16* kh = (f16*)(ws + (size_t)(8u << 20));    // 8 MiB
  f16* vt = (f16*)(ws + (size_t)(16u << 20));   // 8 MiB
  float* qnsq = (float*)(ws + (size_t)(24u << 20));  // 32 KiB
  float* knsq = qnsq + MQ;                           // 32 KiB

  transform_kernel<<<256, 256, 0, stream>>>(query, Wq, bq, qh);
  transform_kernel<<<256, 256, 0, stream>>>(key, Wk, bk, kh);
  rownorm_kernel<<<MQ / 4, 256, 0, stream>>>(qh, qnsq);
  rownorm_kernel<<<MQ / 4, 256, 0, stream>>>(kh, knsq);
  transpose_v_kernel<<<1024, 256, 0, stream>>>(value, vt);
  scores_kernel<<<1024, 256, 0, stream>>>(qh, kh, qnsq, knsq, sw, attn);
  softmax_kernel<<<BATCH * LQ, 256, 0, stream>>>(attn);
  pv_kernel<<<256, 256, 0, stream>>>(attn, vt, ctx);
}

// Round 2
// 183.302 us; speedup vs baseline: 1.0589x; 1.0589x over previous
//
#include <hip/hip_runtime.h>
#include <cstdint>
#include <cstddef>

namespace {

constexpr int BATCH = 4;
constexpr int LQ = 2048;
constexpr int LK = 2048;
constexpr int D = 512;
constexpr int MQ = BATCH * LQ;

using f16 = _Float16;
typedef _Float16 f16x8 __attribute__((ext_vector_type(8)));
typedef float f32x4 __attribute__((ext_vector_type(4)));

__device__ __forceinline__ f16x8 cvt8(const float4 a, const float4 b) {
  f16x8 h;
  h[0] = (f16)a.x; h[1] = (f16)a.y; h[2] = (f16)a.z; h[3] = (f16)a.w;
  h[4] = (f16)b.x; h[5] = (f16)b.y; h[6] = (f16)b.z; h[7] = (f16)b.w;
  return h;
}

typedef __attribute__((address_space(1))) const void gas_void;
typedef __attribute__((address_space(3))) void las_void;
__device__ __forceinline__ void gload_lds16(const void* g, void* l) {
  __builtin_amdgcn_global_load_lds((gas_void*)g, (las_void*)l, 16, 0, 0);
}

// ---------------------------------------------------------------------------
// transform: out = tanh(X @ W^T + b), fp16 out. (unchanged from R1; ~12us ea)
// ---------------------------------------------------------------------------
__global__ __launch_bounds__(256) void transform_kernel(
    const float* __restrict__ X, const float* __restrict__ W,
    const float* __restrict__ bias, f16* __restrict__ out) {
  const int bid = blockIdx.x;
  const int tm = bid & 63;
  const int tn = bid >> 6;
  const int brow = tm * 128, bcol = tn * 128;
  const int t = threadIdx.x;
  const int lane = t & 63;
  const int wid = t >> 6;
  const int wr = (wid >> 1) * 64, wc = (wid & 1) * 64;
  const int lr = lane & 15;
  const int lk = (lane >> 4) << 3;
  const int l4 = (lane >> 4) << 2;

  __shared__ f16 As[128][40];
  __shared__ f16 Bs[128][40];

  f32x4 acc[4][4] = {};

  for (int k0 = 0; k0 < D; k0 += 32) {
#pragma unroll
    for (int i = 0; i < 2; ++i) {
      const int u = t + i * 256;
      const int r = u >> 2;
      const int c8 = (u & 3) << 3;
      const float4* pa =
          reinterpret_cast<const float4*>(X + (size_t)(brow + r) * D + k0 + c8);
      *reinterpret_cast<f16x8*>(&As[r][c8]) = cvt8(pa[0], pa[1]);
      const float4* pb =
          reinterpret_cast<const float4*>(W + (size_t)(bcol + r) * D + k0 + c8);
      *reinterpret_cast<f16x8*>(&Bs[r][c8]) = cvt8(pb[0], pb[1]);
    }
    __syncthreads();
    f16x8 af[4], bf[4];
#pragma unroll
    for (int m = 0; m < 4; ++m)
      af[m] = *reinterpret_cast<const f16x8*>(&As[wr + m * 16 + lr][lk]);
#pragma unroll
    for (int n = 0; n < 4; ++n)
      bf[n] = *reinterpret_cast<const f16x8*>(&Bs[wc + n * 16 + lr][lk]);
#pragma unroll
    for (int m = 0; m < 4; ++m)
#pragma unroll
      for (int n = 0; n < 4; ++n)
        acc[m][n] =
            __builtin_amdgcn_mfma_f32_16x16x32_f16(af[m], bf[n], acc[m][n], 0, 0, 0);
    __syncthreads();
  }

#pragma unroll
  for (int n = 0; n < 4; ++n) {
    const int col = bcol + wc + n * 16 + lr;
    const float bv = bias[col];
#pragma unroll
    for (int m = 0; m < 4; ++m)
#pragma unroll
      for (int r = 0; r < 4; ++r) {
        const int row = brow + wr + m * 16 + l4 + r;
        out[(size_t)row * D + col] = (f16)tanhf(acc[m][n][r] + bv);
      }
  }
}

__global__ __launch_bounds__(256) void rownorm_kernel(const f16* __restrict__ x,
                                                      float* __restrict__ nsq) {
  const int row = blockIdx.x * 4 + (threadIdx.x >> 6);
  const int lane = threadIdx.x & 63;
  f16x8 h = *reinterpret_cast<const f16x8*>(x + (size_t)row * D + lane * 8);
  float s = 0.f;
#pragma unroll
  for (int j = 0; j < 8; ++j) {
    float v = (float)h[j];
    s += v * v;
  }
#pragma unroll
  for (int off = 32; off; off >>= 1) s += __shfl_xor(s, off);
  if (lane == 0) nsq[row] = s;
}

__global__ __launch_bounds__(256) void transpose_v_kernel(
    const float* __restrict__ v, f16* __restrict__ vt) {
  const int bid = blockIdx.x;
  const int kt = bid & 31;
  const int dt = (bid >> 5) & 7;
  const int b = bid >> 8;
  const int k0 = kt * 64, d0 = dt * 64;
  const int t = threadIdx.x;
  __shared__ f16 T[64][72];
#pragma unroll
  for (int i = 0; i < 4; ++i) {
    const int u = t + i * 256;
    const int k = u >> 4;
    const int d4 = (u & 15) << 2;
    float4 x = *reinterpret_cast<const float4*>(
        v + (size_t)(b * LK + k0 + k) * D + d0 + d4);
    T[d4 + 0][k] = (f16)x.x;
    T[d4 + 1][k] = (f16)x.y;
    T[d4 + 2][k] = (f16)x.z;
    T[d4 + 3][k] = (f16)x.w;
  }
  __syncthreads();
#pragma unroll
  for (int i = 0; i < 2; ++i) {
    const int u = t + i * 256;
    const int d = u >> 3;
    const int k8 = (u & 7) << 3;
    f16x8 h = *reinterpret_cast<const f16x8*>(&T[d][k8]);
    *reinterpret_cast<f16x8*>(vt + (size_t)(b * D + d0 + d) * LK + k0 + k8) = h;
  }
}

// ---------------------------------------------------------------------------
// scores: s = w0*dot + w1*cos - w2*sqrt(max(qn^2+kn^2-2dot,0)) (raw, f32)
// + fused per-(row,tile) softmax stats (max, expsum) -> tstats.
// 128x128 tile, BK=64, global_load_lds + XOR swizzle staging.
// ---------------------------------------------------------------------------
__global__ __launch_bounds__(256, 2) void scores_kernel(
    const f16* __restrict__ qh, const f16* __restrict__ kh,
    const float* __restrict__ qnsq, const float* __restrict__ knsq,
    const float* __restrict__ sw, float* __restrict__ attn,
    float2* __restrict__ tstats) {
  const int bid = blockIdx.x;
  const int tn = bid & 15;
  const int tm = (bid >> 4) & 15;
  const int b = bid >> 8;
  const int brow = tm * 128, bcol = tn * 128;
  const int t = threadIdx.x;
  const int lane = t & 63;
  const int wid = t >> 6;
  const int wr = (wid >> 1) * 64, wc = (wid & 1) * 64;
  const int lr = lane & 15;
  const int lk = (lane >> 4) << 3;
  const int g4 = (lane >> 4) << 2;

  __shared__ f16 As[128 * 64];
  __shared__ f16 Bs[128 * 64];
  __shared__ float s_m[128][2];
  __shared__ float s_l[128][2];

  f32x4 acc[4][4] = {};

  const int srow = lane >> 3;                   // row within 8-row chunk
  const int scol = ((lane & 7) ^ srow) << 4;    // pre-swizzled source col bytes
  const char* aBase = (const char*)(qh + (size_t)(b * LQ + brow) * D);
  const char* bBase = (const char*)(kh + (size_t)(b * LK + bcol) * D);
  const int swz = (lr & 7) << 4;

  for (int k0 = 0; k0 < D; k0 += 64) {
#pragma unroll
    for (int i = 0; i < 4; ++i) {
      const int chunk = wid * 4 + i;
      const int row = chunk * 8 + srow;
      gload_lds16(aBase + (size_t)row * (D * 2) + k0 * 2 + scol,
                  (char*)As + chunk * 1024);
      gload_lds16(bBase + (size_t)row * (D * 2) + k0 * 2 + scol,
                  (char*)Bs + chunk * 1024);
    }
    __syncthreads();
    f16x8 af[2][4], bf[2][4];
#pragma unroll
    for (int h = 0; h < 2; ++h) {
      const int cb = h * 64 + lk * 2;
#pragma unroll
      for (int m = 0; m < 4; ++m)
        af[h][m] = *(const f16x8*)((const char*)As + (wr + m * 16 + lr) * 128 +
                                   (cb ^ swz));
#pragma unroll
      for (int n = 0; n < 4; ++n)
        bf[h][n] = *(const f16x8*)((const char*)Bs + (wc + n * 16 + lr) * 128 +
                                   (cb ^ swz));
    }
#pragma unroll
    for (int h = 0; h < 2; ++h)
#pragma unroll
      for (int m = 0; m < 4; ++m)
#pragma unroll
        for (int n = 0; n < 4; ++n)
          acc[m][n] = __builtin_amdgcn_mfma_f32_16x16x32_f16(af[h][m], bf[h][n],
                                                             acc[m][n], 0, 0, 0);
    __syncthreads();
  }

  const float s0 = sw[0], s1 = sw[1], s2 = sw[2];
  const float smx = fmaxf(s0, fmaxf(s1, s2));
  float w0 = __expf(s0 - smx), w1 = __expf(s1 - smx), w2 = __expf(s2 - smx);
  const float winv = 1.f / (w0 + w1 + w2);
  w0 *= winv; w1 *= winv; w2 *= winv;

  float qn_[4][4];
#pragma unroll
  for (int m = 0; m < 4; ++m)
#pragma unroll
    for (int r = 0; r < 4; ++r)
      qn_[m][r] = sqrtf(qnsq[b * LQ + brow + wr + m * 16 + g4 + r]);
  float kn_[4];
#pragma unroll
  for (int n = 0; n < 4; ++n)
    kn_[n] = sqrtf(knsq[b * LK + bcol + wc + n * 16 + lr]);

  // compute final scores in-place in acc, write to attn
#pragma unroll
  for (int m = 0; m < 4; ++m)
#pragma unroll
    for (int n = 0; n < 4; ++n)
#pragma unroll
      for (int r = 0; r < 4; ++r) {
        const float dot = acc[m][n][r];
        const float qn = qn_[m][r], kn = kn_[n];
        const float cosv = dot / fmaxf(qn * kn, 1e-8f);
        const float sq = fmaxf(qn * qn + kn * kn - 2.f * dot, 0.f);
        const float s = w0 * dot + w1 * cosv - w2 * sqrtf(sq);
        acc[m][n][r] = s;
        const int row = brow + wr + m * 16 + g4 + r;
        const int col = bcol + wc + n * 16 + lr;
        attn[(size_t)(b * LQ + row) * LK + col] = s;
      }

  // per-row (max, expsum) over this tile's 128 cols
#pragma unroll
  for (int m = 0; m < 4; ++m)
#pragma unroll
    for (int r = 0; r < 4; ++r) {
      float mx = fmaxf(fmaxf(acc[m][0][r], acc[m][1][r]),
                       fmaxf(acc[m][2][r], acc[m][3][r]));
#pragma unroll
      for (int msk = 1; msk < 16; msk <<= 1) mx = fmaxf(mx, __shfl_xor(mx, msk));
      float es = 0.f;
#pragma unroll
      for (int n = 0; n < 4; ++n) es += __expf(acc[m][n][r] - mx);
#pragma unroll
      for (int msk = 1; msk < 16; msk <<= 1) es += __shfl_xor(es, msk);
      if ((lane & 15) == 0) {
        const int rt = wr + m * 16 + g4 + r;
        s_m[rt][wid & 1] = mx;
        s_l[rt][wid & 1] = es;
      }
    }
  __syncthreads();
  if (t < 128) {
    const float m0 = s_m[t][0], m1 = s_m[t][1];
    const float M = fmaxf(m0, m1);
    const float L = s_l[t][0] * __expf(m0 - M) + s_l[t][1] * __expf(m1 - M);
    tstats[(size_t)(b * LQ + brow + t) * 16 + tn] = make_float2(M, L);
  }
}

// ---------------------------------------------------------------------------
// normalize: combine tile stats -> row (M, 1/L); p = exp(s-M)/L written f32
// in-place (attn output) and optionally f16 to p16 for the PV GEMM.
// One block per row, 8 elems/thread.
// ---------------------------------------------------------------------------
__global__ __launch_bounds__(256) void normalize_kernel(
    float* __restrict__ attn, const float2* __restrict__ tstats,
    f16* __restrict__ p16, const int write16) {
  const int row = blockIdx.x;
  __shared__ float sM, sI;
  if (threadIdx.x == 0) {
    float M = -3.4e38f;
    float2 st[16];
#pragma unroll
    for (int i = 0; i < 16; ++i) {
      st[i] = tstats[(size_t)row * 16 + i];
      M = fmaxf(M, st[i].x);
    }
    float L = 0.f;
#pragma unroll
    for (int i = 0; i < 16; ++i) L += st[i].y * __expf(st[i].x - M);
    sM = M;
    sI = 1.f / L;
  }
  __syncthreads();
  const float M = sM, invL = sI;
  float* rp = attn + (size_t)row * LK + threadIdx.x * 8;
  float4 v0 = *reinterpret_cast<const float4*>(rp);
  float4 v1 = *reinterpret_cast<const float4*>(rp + 4);
  v0.x = __expf(v0.x - M) * invL; v0.y = __expf(v0.y - M) * invL;
  v0.z = __expf(v0.z - M) * invL; v0.w = __expf(v0.w - M) * invL;
  v1.x = __expf(v1.x - M) * invL; v1.y = __expf(v1.y - M) * invL;
  v1.z = __expf(v1.z - M) * invL; v1.w = __expf(v1.w - M) * invL;
  *reinterpret_cast<float4*>(rp) = v0;
  *reinterpret_cast<float4*>(rp + 4) = v1;
  if (write16) {
    *reinterpret_cast<f16x8*>(p16 + (size_t)row * LK + threadIdx.x * 8) =
        cvt8(v0, v1);
  }
}

// ---------------------------------------------------------------------------
// pv: ctx = p @ v. 128x64 tile, BK=64, grid 512 (2 blocks/CU).
// A16: p from f16 copy via global_load_lds (+swizzle). else: reg-staged f32.
// B: vt f16 via global_load_lds (+swizzle).
// ---------------------------------------------------------------------------
template <bool A16>
__global__ __launch_bounds__(256, 2) void pv_kernel(
    const float* __restrict__ attnf, const f16* __restrict__ p16,
    const f16* __restrict__ vt, float* __restrict__ ctx) {
  const int bid = blockIdx.x;
  const int tn = bid & 7;
  const int tm = (bid >> 3) & 15;
  const int b = bid >> 7;
  const int brow = tm * 128, bcol = tn * 64;
  const int t = threadIdx.x;
  const int lane = t & 63;
  const int wid = t >> 6;
  const int wr = (wid >> 1) * 64, wc = (wid & 1) * 32;
  const int lr = lane & 15;
  const int lk = (lane >> 4) << 3;
  const int g4 = (lane >> 4) << 2;

  __shared__ f16 As[128 * 64];  // 16 KB
  __shared__ f16 Bs[64 * 64];   // 8 KB

  f32x4 acc[4][2] = {};

  const int srow = lane >> 3;
  const int scol = ((lane & 7) ^ srow) << 4;
  const size_t arow0 = (size_t)(b * LQ + brow);
  const char* bBase = (const char*)(vt + (size_t)(b * D + bcol) * LK);
  const int swz = (lr & 7) << 4;

  for (int k0 = 0; k0 < LK; k0 += 64) {
    if constexpr (A16) {
      const char* aBase = (const char*)(p16 + arow0 * LK);
#pragma unroll
      for (int i = 0; i < 4; ++i) {
        const int chunk = wid * 4 + i;
        const int row = chunk * 8 + srow;
        gload_lds16(aBase + (size_t)row * (LK * 2) + k0 * 2 + scol,
                    (char*)As + chunk * 1024);
      }
    } else {
#pragma unroll
      for (int i = 0; i < 4; ++i) {
        const int u = t + i * 256;       // 1024 16B-units
        const int row = u >> 3;
        const int c16 = (u & 7) << 4;    // physical col bytes (f16)
        const int csrc = c16 ^ ((row & 7) << 4);
        const float4* ps = (const float4*)((const char*)attnf +
                                           ((arow0 + row) * LK + k0) * 4 + csrc * 2);
        *(f16x8*)((char*)As + row * 128 + c16) = cvt8(ps[0], ps[1]);
      }
    }
#pragma unroll
    for (int i = 0; i < 2; ++i) {
      const int chunk = wid * 2 + i;
      const int row = chunk * 8 + srow;
      gload_lds16(bBase + (size_t)row * (LK * 2) + k0 * 2 + scol,
                  (char*)Bs + chunk * 1024);
    }
    __syncthreads();
    f16x8 af[2][4], bf[2][2];
#pragma unroll
    for (int h = 0; h < 2; ++h) {
      const int cb = h * 64 + lk * 2;
#pragma unroll
      for (int m = 0; m < 4; ++m)
        af[h][m] = *(const f16x8*)((const char*)As + (wr + m * 16 + lr) * 128 +
                                   (cb ^ swz));
#pragma unroll
      for (int n = 0; n < 2; ++n)
        bf[h][n] = *(const f16x8*)((const char*)Bs + (wc + n * 16 + lr) * 128 +
                                   (cb ^ swz));
    }
#pragma unroll
    for (int h = 0; h < 2; ++h)
#pragma unroll
      for (int m = 0; m < 4; ++m)
#pragma unroll
        for (int n = 0; n < 2; ++n)
          acc[m][n] = __builtin_amdgcn_mfma_f32_16x16x32_f16(af[h][m], bf[h][n],
                                                             acc[m][n], 0, 0, 0);
    __syncthreads();
  }

#pragma unroll
  for (int m = 0; m < 4; ++m)
#pragma unroll
    for (int n = 0; n < 2; ++n)
#pragma unroll
      for (int r = 0; r < 4; ++r) {
        const int row = brow + wr + m * 16 + g4 + r;
        const int col = bcol + wc + n * 16 + lr;
        ctx[(size_t)(b * LQ + row) * D + col] = acc[m][n][r];
      }
}

}  // namespace

extern "C" void kernel_launch(void* const* d_in, const int* in_sizes, int n_in,
                              void* d_out, int out_size, void* d_ws,
                              size_t ws_size, hipStream_t stream) {
  const float* query = (const float*)d_in[0];
  const float* key = (const float*)d_in[1];
  const float* value = (const float*)d_in[2];
  const float* Wq = (const float*)d_in[3];
  const float* bq = (const float*)d_in[4];
  const float* Wk = (const float*)d_in[5];
  const float* bk = (const float*)d_in[6];
  const float* sw = (const float*)d_in[7];

  float* ctx = (float*)d_out;                            // [B,LQ,D]
  float* attn = (float*)d_out + (size_t)BATCH * LQ * D;  // [B,LQ,LK]

  char* ws = (char*)d_ws;
  f16* vt = (f16*)ws;                                    // 8 MiB
  f16* qh = (f16*)(ws + (size_t)(8u << 20));             // 8 MiB
  f16* kh = (f16*)(ws + (size_t)(16u << 20));            // 8 MiB
  float* qnsq = (float*)(ws + (size_t)(24u << 20));      // 32 KiB
  float* knsq = qnsq + MQ;                               // 32 KiB
  float2* tstats = (float2*)(ws + (size_t)(25u << 20));  // 1 MiB
  f16* p16 = (f16*)(ws + (size_t)(26u << 20));           // 32 MiB
  const size_t ws_needed =
      ((size_t)(26u << 20)) + (size_t)BATCH * LQ * LK * sizeof(f16);
  const bool useA16 = ws_size >= ws_needed;

  transform_kernel<<<256, 256, 0, stream>>>(query, Wq, bq, qh);
  transform_kernel<<<256, 256, 0, stream>>>(key, Wk, bk, kh);
  rownorm_kernel<<<MQ / 4, 256, 0, stream>>>(qh, qnsq);
  rownorm_kernel<<<MQ / 4, 256, 0, stream>>>(kh, knsq);
  transpose_v_kernel<<<1024, 256, 0, stream>>>(value, vt);
  scores_kernel<<<1024, 256, 0, stream>>>(qh, kh, qnsq, knsq, sw, attn, tstats);
  normalize_kernel<<<MQ, 256, 0, stream>>>(attn, tstats, p16, useA16 ? 1 : 0);
  if (useA16) {
    pv_kernel<true><<<512, 256, 0, stream>>>(attn, p16, vt, ctx);
  } else {
    pv_kernel<false><<<512, 256, 0, stream>>>(attn, p16, vt, ctx);
  }
}

// Round 3
// 146.639 us; speedup vs baseline: 1.3237x; 1.2500x over previous
//
#include <hip/hip_runtime.h>
#include <cstdint>
#include <cstddef>

namespace {

constexpr int BATCH = 4;
constexpr int LQ = 2048;
constexpr int LK = 2048;
constexpr int D = 512;
constexpr int MQ = BATCH * LQ;

using f16 = _Float16;
typedef _Float16 f16x8 __attribute__((ext_vector_type(8)));
typedef _Float16 f16x4 __attribute__((ext_vector_type(4)));
typedef float f32x4 __attribute__((ext_vector_type(4)));

__device__ __forceinline__ f16x8 cvt8(const float4 a, const float4 b) {
  f16x8 h;
  h[0] = (f16)a.x; h[1] = (f16)a.y; h[2] = (f16)a.z; h[3] = (f16)a.w;
  h[4] = (f16)b.x; h[5] = (f16)b.y; h[6] = (f16)b.z; h[7] = (f16)b.w;
  return h;
}

typedef __attribute__((address_space(1))) const void gas_void;
typedef __attribute__((address_space(3))) void las_void;
__device__ __forceinline__ void gload_lds16(const void* g, void* l) {
  __builtin_amdgcn_global_load_lds((gas_void*)g, (las_void*)l, 16, 0, 0);
}

// ---------------------------------------------------------------------------
// transform: out = tanh(X @ W^T + b) -> f16, fused row sum-of-squares (atomic).
// Transposed MFMA epilogue: lane holds 4 consecutive out-cols -> f16x4 stores.
// gridDim.y: 0 = query-side, 1 = key-side.
// ---------------------------------------------------------------------------
__global__ __launch_bounds__(256) void transform_kernel(
    const float* __restrict__ query, const float* __restrict__ keyp,
    const float* __restrict__ Wq, const float* __restrict__ Wk,
    const float* __restrict__ bq, const float* __restrict__ bk,
    f16* __restrict__ qh, f16* __restrict__ kh, float* __restrict__ qnsq,
    float* __restrict__ knsq) {
  const int which = blockIdx.y;
  const float* __restrict__ X = which ? keyp : query;
  const float* __restrict__ W = which ? Wk : Wq;
  const float* __restrict__ bias = which ? bk : bq;
  f16* __restrict__ out = which ? kh : qh;
  float* __restrict__ nsq = which ? knsq : qnsq;

  const int bid = blockIdx.x;
  const int tm = bid & 63;
  const int tn = bid >> 6;
  const int brow = tm * 128, bcol = tn * 128;
  const int t = threadIdx.x;
  const int lane = t & 63;
  const int wid = t >> 6;
  const int wr = (wid >> 1) * 64, wc = (wid & 1) * 64;
  const int lr = lane & 15;
  const int lk = (lane >> 4) << 3;
  const int g4 = (lane >> 4) << 2;

  __shared__ f16 As[128][40];
  __shared__ f16 Bs[128][40];

  f32x4 acc[4][4] = {};

  for (int k0 = 0; k0 < D; k0 += 32) {
#pragma unroll
    for (int i = 0; i < 2; ++i) {
      const int u = t + i * 256;
      const int r = u >> 2;
      const int c8 = (u & 3) << 3;
      const float4* pa =
          reinterpret_cast<const float4*>(X + (size_t)(brow + r) * D + k0 + c8);
      *reinterpret_cast<f16x8*>(&As[r][c8]) = cvt8(pa[0], pa[1]);
      const float4* pb =
          reinterpret_cast<const float4*>(W + (size_t)(bcol + r) * D + k0 + c8);
      *reinterpret_cast<f16x8*>(&Bs[r][c8]) = cvt8(pb[0], pb[1]);
    }
    __syncthreads();
    f16x8 af[4], bf[4];
#pragma unroll
    for (int m = 0; m < 4; ++m)
      af[m] = *reinterpret_cast<const f16x8*>(&As[wr + m * 16 + lr][lk]);
#pragma unroll
    for (int n = 0; n < 4; ++n)
      bf[n] = *reinterpret_cast<const f16x8*>(&Bs[wc + n * 16 + lr][lk]);
    // transposed: D-row = W-row (out col), D-col = X-row (out row)
#pragma unroll
    for (int m = 0; m < 4; ++m)
#pragma unroll
      for (int n = 0; n < 4; ++n)
        acc[m][n] =
            __builtin_amdgcn_mfma_f32_16x16x32_f16(bf[n], af[m], acc[m][n], 0, 0, 0);
    __syncthreads();
  }

  float4 bv[4];
#pragma unroll
  for (int n = 0; n < 4; ++n)
    bv[n] = *reinterpret_cast<const float4*>(&bias[bcol + wc + n * 16 + g4]);

#pragma unroll
  for (int m = 0; m < 4; ++m) {
    const int row = brow + wr + m * 16 + lr;
    float ss = 0.f;
#pragma unroll
    for (int n = 0; n < 4; ++n) {
      float th[4];
#pragma unroll
      for (int r = 0; r < 4; ++r) {
        th[r] = tanhf(acc[m][n][r] + ((const float*)&bv[n])[r]);
        ss = fmaf(th[r], th[r], ss);
      }
      f16x4 h4;
      h4[0] = (f16)th[0]; h4[1] = (f16)th[1];
      h4[2] = (f16)th[2]; h4[3] = (f16)th[3];
      *reinterpret_cast<f16x4*>(out + (size_t)row * D + bcol + wc + n * 16 + g4) =
          h4;
    }
    ss += __shfl_xor(ss, 16);
    ss += __shfl_xor(ss, 32);
    if (lane < 16) atomicAdd(&nsq[row], ss);
  }
}

__global__ __launch_bounds__(256) void transpose_v_kernel(
    const float* __restrict__ v, f16* __restrict__ vt) {
  const int bid = blockIdx.x;
  const int kt = bid & 31;
  const int dt = (bid >> 5) & 7;
  const int b = bid >> 8;
  const int k0 = kt * 64, d0 = dt * 64;
  const int t = threadIdx.x;
  __shared__ f16 T[64][72];
#pragma unroll
  for (int i = 0; i < 4; ++i) {
    const int u = t + i * 256;
    const int k = u >> 4;
    const int d4 = (u & 15) << 2;
    float4 x = *reinterpret_cast<const float4*>(
        v + (size_t)(b * LK + k0 + k) * D + d0 + d4);
    T[d4 + 0][k] = (f16)x.x;
    T[d4 + 1][k] = (f16)x.y;
    T[d4 + 2][k] = (f16)x.z;
    T[d4 + 3][k] = (f16)x.w;
  }
  __syncthreads();
#pragma unroll
  for (int i = 0; i < 2; ++i) {
    const int u = t + i * 256;
    const int d = u >> 3;
    const int k8 = (u & 7) << 3;
    f16x8 h = *reinterpret_cast<const f16x8*>(&T[d][k8]);
    *reinterpret_cast<f16x8*>(vt + (size_t)(b * D + d0 + d) * LK + k0 + k8) = h;
  }
}

// ---------------------------------------------------------------------------
// scores: raw s = dot*(w0 + w1*rq*rk) - w2*sqrt(max(qn2+kn2-2dot,0)) -> attn,
// + per-(row, col-tile) row MAX -> tmax. Transposed MFMA: float4 stores.
// ---------------------------------------------------------------------------
__global__ __launch_bounds__(256, 2) void scores_kernel(
    const f16* __restrict__ qh, const f16* __restrict__ kh,
    const float* __restrict__ qnsq, const float* __restrict__ knsq,
    const float* __restrict__ sw, float* __restrict__ attn,
    float* __restrict__ tmax) {
  const int bid = blockIdx.x;
  const int tn = bid & 15;
  const int tm = (bid >> 4) & 15;
  const int b = bid >> 8;
  const int brow = tm * 128, bcol = tn * 128;
  const int t = threadIdx.x;
  const int lane = t & 63;
  const int wid = t >> 6;
  const int wr = (wid >> 1) * 64, wc = (wid & 1) * 64;
  const int lr = lane & 15;
  const int lk = (lane >> 4) << 3;
  const int g4 = (lane >> 4) << 2;

  __shared__ f16 As[128 * 64];
  __shared__ f16 Bs[128 * 64];
  __shared__ float s_m[128][2];

  f32x4 acc[4][4] = {};

  const int srow = lane >> 3;
  const int scol = ((lane & 7) ^ srow) << 4;
  const char* aBase = (const char*)(qh + (size_t)(b * LQ + brow) * D);
  const char* bBase = (const char*)(kh + (size_t)(b * LK + bcol) * D);
  const int swz = (lr & 7) << 4;

  for (int k0 = 0; k0 < D; k0 += 64) {
#pragma unroll
    for (int i = 0; i < 4; ++i) {
      const int chunk = wid * 4 + i;
      const int row = chunk * 8 + srow;
      gload_lds16(aBase + (size_t)row * (D * 2) + k0 * 2 + scol,
                  (char*)As + chunk * 1024);
      gload_lds16(bBase + (size_t)row * (D * 2) + k0 * 2 + scol,
                  (char*)Bs + chunk * 1024);
    }
    __syncthreads();
    f16x8 af[2][4], bf[2][4];
#pragma unroll
    for (int h = 0; h < 2; ++h) {
      const int cb = h * 64 + lk * 2;
#pragma unroll
      for (int m = 0; m < 4; ++m)
        af[h][m] = *(const f16x8*)((const char*)As + (wr + m * 16 + lr) * 128 +
                                   (cb ^ swz));
#pragma unroll
      for (int n = 0; n < 4; ++n)
        bf[h][n] = *(const f16x8*)((const char*)Bs + (wc + n * 16 + lr) * 128 +
                                   (cb ^ swz));
    }
    // transposed: D-row = k-dim (4 consecutive per lane), D-col = q-dim
#pragma unroll
    for (int h = 0; h < 2; ++h)
#pragma unroll
      for (int m = 0; m < 4; ++m)
#pragma unroll
        for (int n = 0; n < 4; ++n)
          acc[m][n] = __builtin_amdgcn_mfma_f32_16x16x32_f16(bf[h][n], af[h][m],
                                                             acc[m][n], 0, 0, 0);
    __syncthreads();
  }

  const float s0 = sw[0], s1 = sw[1], s2 = sw[2];
  const float smx = fmaxf(s0, fmaxf(s1, s2));
  float w0 = __expf(s0 - smx), w1 = __expf(s1 - smx), w2 = __expf(s2 - smx);
  const float winv = 1.f / (w0 + w1 + w2);
  w0 *= winv; w1 *= winv; w2 *= winv;

  // per lane: one q-row per m; 16 k-cols per (n,r)
  float qn2_[4], w1rq[4];
#pragma unroll
  for (int m = 0; m < 4; ++m) {
    const float v = qnsq[b * LQ + brow + wr + m * 16 + lr];
    qn2_[m] = v;
    w1rq[m] = w1 * rsqrtf(fmaxf(v, 1e-16f));
  }
  float4 kn2[4];
  float rk[4][4];
#pragma unroll
  for (int n = 0; n < 4; ++n) {
    kn2[n] = *reinterpret_cast<const float4*>(
        &knsq[b * LK + bcol + wc + n * 16 + g4]);
#pragma unroll
    for (int r = 0; r < 4; ++r)
      rk[n][r] = rsqrtf(fmaxf(((const float*)&kn2[n])[r], 1e-16f));
  }

#pragma unroll
  for (int m = 0; m < 4; ++m) {
    const int row = brow + wr + m * 16 + lr;
    float* rowp = attn + (size_t)(b * LQ + row) * LK + bcol + wc;
    float mx = -3.4e38f;
#pragma unroll
    for (int n = 0; n < 4; ++n) {
      float4 o;
#pragma unroll
      for (int r = 0; r < 4; ++r) {
        const float dot = acc[m][n][r];
        const float qk2 = qn2_[m] + ((const float*)&kn2[n])[r];
        const float st = sqrtf(fmaxf(qk2 - 2.f * dot, 0.f));
        const float c = fmaf(w1rq[m], rk[n][r], w0);
        const float s = fmaf(dot, c, -w2 * st);
        ((float*)&o)[r] = s;
        mx = fmaxf(mx, s);
      }
      *reinterpret_cast<float4*>(rowp + n * 16 + g4) = o;
    }
    mx = fmaxf(mx, __shfl_xor(mx, 16));
    mx = fmaxf(mx, __shfl_xor(mx, 32));
    if (lane < 16) s_m[wr + m * 16 + lr][wid & 1] = mx;
  }
  __syncthreads();
  if (t < 128)
    tmax[(size_t)(b * LQ + brow + t) * 16 + tn] = fmaxf(s_m[t][0], s_m[t][1]);
}

// ---------------------------------------------------------------------------
// normalize: M = max of 16 tile maxes; e = exp(s-M); L = block reduce;
// p = e/L written f32 in-place + f16 copy. One block per row.
// ---------------------------------------------------------------------------
__global__ __launch_bounds__(256) void normalize_kernel(
    float* __restrict__ attn, const float* __restrict__ tmax,
    f16* __restrict__ p16, const int write16) {
  const int row = blockIdx.x;
  const int t = threadIdx.x;
  __shared__ float red[4];
  __shared__ float sM;

  float M = (t < 16) ? tmax[(size_t)row * 16 + t] : -3.4e38f;
  M = fmaxf(M, __shfl_xor(M, 8));
  M = fmaxf(M, __shfl_xor(M, 4));
  M = fmaxf(M, __shfl_xor(M, 2));
  M = fmaxf(M, __shfl_xor(M, 1));
  if (t == 0) sM = M;
  __syncthreads();
  M = sM;

  float* rp = attn + (size_t)row * LK + t * 8;
  float4 v0 = *reinterpret_cast<const float4*>(rp);
  float4 v1 = *reinterpret_cast<const float4*>(rp + 4);
  v0.x = __expf(v0.x - M); v0.y = __expf(v0.y - M);
  v0.z = __expf(v0.z - M); v0.w = __expf(v0.w - M);
  v1.x = __expf(v1.x - M); v1.y = __expf(v1.y - M);
  v1.z = __expf(v1.z - M); v1.w = __expf(v1.w - M);
  float s = ((v0.x + v0.y) + (v0.z + v0.w)) + ((v1.x + v1.y) + (v1.z + v1.w));
#pragma unroll
  for (int off = 32; off; off >>= 1) s += __shfl_xor(s, off);
  if ((t & 63) == 0) red[t >> 6] = s;
  __syncthreads();
  const float L = (red[0] + red[1]) + (red[2] + red[3]);
  const float invL = 1.f / L;
  v0.x *= invL; v0.y *= invL; v0.z *= invL; v0.w *= invL;
  v1.x *= invL; v1.y *= invL; v1.z *= invL; v1.w *= invL;
  *reinterpret_cast<float4*>(rp) = v0;
  *reinterpret_cast<float4*>(rp + 4) = v1;
  if (write16) {
    *reinterpret_cast<f16x8*>(p16 + (size_t)row * LK + t * 8) = cvt8(v0, v1);
  }
}

// ---------------------------------------------------------------------------
// pv: ctx = p @ v. 128x64 tile, BK=64, grid 512 (2 blocks/CU). (unchanged)
// ---------------------------------------------------------------------------
template <bool A16>
__global__ __launch_bounds__(256, 2) void pv_kernel(
    const float* __restrict__ attnf, const f16* __restrict__ p16,
    const f16* __restrict__ vt, float* __restrict__ ctx) {
  const int bid = blockIdx.x;
  const int tn = bid & 7;
  const int tm = (bid >> 3) & 15;
  const int b = bid >> 7;
  const int brow = tm * 128, bcol = tn * 64;
  const int t = threadIdx.x;
  const int lane = t & 63;
  const int wid = t >> 6;
  const int wr = (wid >> 1) * 64, wc = (wid & 1) * 32;
  const int lr = lane & 15;
  const int lk = (lane >> 4) << 3;
  const int g4 = (lane >> 4) << 2;

  __shared__ f16 As[128 * 64];
  __shared__ f16 Bs[64 * 64];

  f32x4 acc[4][2] = {};

  const int srow = lane >> 3;
  const int scol = ((lane & 7) ^ srow) << 4;
  const size_t arow0 = (size_t)(b * LQ + brow);
  const char* bBase = (const char*)(vt + (size_t)(b * D + bcol) * LK);
  const int swz = (lr & 7) << 4;

  for (int k0 = 0; k0 < LK; k0 += 64) {
    if constexpr (A16) {
      const char* aBase = (const char*)(p16 + arow0 * LK);
#pragma unroll
      for (int i = 0; i < 4; ++i) {
        const int chunk = wid * 4 + i;
        const int row = chunk * 8 + srow;
        gload_lds16(aBase + (size_t)row * (LK * 2) + k0 * 2 + scol,
                    (char*)As + chunk * 1024);
      }
    } else {
#pragma unroll
      for (int i = 0; i < 4; ++i) {
        const int u = t + i * 256;
        const int row = u >> 3;
        const int c16 = (u & 7) << 4;
        const int csrc = c16 ^ ((row & 7) << 4);
        const float4* ps = (const float4*)((const char*)attnf +
                                           ((arow0 + row) * LK + k0) * 4 + csrc * 2);
        *(f16x8*)((char*)As + row * 128 + c16) = cvt8(ps[0], ps[1]);
      }
    }
#pragma unroll
    for (int i = 0; i < 2; ++i) {
      const int chunk = wid * 2 + i;
      const int row = chunk * 8 + srow;
      gload_lds16(bBase + (size_t)row * (LK * 2) + k0 * 2 + scol,
                  (char*)Bs + chunk * 1024);
    }
    __syncthreads();
    f16x8 af[2][4], bf[2][2];
#pragma unroll
    for (int h = 0; h < 2; ++h) {
      const int cb = h * 64 + lk * 2;
#pragma unroll
      for (int m = 0; m < 4; ++m)
        af[h][m] = *(const f16x8*)((const char*)As + (wr + m * 16 + lr) * 128 +
                                   (cb ^ swz));
#pragma unroll
      for (int n = 0; n < 2; ++n)
        bf[h][n] = *(const f16x8*)((const char*)Bs + (wc + n * 16 + lr) * 128 +
                                   (cb ^ swz));
    }
#pragma unroll
    for (int h = 0; h < 2; ++h)
#pragma unroll
      for (int m = 0; m < 4; ++m)
#pragma unroll
        for (int n = 0; n < 2; ++n)
          acc[m][n] = __builtin_amdgcn_mfma_f32_16x16x32_f16(af[h][m], bf[h][n],
                                                             acc[m][n], 0, 0, 0);
    __syncthreads();
  }

#pragma unroll
  for (int m = 0; m < 4; ++m)
#pragma unroll
    for (int n = 0; n < 2; ++n)
#pragma unroll
      for (int r = 0; r < 4; ++r) {
        const int row = brow + wr + m * 16 + g4 + r;
        const int col = bcol + wc + n * 16 + lr;
        ctx[(size_t)(b * LQ + row) * D + col] = acc[m][n][r];
      }
}

}  // namespace

extern "C" void kernel_launch(void* const* d_in, const int* in_sizes, int n_in,
                              void* d_out, int out_size, void* d_ws,
                              size_t ws_size, hipStream_t stream) {
  const float* query = (const float*)d_in[0];
  const float* key = (const float*)d_in[1];
  const float* value = (const float*)d_in[2];
  const float* Wq = (const float*)d_in[3];
  const float* bq = (const float*)d_in[4];
  const float* Wk = (const float*)d_in[5];
  const float* bk = (const float*)d_in[6];
  const float* sw = (const float*)d_in[7];

  float* ctx = (float*)d_out;                            // [B,LQ,D]
  float* attn = (float*)d_out + (size_t)BATCH * LQ * D;  // [B,LQ,LK]

  char* ws = (char*)d_ws;
  f16* vt = (f16*)ws;                                    // 8 MiB
  f16* qh = (f16*)(ws + (size_t)(8u << 20));             // 8 MiB
  f16* kh = (f16*)(ws + (size_t)(16u << 20));            // 8 MiB
  float* qnsq = (float*)(ws + (size_t)(24u << 20));      // 32 KiB
  float* knsq = qnsq + MQ;                               // 32 KiB
  float* tmax = (float*)(ws + (size_t)(25u << 20));      // 512 KiB
  f16* p16 = (f16*)(ws + (size_t)(26u << 20));           // 32 MiB
  const size_t ws_needed =
      ((size_t)(26u << 20)) + (size_t)BATCH * LQ * LK * sizeof(f16);
  const bool useA16 = ws_size >= ws_needed;

  hipMemsetAsync(qnsq, 0, (size_t)MQ * 2 * sizeof(float), stream);
  transform_kernel<<<dim3(256, 2), 256, 0, stream>>>(query, key, Wq, Wk, bq, bk,
                                                     qh, kh, qnsq, knsq);
  transpose_v_kernel<<<1024, 256, 0, stream>>>(value, vt);
  scores_kernel<<<1024, 256, 0, stream>>>(qh, kh, qnsq, knsq, sw, attn, tmax);
  normalize_kernel<<<MQ, 256, 0, stream>>>(attn, tmax, p16, useA16 ? 1 : 0);
  if (useA16) {
    pv_kernel<true><<<512, 256, 0, stream>>>(attn, p16, vt, ctx);
  } else {
    pv_kernel<false><<<512, 256, 0, stream>>>(attn, p16, vt, ctx);
  }
}

// Round 4
// 143.712 us; speedup vs baseline: 1.3507x; 1.0204x over previous
//
#include <hip/hip_runtime.h>
#include <cstdint>
#include <cstddef>

namespace {

constexpr int BATCH = 4;
constexpr int LQ = 2048;
constexpr int LK = 2048;
constexpr int D = 512;
constexpr int MQ = BATCH * LQ;

using f16 = _Float16;
typedef _Float16 f16x8 __attribute__((ext_vector_type(8)));
typedef _Float16 f16x4 __attribute__((ext_vector_type(4)));
typedef float f32x4 __attribute__((ext_vector_type(4)));

__device__ __forceinline__ f16x8 cvt8(const float4 a, const float4 b) {
  f16x8 h;
  h[0] = (f16)a.x; h[1] = (f16)a.y; h[2] = (f16)a.z; h[3] = (f16)a.w;
  h[4] = (f16)b.x; h[5] = (f16)b.y; h[6] = (f16)b.z; h[7] = (f16)b.w;
  return h;
}

typedef __attribute__((address_space(1))) const void gas_void;
typedef __attribute__((address_space(3))) void las_void;
__device__ __forceinline__ void gload_lds16(const void* g, void* l) {
  __builtin_amdgcn_global_load_lds((gas_void*)g, (las_void*)l, 16, 0, 0);
}

// ---------------------------------------------------------------------------
// transform: out = tanh(X @ W^T + b) -> f16, + per-(row, col-tile) partial
// sum-of-squares -> nsqp[row*4 + tn] (no memset, no atomics).
// gridDim.y: 0 = query-side, 1 = key-side.
// ---------------------------------------------------------------------------
__global__ __launch_bounds__(256) void transform_kernel(
    const float* __restrict__ query, const float* __restrict__ keyp,
    const float* __restrict__ Wq, const float* __restrict__ Wk,
    const float* __restrict__ bq, const float* __restrict__ bk,
    f16* __restrict__ qh, f16* __restrict__ kh, float* __restrict__ qnsqp,
    float* __restrict__ knsqp) {
  const int which = blockIdx.y;
  const float* __restrict__ X = which ? keyp : query;
  const float* __restrict__ W = which ? Wk : Wq;
  const float* __restrict__ bias = which ? bk : bq;
  f16* __restrict__ out = which ? kh : qh;
  float* __restrict__ nsqp = which ? knsqp : qnsqp;

  const int bid = blockIdx.x;
  const int tm = bid & 63;
  const int tn = bid >> 6;
  const int brow = tm * 128, bcol = tn * 128;
  const int t = threadIdx.x;
  const int lane = t & 63;
  const int wid = t >> 6;
  const int wr = (wid >> 1) * 64, wc = (wid & 1) * 64;
  const int lr = lane & 15;
  const int lk = (lane >> 4) << 3;
  const int g4 = (lane >> 4) << 2;

  __shared__ f16 As[128][40];
  __shared__ f16 Bs[128][40];
  __shared__ float s_ss[128][2];

  f32x4 acc[4][4] = {};

  for (int k0 = 0; k0 < D; k0 += 32) {
#pragma unroll
    for (int i = 0; i < 2; ++i) {
      const int u = t + i * 256;
      const int r = u >> 2;
      const int c8 = (u & 3) << 3;
      const float4* pa =
          reinterpret_cast<const float4*>(X + (size_t)(brow + r) * D + k0 + c8);
      *reinterpret_cast<f16x8*>(&As[r][c8]) = cvt8(pa[0], pa[1]);
      const float4* pb =
          reinterpret_cast<const float4*>(W + (size_t)(bcol + r) * D + k0 + c8);
      *reinterpret_cast<f16x8*>(&Bs[r][c8]) = cvt8(pb[0], pb[1]);
    }
    __syncthreads();
    f16x8 af[4], bf[4];
#pragma unroll
    for (int m = 0; m < 4; ++m)
      af[m] = *reinterpret_cast<const f16x8*>(&As[wr + m * 16 + lr][lk]);
#pragma unroll
    for (int n = 0; n < 4; ++n)
      bf[n] = *reinterpret_cast<const f16x8*>(&Bs[wc + n * 16 + lr][lk]);
    // transposed: D-row = W-row (out col), D-col = X-row (out row)
#pragma unroll
    for (int m = 0; m < 4; ++m)
#pragma unroll
      for (int n = 0; n < 4; ++n)
        acc[m][n] =
            __builtin_amdgcn_mfma_f32_16x16x32_f16(bf[n], af[m], acc[m][n], 0, 0, 0);
    __syncthreads();
  }

  float4 bv[4];
#pragma unroll
  for (int n = 0; n < 4; ++n)
    bv[n] = *reinterpret_cast<const float4*>(&bias[bcol + wc + n * 16 + g4]);

#pragma unroll
  for (int m = 0; m < 4; ++m) {
    const int row = brow + wr + m * 16 + lr;
    float ss = 0.f;
#pragma unroll
    for (int n = 0; n < 4; ++n) {
      float th[4];
#pragma unroll
      for (int r = 0; r < 4; ++r) {
        th[r] = tanhf(acc[m][n][r] + ((const float*)&bv[n])[r]);
        ss = fmaf(th[r], th[r], ss);
      }
      f16x4 h4;
      h4[0] = (f16)th[0]; h4[1] = (f16)th[1];
      h4[2] = (f16)th[2]; h4[3] = (f16)th[3];
      *reinterpret_cast<f16x4*>(out + (size_t)row * D + bcol + wc + n * 16 + g4) =
          h4;
    }
    ss += __shfl_xor(ss, 16);
    ss += __shfl_xor(ss, 32);
    if (lane < 16) s_ss[wr + m * 16 + lr][wid & 1] = ss;
  }
  __syncthreads();
  if (t < 128)
    nsqp[(size_t)(brow + t) * 4 + tn] = s_ss[t][0] + s_ss[t][1];
}

__global__ __launch_bounds__(256) void transpose_v_kernel(
    const float* __restrict__ v, f16* __restrict__ vt) {
  const int bid = blockIdx.x;
  const int kt = bid & 31;
  const int dt = (bid >> 5) & 7;
  const int b = bid >> 8;
  const int k0 = kt * 64, d0 = dt * 64;
  const int t = threadIdx.x;
  __shared__ f16 T[64][72];
#pragma unroll
  for (int i = 0; i < 4; ++i) {
    const int u = t + i * 256;
    const int k = u >> 4;
    const int d4 = (u & 15) << 2;
    float4 x = *reinterpret_cast<const float4*>(
        v + (size_t)(b * LK + k0 + k) * D + d0 + d4);
    T[d4 + 0][k] = (f16)x.x;
    T[d4 + 1][k] = (f16)x.y;
    T[d4 + 2][k] = (f16)x.z;
    T[d4 + 3][k] = (f16)x.w;
  }
  __syncthreads();
#pragma unroll
  for (int i = 0; i < 2; ++i) {
    const int u = t + i * 256;
    const int d = u >> 3;
    const int k8 = (u & 7) << 3;
    f16x8 h = *reinterpret_cast<const f16x8*>(&T[d][k8]);
    *reinterpret_cast<f16x8*>(vt + (size_t)(b * D + d0 + d) * LK + k0 + k8) = h;
  }
}

// ---------------------------------------------------------------------------
// scores: raw s = dot*(w0 + w1*rq*rk) - w2*sqrt(max(qn2+kn2-2dot,0)) -> attn,
// + per-(row, col-tile) row MAX -> tmax. Transposed MFMA: float4 stores.
// Row/col norms come as 4 partials each (sum on load).
// ---------------------------------------------------------------------------
__global__ __launch_bounds__(256, 2) void scores_kernel(
    const f16* __restrict__ qh, const f16* __restrict__ kh,
    const float* __restrict__ qnsqp, const float* __restrict__ knsqp,
    const float* __restrict__ sw, float* __restrict__ attn,
    float* __restrict__ tmax) {
  const int bid = blockIdx.x;
  const int tn = bid & 15;
  const int tm = (bid >> 4) & 15;
  const int b = bid >> 8;
  const int brow = tm * 128, bcol = tn * 128;
  const int t = threadIdx.x;
  const int lane = t & 63;
  const int wid = t >> 6;
  const int wr = (wid >> 1) * 64, wc = (wid & 1) * 64;
  const int lr = lane & 15;
  const int lk = (lane >> 4) << 3;
  const int g4 = (lane >> 4) << 2;

  __shared__ f16 As[128 * 64];
  __shared__ f16 Bs[128 * 64];
  __shared__ float s_m[128][2];

  f32x4 acc[4][4] = {};

  const int srow = lane >> 3;
  const int scol = ((lane & 7) ^ srow) << 4;
  const char* aBase = (const char*)(qh + (size_t)(b * LQ + brow) * D);
  const char* bBase = (const char*)(kh + (size_t)(b * LK + bcol) * D);
  const int swz = (lr & 7) << 4;

  for (int k0 = 0; k0 < D; k0 += 64) {
#pragma unroll
    for (int i = 0; i < 4; ++i) {
      const int chunk = wid * 4 + i;
      const int row = chunk * 8 + srow;
      gload_lds16(aBase + (size_t)row * (D * 2) + k0 * 2 + scol,
                  (char*)As + chunk * 1024);
      gload_lds16(bBase + (size_t)row * (D * 2) + k0 * 2 + scol,
                  (char*)Bs + chunk * 1024);
    }
    __syncthreads();
    f16x8 af[2][4], bf[2][4];
#pragma unroll
    for (int h = 0; h < 2; ++h) {
      const int cb = h * 64 + lk * 2;
#pragma unroll
      for (int m = 0; m < 4; ++m)
        af[h][m] = *(const f16x8*)((const char*)As + (wr + m * 16 + lr) * 128 +
                                   (cb ^ swz));
#pragma unroll
      for (int n = 0; n < 4; ++n)
        bf[h][n] = *(const f16x8*)((const char*)Bs + (wc + n * 16 + lr) * 128 +
                                   (cb ^ swz));
    }
    // transposed: D-row = k-dim (4 consecutive per lane), D-col = q-dim
#pragma unroll
    for (int h = 0; h < 2; ++h)
#pragma unroll
      for (int m = 0; m < 4; ++m)
#pragma unroll
        for (int n = 0; n < 4; ++n)
          acc[m][n] = __builtin_amdgcn_mfma_f32_16x16x32_f16(bf[h][n], af[h][m],
                                                             acc[m][n], 0, 0, 0);
    __syncthreads();
  }

  const float s0 = sw[0], s1 = sw[1], s2 = sw[2];
  const float smx = fmaxf(s0, fmaxf(s1, s2));
  float w0 = __expf(s0 - smx), w1 = __expf(s1 - smx), w2 = __expf(s2 - smx);
  const float winv = 1.f / (w0 + w1 + w2);
  w0 *= winv; w1 *= winv; w2 *= winv;

  // per lane: one q-row per m; 16 k-cols per (n,r)
  float qn2_[4], w1rq[4];
#pragma unroll
  for (int m = 0; m < 4; ++m) {
    const float4 qp = *reinterpret_cast<const float4*>(
        &qnsqp[(size_t)(b * LQ + brow + wr + m * 16 + lr) * 4]);
    const float v = (qp.x + qp.y) + (qp.z + qp.w);
    qn2_[m] = v;
    w1rq[m] = w1 * rsqrtf(fmaxf(v, 1e-16f));
  }
  float kn2[4][4], rk[4][4];
#pragma unroll
  for (int n = 0; n < 4; ++n) {
#pragma unroll
    for (int r = 0; r < 4; ++r) {
      const int col = bcol + wc + n * 16 + g4 + r;
      const float4 kp = *reinterpret_cast<const float4*>(
          &knsqp[(size_t)(b * LK + col) * 4]);
      const float v = (kp.x + kp.y) + (kp.z + kp.w);
      kn2[n][r] = v;
      rk[n][r] = rsqrtf(fmaxf(v, 1e-16f));
    }
  }

#pragma unroll
  for (int m = 0; m < 4; ++m) {
    const int row = brow + wr + m * 16 + lr;
    float* rowp = attn + (size_t)(b * LQ + row) * LK + bcol + wc;
    float mx = -3.4e38f;
#pragma unroll
    for (int n = 0; n < 4; ++n) {
      float4 o;
#pragma unroll
      for (int r = 0; r < 4; ++r) {
        const float dot = acc[m][n][r];
        const float qk2 = qn2_[m] + kn2[n][r];
        const float st = sqrtf(fmaxf(qk2 - 2.f * dot, 0.f));
        const float c = fmaf(w1rq[m], rk[n][r], w0);
        const float s = fmaf(dot, c, -w2 * st);
        ((float*)&o)[r] = s;
        mx = fmaxf(mx, s);
      }
      *reinterpret_cast<float4*>(rowp + n * 16 + g4) = o;
    }
    mx = fmaxf(mx, __shfl_xor(mx, 16));
    mx = fmaxf(mx, __shfl_xor(mx, 32));
    if (lane < 16) s_m[wr + m * 16 + lr][wid & 1] = mx;
  }
  __syncthreads();
  if (t < 128)
    tmax[(size_t)(b * LQ + brow + t) * 16 + tn] = fmaxf(s_m[t][0], s_m[t][1]);
}

// ---------------------------------------------------------------------------
// normalize: M = max of 16 tile maxes; e = exp(s-M); L = block reduce;
// p = e/L written f32 in-place + f16 copy. One block per row.
// ---------------------------------------------------------------------------
__global__ __launch_bounds__(256) void normalize_kernel(
    float* __restrict__ attn, const float* __restrict__ tmax,
    f16* __restrict__ p16, const int write16) {
  const int row = blockIdx.x;
  const int t = threadIdx.x;
  __shared__ float red[4];
  __shared__ float sM;

  float M = (t < 16) ? tmax[(size_t)row * 16 + t] : -3.4e38f;
  M = fmaxf(M, __shfl_xor(M, 8));
  M = fmaxf(M, __shfl_xor(M, 4));
  M = fmaxf(M, __shfl_xor(M, 2));
  M = fmaxf(M, __shfl_xor(M, 1));
  if (t == 0) sM = M;
  __syncthreads();
  M = sM;

  float* rp = attn + (size_t)row * LK + t * 8;
  float4 v0 = *reinterpret_cast<const float4*>(rp);
  float4 v1 = *reinterpret_cast<const float4*>(rp + 4);
  v0.x = __expf(v0.x - M); v0.y = __expf(v0.y - M);
  v0.z = __expf(v0.z - M); v0.w = __expf(v0.w - M);
  v1.x = __expf(v1.x - M); v1.y = __expf(v1.y - M);
  v1.z = __expf(v1.z - M); v1.w = __expf(v1.w - M);
  float s = ((v0.x + v0.y) + (v0.z + v0.w)) + ((v1.x + v1.y) + (v1.z + v1.w));
#pragma unroll
  for (int off = 32; off; off >>= 1) s += __shfl_xor(s, off);
  if ((t & 63) == 0) red[t >> 6] = s;
  __syncthreads();
  const float L = (red[0] + red[1]) + (red[2] + red[3]);
  const float invL = 1.f / L;
  v0.x *= invL; v0.y *= invL; v0.z *= invL; v0.w *= invL;
  v1.x *= invL; v1.y *= invL; v1.z *= invL; v1.w *= invL;
  *reinterpret_cast<float4*>(rp) = v0;
  *reinterpret_cast<float4*>(rp + 4) = v1;
  if (write16) {
    *reinterpret_cast<f16x8*>(p16 + (size_t)row * LK + t * 8) = cvt8(v0, v1);
  }
}

// ---------------------------------------------------------------------------
// pv: ctx = p @ v. 128x64 tile, BK=64, grid 512 (2 blocks/CU).
// ---------------------------------------------------------------------------
template <bool A16>
__global__ __launch_bounds__(256, 2) void pv_kernel(
    const float* __restrict__ attnf, const f16* __restrict__ p16,
    const f16* __restrict__ vt, float* __restrict__ ctx) {
  const int bid = blockIdx.x;
  const int tn = bid & 7;
  const int tm = (bid >> 3) & 15;
  const int b = bid >> 7;
  const int brow = tm * 128, bcol = tn * 64;
  const int t = threadIdx.x;
  const int lane = t & 63;
  const int wid = t >> 6;
  const int wr = (wid >> 1) * 64, wc = (wid & 1) * 32;
  const int lr = lane & 15;
  const int lk = (lane >> 4) << 3;
  const int g4 = (lane >> 4) << 2;

  __shared__ f16 As[128 * 64];
  __shared__ f16 Bs[64 * 64];

  f32x4 acc[4][2] = {};

  const int srow = lane >> 3;
  const int scol = ((lane & 7) ^ srow) << 4;
  const size_t arow0 = (size_t)(b * LQ + brow);
  const char* bBase = (const char*)(vt + (size_t)(b * D + bcol) * LK);
  const int swz = (lr & 7) << 4;

  for (int k0 = 0; k0 < LK; k0 += 64) {
    if constexpr (A16) {
      const char* aBase = (const char*)(p16 + arow0 * LK);
#pragma unroll
      for (int i = 0; i < 4; ++i) {
        const int chunk = wid * 4 + i;
        const int row = chunk * 8 + srow;
        gload_lds16(aBase + (size_t)row * (LK * 2) + k0 * 2 + scol,
                    (char*)As + chunk * 1024);
      }
    } else {
#pragma unroll
      for (int i = 0; i < 4; ++i) {
        const int u = t + i * 256;
        const int row = u >> 3;
        const int c16 = (u & 7) << 4;
        const int csrc = c16 ^ ((row & 7) << 4);
        const float4* ps = (const float4*)((const char*)attnf +
                                           ((arow0 + row) * LK + k0) * 4 + csrc * 2);
        *(f16x8*)((char*)As + row * 128 + c16) = cvt8(ps[0], ps[1]);
      }
    }
#pragma unroll
    for (int i = 0; i < 2; ++i) {
      const int chunk = wid * 2 + i;
      const int row = chunk * 8 + srow;
      gload_lds16(bBase + (size_t)row * (LK * 2) + k0 * 2 + scol,
                  (char*)Bs + chunk * 1024);
    }
    __syncthreads();
    f16x8 af[2][4], bf[2][2];
#pragma unroll
    for (int h = 0; h < 2; ++h) {
      const int cb = h * 64 + lk * 2;
#pragma unroll
      for (int m = 0; m < 4; ++m)
        af[h][m] = *(const f16x8*)((const char*)As + (wr + m * 16 + lr) * 128 +
                                   (cb ^ swz));
#pragma unroll
      for (int n = 0; n < 2; ++n)
        bf[h][n] = *(const f16x8*)((const char*)Bs + (wc + n * 16 + lr) * 128 +
                                   (cb ^ swz));
    }
#pragma unroll
    for (int h = 0; h < 2; ++h)
#pragma unroll
      for (int m = 0; m < 4; ++m)
#pragma unroll
        for (int n = 0; n < 2; ++n)
          acc[m][n] = __builtin_amdgcn_mfma_f32_16x16x32_f16(af[h][m], bf[h][n],
                                                             acc[m][n], 0, 0, 0);
    __syncthreads();
  }

#pragma unroll
  for (int m = 0; m < 4; ++m)
#pragma unroll
    for (int n = 0; n < 2; ++n)
#pragma unroll
      for (int r = 0; r < 4; ++r) {
        const int row = brow + wr + m * 16 + g4 + r;
        const int col = bcol + wc + n * 16 + lr;
        ctx[(size_t)(b * LQ + row) * D + col] = acc[m][n][r];
      }
}

}  // namespace

extern "C" void kernel_launch(void* const* d_in, const int* in_sizes, int n_in,
                              void* d_out, int out_size, void* d_ws,
                              size_t ws_size, hipStream_t stream) {
  const float* query = (const float*)d_in[0];
  const float* key = (const float*)d_in[1];
  const float* value = (const float*)d_in[2];
  const float* Wq = (const float*)d_in[3];
  const float* bq = (const float*)d_in[4];
  const float* Wk = (const float*)d_in[5];
  const float* bk = (const float*)d_in[6];
  const float* sw = (const float*)d_in[7];

  float* ctx = (float*)d_out;                            // [B,LQ,D]
  float* attn = (float*)d_out + (size_t)BATCH * LQ * D;  // [B,LQ,LK]

  char* ws = (char*)d_ws;
  f16* vt = (f16*)ws;                                    // 8 MiB
  f16* qh = (f16*)(ws + (size_t)(8u << 20));             // 8 MiB
  f16* kh = (f16*)(ws + (size_t)(16u << 20));            // 8 MiB
  float* qnsqp = (float*)(ws + (size_t)(24u << 20));     // 128 KiB
  float* knsqp = qnsqp + (size_t)MQ * 4;                 // 128 KiB
  float* tmax = (float*)(ws + (size_t)(25u << 20));      // 512 KiB
  f16* p16 = (f16*)(ws + (size_t)(26u << 20));           // 32 MiB
  const size_t ws_needed =
      ((size_t)(26u << 20)) + (size_t)BATCH * LQ * LK * sizeof(f16);
  const bool useA16 = ws_size >= ws_needed;

  transform_kernel<<<dim3(256, 2), 256, 0, stream>>>(query, key, Wq, Wk, bq, bk,
                                                     qh, kh, qnsqp, knsqp);
  transpose_v_kernel<<<1024, 256, 0, stream>>>(value, vt);
  scores_kernel<<<1024, 256, 0, stream>>>(qh, kh, qnsqp, knsqp, sw, attn, tmax);
  normalize_kernel<<<MQ, 256, 0, stream>>>(attn, tmax, p16, useA16 ? 1 : 0);
  if (useA16) {
    pv_kernel<true><<<512, 256, 0, stream>>>(attn, p16, vt, ctx);
  } else {
    pv_kernel<false><<<512, 256, 0, stream>>>(attn, p16, vt, ctx);
  }
}

// Round 5
// 134.021 us; speedup vs baseline: 1.4483x; 1.0723x over previous
//
#include <hip/hip_runtime.h>
#include <cstdint>
#include <cstddef>

namespace {

constexpr int BATCH = 4;
constexpr int LQ = 2048;
constexpr int LK = 2048;
constexpr int D = 512;
constexpr int MQ = BATCH * LQ;

using f16 = _Float16;
typedef _Float16 f16x8 __attribute__((ext_vector_type(8)));
typedef _Float16 f16x4 __attribute__((ext_vector_type(4)));
typedef float f32x4 __attribute__((ext_vector_type(4)));

__device__ __forceinline__ f16x8 cvt8(const float4 a, const float4 b) {
  f16x8 h;
  h[0] = (f16)a.x; h[1] = (f16)a.y; h[2] = (f16)a.z; h[3] = (f16)a.w;
  h[4] = (f16)b.x; h[5] = (f16)b.y; h[6] = (f16)b.z; h[7] = (f16)b.w;
  return h;
}

typedef __attribute__((address_space(1))) const void gas_void;
typedef __attribute__((address_space(3))) void las_void;
__device__ __forceinline__ void gload_lds16(const void* g, void* l) {
  __builtin_amdgcn_global_load_lds((gas_void*)g, (las_void*)l, 16, 0, 0);
}

// ---------------------------------------------------------------------------
// prep: flat-grid fusion of {q-transform, k-transform, v-transpose} so the
// independent pieces overlap in one dispatch.
//   bid <  256: qh = tanh(query@Wq^T+bq) + partial row sumsq
//   bid <  512: kh = tanh(key @Wk^T+bk) + partial row sumsq
//   bid < 1536: vt[b,d,k] = (f16) value[b,k,d]
// ---------------------------------------------------------------------------
__global__ __launch_bounds__(256) void prep_kernel(
    const float* __restrict__ query, const float* __restrict__ keyp,
    const float* __restrict__ value, const float* __restrict__ Wq,
    const float* __restrict__ Wk, const float* __restrict__ bq,
    const float* __restrict__ bk, f16* __restrict__ qh, f16* __restrict__ kh,
    float* __restrict__ qnsqp, float* __restrict__ knsqp,
    f16* __restrict__ vt) {
  __shared__ __align__(16) char smem[21504];
  const int bid0 = blockIdx.x;
  const int t = threadIdx.x;

  if (bid0 >= 512) {
    // ---- v-transpose: 64x64 tile ----
    const int bid = bid0 - 512;
    const int kt = bid & 31;
    const int dt = (bid >> 5) & 7;
    const int b = bid >> 8;
    const int k0 = kt * 64, d0 = dt * 64;
    f16(*T)[72] = reinterpret_cast<f16(*)[72]>(smem);
#pragma unroll
    for (int i = 0; i < 4; ++i) {
      const int u = t + i * 256;
      const int k = u >> 4;
      const int d4 = (u & 15) << 2;
      float4 x = *reinterpret_cast<const float4*>(
          value + (size_t)(b * LK + k0 + k) * D + d0 + d4);
      T[d4 + 0][k] = (f16)x.x;
      T[d4 + 1][k] = (f16)x.y;
      T[d4 + 2][k] = (f16)x.z;
      T[d4 + 3][k] = (f16)x.w;
    }
    __syncthreads();
#pragma unroll
    for (int i = 0; i < 2; ++i) {
      const int u = t + i * 256;
      const int d = u >> 3;
      const int k8 = (u & 7) << 3;
      f16x8 h = *reinterpret_cast<const f16x8*>(&T[d][k8]);
      *reinterpret_cast<f16x8*>(vt + (size_t)(b * D + d0 + d) * LK + k0 + k8) =
          h;
    }
    return;
  }

  // ---- tanh-transform ----
  const int which = bid0 >> 8;
  const float* __restrict__ X = which ? keyp : query;
  const float* __restrict__ W = which ? Wk : Wq;
  const float* __restrict__ bias = which ? bk : bq;
  f16* __restrict__ out = which ? kh : qh;
  float* __restrict__ nsqp = which ? knsqp : qnsqp;

  const int bid = bid0 & 255;
  const int tm = bid & 63;
  const int tn = bid >> 6;
  const int brow = tm * 128, bcol = tn * 128;
  const int lane = t & 63;
  const int wid = t >> 6;
  const int wr = (wid >> 1) * 64, wc = (wid & 1) * 64;
  const int lr = lane & 15;
  const int lk = (lane >> 4) << 3;
  const int g4 = (lane >> 4) << 2;

  f16(*As)[40] = reinterpret_cast<f16(*)[40]>(smem);
  f16(*Bs)[40] = reinterpret_cast<f16(*)[40]>(smem + 10240);
  float(*s_ss)[2] = reinterpret_cast<float(*)[2]>(smem + 20480);

  f32x4 acc[4][4] = {};

  for (int k0 = 0; k0 < D; k0 += 32) {
#pragma unroll
    for (int i = 0; i < 2; ++i) {
      const int u = t + i * 256;
      const int r = u >> 2;
      const int c8 = (u & 3) << 3;
      const float4* pa =
          reinterpret_cast<const float4*>(X + (size_t)(brow + r) * D + k0 + c8);
      *reinterpret_cast<f16x8*>(&As[r][c8]) = cvt8(pa[0], pa[1]);
      const float4* pb =
          reinterpret_cast<const float4*>(W + (size_t)(bcol + r) * D + k0 + c8);
      *reinterpret_cast<f16x8*>(&Bs[r][c8]) = cvt8(pb[0], pb[1]);
    }
    __syncthreads();
    f16x8 af[4], bf[4];
#pragma unroll
    for (int m = 0; m < 4; ++m)
      af[m] = *reinterpret_cast<const f16x8*>(&As[wr + m * 16 + lr][lk]);
#pragma unroll
    for (int n = 0; n < 4; ++n)
      bf[n] = *reinterpret_cast<const f16x8*>(&Bs[wc + n * 16 + lr][lk]);
#pragma unroll
    for (int m = 0; m < 4; ++m)
#pragma unroll
      for (int n = 0; n < 4; ++n)
        acc[m][n] =
            __builtin_amdgcn_mfma_f32_16x16x32_f16(bf[n], af[m], acc[m][n], 0, 0, 0);
    __syncthreads();
  }

  float4 bv[4];
#pragma unroll
  for (int n = 0; n < 4; ++n)
    bv[n] = *reinterpret_cast<const float4*>(&bias[bcol + wc + n * 16 + g4]);

#pragma unroll
  for (int m = 0; m < 4; ++m) {
    const int row = brow + wr + m * 16 + lr;
    float ss = 0.f;
#pragma unroll
    for (int n = 0; n < 4; ++n) {
      float th[4];
#pragma unroll
      for (int r = 0; r < 4; ++r) {
        th[r] = tanhf(acc[m][n][r] + ((const float*)&bv[n])[r]);
        ss = fmaf(th[r], th[r], ss);
      }
      f16x4 h4;
      h4[0] = (f16)th[0]; h4[1] = (f16)th[1];
      h4[2] = (f16)th[2]; h4[3] = (f16)th[3];
      *reinterpret_cast<f16x4*>(out + (size_t)row * D + bcol + wc + n * 16 + g4) =
          h4;
    }
    ss += __shfl_xor(ss, 16);
    ss += __shfl_xor(ss, 32);
    if (lane < 16) s_ss[wr + m * 16 + lr][wid & 1] = ss;
  }
  __syncthreads();
  if (t < 128) nsqp[(size_t)(brow + t) * 4 + tn] = s_ss[t][0] + s_ss[t][1];
}

// ---------------------------------------------------------------------------
// scores: raw s = dot*(w0 + w1*rq*rk) - w2*sqrt(max(qn2+kn2-2dot,0)) -> attn,
// + per-(row, col-tile) row MAX -> tmax. Transposed MFMA: float4 stores.
// ---------------------------------------------------------------------------
__global__ __launch_bounds__(256, 2) void scores_kernel(
    const f16* __restrict__ qh, const f16* __restrict__ kh,
    const float* __restrict__ qnsqp, const float* __restrict__ knsqp,
    const float* __restrict__ sw, float* __restrict__ attn,
    float* __restrict__ tmax) {
  const int bid = blockIdx.x;
  const int tn = bid & 15;
  const int tm = (bid >> 4) & 15;
  const int b = bid >> 8;
  const int brow = tm * 128, bcol = tn * 128;
  const int t = threadIdx.x;
  const int lane = t & 63;
  const int wid = t >> 6;
  const int wr = (wid >> 1) * 64, wc = (wid & 1) * 64;
  const int lr = lane & 15;
  const int lk = (lane >> 4) << 3;
  const int g4 = (lane >> 4) << 2;

  __shared__ f16 As[128 * 64];
  __shared__ f16 Bs[128 * 64];
  __shared__ float s_m[128][2];

  f32x4 acc[4][4] = {};

  const int srow = lane >> 3;
  const int scol = ((lane & 7) ^ srow) << 4;
  const char* aBase = (const char*)(qh + (size_t)(b * LQ + brow) * D);
  const char* bBase = (const char*)(kh + (size_t)(b * LK + bcol) * D);
  const int swz = (lr & 7) << 4;

  for (int k0 = 0; k0 < D; k0 += 64) {
#pragma unroll
    for (int i = 0; i < 4; ++i) {
      const int chunk = wid * 4 + i;
      const int row = chunk * 8 + srow;
      gload_lds16(aBase + (size_t)row * (D * 2) + k0 * 2 + scol,
                  (char*)As + chunk * 1024);
      gload_lds16(bBase + (size_t)row * (D * 2) + k0 * 2 + scol,
                  (char*)Bs + chunk * 1024);
    }
    __syncthreads();
    f16x8 af[2][4], bf[2][4];
#pragma unroll
    for (int h = 0; h < 2; ++h) {
      const int cb = h * 64 + lk * 2;
#pragma unroll
      for (int m = 0; m < 4; ++m)
        af[h][m] = *(const f16x8*)((const char*)As + (wr + m * 16 + lr) * 128 +
                                   (cb ^ swz));
#pragma unroll
      for (int n = 0; n < 4; ++n)
        bf[h][n] = *(const f16x8*)((const char*)Bs + (wc + n * 16 + lr) * 128 +
                                   (cb ^ swz));
    }
#pragma unroll
    for (int h = 0; h < 2; ++h)
#pragma unroll
      for (int m = 0; m < 4; ++m)
#pragma unroll
        for (int n = 0; n < 4; ++n)
          acc[m][n] = __builtin_amdgcn_mfma_f32_16x16x32_f16(bf[h][n], af[h][m],
                                                             acc[m][n], 0, 0, 0);
    __syncthreads();
  }

  const float s0 = sw[0], s1 = sw[1], s2 = sw[2];
  const float smx = fmaxf(s0, fmaxf(s1, s2));
  float w0 = __expf(s0 - smx), w1 = __expf(s1 - smx), w2 = __expf(s2 - smx);
  const float winv = 1.f / (w0 + w1 + w2);
  w0 *= winv; w1 *= winv; w2 *= winv;

  float qn2_[4], w1rq[4];
#pragma unroll
  for (int m = 0; m < 4; ++m) {
    const float4 qp = *reinterpret_cast<const float4*>(
        &qnsqp[(size_t)(b * LQ + brow + wr + m * 16 + lr) * 4]);
    const float v = (qp.x + qp.y) + (qp.z + qp.w);
    qn2_[m] = v;
    w1rq[m] = w1 * rsqrtf(fmaxf(v, 1e-16f));
  }
  float kn2[4][4], rk[4][4];
#pragma unroll
  for (int n = 0; n < 4; ++n) {
#pragma unroll
    for (int r = 0; r < 4; ++r) {
      const int col = bcol + wc + n * 16 + g4 + r;
      const float4 kp = *reinterpret_cast<const float4*>(
          &knsqp[(size_t)(b * LK + col) * 4]);
      const float v = (kp.x + kp.y) + (kp.z + kp.w);
      kn2[n][r] = v;
      rk[n][r] = rsqrtf(fmaxf(v, 1e-16f));
    }
  }

#pragma unroll
  for (int m = 0; m < 4; ++m) {
    const int row = brow + wr + m * 16 + lr;
    float* rowp = attn + (size_t)(b * LQ + row) * LK + bcol + wc;
    float mx = -3.4e38f;
#pragma unroll
    for (int n = 0; n < 4; ++n) {
      float4 o;
#pragma unroll
      for (int r = 0; r < 4; ++r) {
        const float dot = acc[m][n][r];
        const float qk2 = qn2_[m] + kn2[n][r];
        const float st = sqrtf(fmaxf(qk2 - 2.f * dot, 0.f));
        const float c = fmaf(w1rq[m], rk[n][r], w0);
        const float s = fmaf(dot, c, -w2 * st);
        ((float*)&o)[r] = s;
        mx = fmaxf(mx, s);
      }
      *reinterpret_cast<float4*>(rowp + n * 16 + g4) = o;
    }
    mx = fmaxf(mx, __shfl_xor(mx, 16));
    mx = fmaxf(mx, __shfl_xor(mx, 32));
    if (lane < 16) s_m[wr + m * 16 + lr][wid & 1] = mx;
  }
  __syncthreads();
  if (t < 128)
    tmax[(size_t)(b * LQ + brow + t) * 16 + tn] = fmaxf(s_m[t][0], s_m[t][1]);
}

// ---------------------------------------------------------------------------
// normalize: M = max of 16 tile maxes; e = exp(s-M); L = block reduce;
// p = e/L written f32 in-place + f16 copy for the PV GEMM.
// ---------------------------------------------------------------------------
__global__ __launch_bounds__(256) void normalize_kernel(
    float* __restrict__ attn, const float* __restrict__ tmax,
    f16* __restrict__ p16, const int write16) {
  const int row = blockIdx.x;
  const int t = threadIdx.x;
  __shared__ float red[4];
  __shared__ float sM;

  float M = (t < 16) ? tmax[(size_t)row * 16 + t] : -3.4e38f;
  M = fmaxf(M, __shfl_xor(M, 8));
  M = fmaxf(M, __shfl_xor(M, 4));
  M = fmaxf(M, __shfl_xor(M, 2));
  M = fmaxf(M, __shfl_xor(M, 1));
  if (t == 0) sM = M;
  __syncthreads();
  M = sM;

  float* rp = attn + (size_t)row * LK + t * 8;
  float4 v0 = *reinterpret_cast<const float4*>(rp);
  float4 v1 = *reinterpret_cast<const float4*>(rp + 4);
  v0.x = __expf(v0.x - M); v0.y = __expf(v0.y - M);
  v0.z = __expf(v0.z - M); v0.w = __expf(v0.w - M);
  v1.x = __expf(v1.x - M); v1.y = __expf(v1.y - M);
  v1.z = __expf(v1.z - M); v1.w = __expf(v1.w - M);
  float s = ((v0.x + v0.y) + (v0.z + v0.w)) + ((v1.x + v1.y) + (v1.z + v1.w));
#pragma unroll
  for (int off = 32; off; off >>= 1) s += __shfl_xor(s, off);
  if ((t & 63) == 0) red[t >> 6] = s;
  __syncthreads();
  const float L = (red[0] + red[1]) + (red[2] + red[3]);
  const float invL = 1.f / L;
  v0.x *= invL; v0.y *= invL; v0.z *= invL; v0.w *= invL;
  v1.x *= invL; v1.y *= invL; v1.z *= invL; v1.w *= invL;
  *reinterpret_cast<float4*>(rp) = v0;
  *reinterpret_cast<float4*>(rp + 4) = v1;
  if (write16) {
    *reinterpret_cast<f16x8*>(p16 + (size_t)row * LK + t * 8) = cvt8(v0, v1);
  }
}

// ---------------------------------------------------------------------------
// pv: ctx = p @ v. 64x128 tile (N=128 halves A re-reads), BK=64, grid 512.
// Transposed MFMA epilogue -> float4 ctx stores.
// ---------------------------------------------------------------------------
template <bool A16>
__global__ __launch_bounds__(256, 2) void pv_kernel(
    const float* __restrict__ attnf, const f16* __restrict__ p16,
    const f16* __restrict__ vt, float* __restrict__ ctx) {
  const int bid = blockIdx.x;
  const int tn = bid & 3;          // D/128
  const int tm = (bid >> 2) & 31;  // LQ/64
  const int b = bid >> 7;
  const int brow = tm * 64, bcol = tn * 128;
  const int t = threadIdx.x;
  const int lane = t & 63;
  const int wid = t >> 6;
  const int wr = (wid >> 1) * 32, wc = (wid & 1) * 64;
  const int lr = lane & 15;
  const int lk = (lane >> 4) << 3;
  const int g4 = (lane >> 4) << 2;

  __shared__ f16 As[64 * 64];   // 8 KB
  __shared__ f16 Bs[128 * 64];  // 16 KB

  f32x4 acc[2][4] = {};

  const int srow = lane >> 3;
  const int scol = ((lane & 7) ^ srow) << 4;
  const size_t arow0 = (size_t)(b * LQ + brow);
  const char* bBase = (const char*)(vt + (size_t)(b * D + bcol) * LK);
  const int swz = (lr & 7) << 4;

  for (int k0 = 0; k0 < LK; k0 += 64) {
    if constexpr (A16) {
      const char* aBase = (const char*)(p16 + arow0 * LK);
#pragma unroll
      for (int i = 0; i < 2; ++i) {
        const int chunk = wid * 2 + i;
        const int row = chunk * 8 + srow;
        gload_lds16(aBase + (size_t)row * (LK * 2) + k0 * 2 + scol,
                    (char*)As + chunk * 1024);
      }
    } else {
#pragma unroll
      for (int i = 0; i < 2; ++i) {
        const int u = t + i * 256;  // 512 16B-units (64 rows x 8)
        const int row = u >> 3;
        const int c16 = (u & 7) << 4;
        const int csrc = c16 ^ ((row & 7) << 4);
        const float4* ps = (const float4*)((const char*)attnf +
                                           ((arow0 + row) * LK + k0) * 4 + csrc * 2);
        *(f16x8*)((char*)As + row * 128 + c16) = cvt8(ps[0], ps[1]);
      }
    }
#pragma unroll
    for (int i = 0; i < 4; ++i) {
      const int chunk = wid * 4 + i;
      const int row = chunk * 8 + srow;
      gload_lds16(bBase + (size_t)row * (LK * 2) + k0 * 2 + scol,
                  (char*)Bs + chunk * 1024);
    }
    __syncthreads();
    f16x8 af[2][2], bf[2][4];
#pragma unroll
    for (int h = 0; h < 2; ++h) {
      const int cb = h * 64 + lk * 2;
#pragma unroll
      for (int m = 0; m < 2; ++m)
        af[h][m] = *(const f16x8*)((const char*)As + (wr + m * 16 + lr) * 128 +
                                   (cb ^ swz));
#pragma unroll
      for (int n = 0; n < 4; ++n)
        bf[h][n] = *(const f16x8*)((const char*)Bs + (wc + n * 16 + lr) * 128 +
                                   (cb ^ swz));
    }
    // transposed: lane (lr) -> p-row, regs -> 4 consecutive v-cols
#pragma unroll
    for (int h = 0; h < 2; ++h)
#pragma unroll
      for (int m = 0; m < 2; ++m)
#pragma unroll
        for (int n = 0; n < 4; ++n)
          acc[m][n] = __builtin_amdgcn_mfma_f32_16x16x32_f16(bf[h][n], af[h][m],
                                                             acc[m][n], 0, 0, 0);
    __syncthreads();
  }

#pragma unroll
  for (int m = 0; m < 2; ++m) {
    const int row = brow + wr + m * 16 + lr;
    float* rowp = ctx + (size_t)(b * LQ + row) * D + bcol + wc;
#pragma unroll
    for (int n = 0; n < 4; ++n) {
      float4 o;
      o.x = acc[m][n][0]; o.y = acc[m][n][1];
      o.z = acc[m][n][2]; o.w = acc[m][n][3];
      *reinterpret_cast<float4*>(rowp + n * 16 + g4) = o;
    }
  }
}

}  // namespace

extern "C" void kernel_launch(void* const* d_in, const int* in_sizes, int n_in,
                              void* d_out, int out_size, void* d_ws,
                              size_t ws_size, hipStream_t stream) {
  const float* query = (const float*)d_in[0];
  const float* key = (const float*)d_in[1];
  const float* value = (const float*)d_in[2];
  const float* Wq = (const float*)d_in[3];
  const float* bq = (const float*)d_in[4];
  const float* Wk = (const float*)d_in[5];
  const float* bk = (const float*)d_in[6];
  const float* sw = (const float*)d_in[7];

  float* ctx = (float*)d_out;                            // [B,LQ,D]
  float* attn = (float*)d_out + (size_t)BATCH * LQ * D;  // [B,LQ,LK]

  char* ws = (char*)d_ws;
  f16* vt = (f16*)ws;                                    // 8 MiB
  f16* qh = (f16*)(ws + (size_t)(8u << 20));             // 8 MiB
  f16* kh = (f16*)(ws + (size_t)(16u << 20));            // 8 MiB
  float* qnsqp = (float*)(ws + (size_t)(24u << 20));     // 128 KiB
  float* knsqp = qnsqp + (size_t)MQ * 4;                 // 128 KiB
  float* tmax = (float*)(ws + (size_t)(25u << 20));      // 512 KiB
  f16* p16 = (f16*)(ws + (size_t)(26u << 20));           // 32 MiB
  const size_t ws_needed =
      ((size_t)(26u << 20)) + (size_t)BATCH * LQ * LK * sizeof(f16);
  const bool useA16 = ws_size >= ws_needed;

  prep_kernel<<<1536, 256, 0, stream>>>(query, key, value, Wq, Wk, bq, bk, qh,
                                        kh, qnsqp, knsqp, vt);
  scores_kernel<<<1024, 256, 0, stream>>>(qh, kh, qnsqp, knsqp, sw, attn, tmax);
  normalize_kernel<<<MQ, 256, 0, stream>>>(attn, tmax, p16, useA16 ? 1 : 0);
  if (useA16) {
    pv_kernel<true><<<512, 256, 0, stream>>>(attn, p16, vt, ctx);
  } else {
    pv_kernel<false><<<512, 256, 0, stream>>>(attn, p16, vt, ctx);
  }
}

// Round 6
// 125.635 us; speedup vs baseline: 1.5450x; 1.0668x over previous
//
#include <hip/hip_runtime.h>
#include <cstdint>
#include <cstddef>

namespace {

constexpr int BATCH = 4;
constexpr int LQ = 2048;
constexpr int LK = 2048;
constexpr int D = 512;
constexpr int MQ = BATCH * LQ;

using f16 = _Float16;
typedef _Float16 f16x8 __attribute__((ext_vector_type(8)));
typedef _Float16 f16x4 __attribute__((ext_vector_type(4)));
typedef float f32x4 __attribute__((ext_vector_type(4)));

__device__ __forceinline__ f16x8 cvt8(const float4 a, const float4 b) {
  f16x8 h;
  h[0] = (f16)a.x; h[1] = (f16)a.y; h[2] = (f16)a.z; h[3] = (f16)a.w;
  h[4] = (f16)b.x; h[5] = (f16)b.y; h[6] = (f16)b.z; h[7] = (f16)b.w;
  return h;
}

typedef __attribute__((address_space(1))) const void gas_void;
typedef __attribute__((address_space(3))) void las_void;
__device__ __forceinline__ void gload_lds16(const void* g, void* l) {
  __builtin_amdgcn_global_load_lds((gas_void*)g, (las_void*)l, 16, 0, 0);
}

// ---------------------------------------------------------------------------
// prep: flat-grid fusion of {q-transform, k-transform, v-transpose}.
// ---------------------------------------------------------------------------
__global__ __launch_bounds__(256) void prep_kernel(
    const float* __restrict__ query, const float* __restrict__ keyp,
    const float* __restrict__ value, const float* __restrict__ Wq,
    const float* __restrict__ Wk, const float* __restrict__ bq,
    const float* __restrict__ bk, f16* __restrict__ qh, f16* __restrict__ kh,
    float* __restrict__ qnsqp, float* __restrict__ knsqp,
    f16* __restrict__ vt) {
  __shared__ __align__(16) char smem[21504];
  const int bid0 = blockIdx.x;
  const int t = threadIdx.x;

  if (bid0 >= 512) {
    // ---- v-transpose: 64x64 tile ----
    const int bid = bid0 - 512;
    const int kt = bid & 31;
    const int dt = (bid >> 5) & 7;
    const int b = bid >> 8;
    const int k0 = kt * 64, d0 = dt * 64;
    f16(*T)[72] = reinterpret_cast<f16(*)[72]>(smem);
#pragma unroll
    for (int i = 0; i < 4; ++i) {
      const int u = t + i * 256;
      const int k = u >> 4;
      const int d4 = (u & 15) << 2;
      float4 x = *reinterpret_cast<const float4*>(
          value + (size_t)(b * LK + k0 + k) * D + d0 + d4);
      T[d4 + 0][k] = (f16)x.x;
      T[d4 + 1][k] = (f16)x.y;
      T[d4 + 2][k] = (f16)x.z;
      T[d4 + 3][k] = (f16)x.w;
    }
    __syncthreads();
#pragma unroll
    for (int i = 0; i < 2; ++i) {
      const int u = t + i * 256;
      const int d = u >> 3;
      const int k8 = (u & 7) << 3;
      f16x8 h = *reinterpret_cast<const f16x8*>(&T[d][k8]);
      *reinterpret_cast<f16x8*>(vt + (size_t)(b * D + d0 + d) * LK + k0 + k8) =
          h;
    }
    return;
  }

  // ---- tanh-transform ----
  const int which = bid0 >> 8;
  const float* __restrict__ X = which ? keyp : query;
  const float* __restrict__ W = which ? Wk : Wq;
  const float* __restrict__ bias = which ? bk : bq;
  f16* __restrict__ out = which ? kh : qh;
  float* __restrict__ nsqp = which ? knsqp : qnsqp;

  const int bid = bid0 & 255;
  const int tm = bid & 63;
  const int tn = bid >> 6;
  const int brow = tm * 128, bcol = tn * 128;
  const int lane = t & 63;
  const int wid = t >> 6;
  const int wr = (wid >> 1) * 64, wc = (wid & 1) * 64;
  const int lr = lane & 15;
  const int lk = (lane >> 4) << 3;
  const int g4 = (lane >> 4) << 2;

  f16(*As)[40] = reinterpret_cast<f16(*)[40]>(smem);
  f16(*Bs)[40] = reinterpret_cast<f16(*)[40]>(smem + 10240);
  float(*s_ss)[2] = reinterpret_cast<float(*)[2]>(smem + 20480);

  f32x4 acc[4][4] = {};

  for (int k0 = 0; k0 < D; k0 += 32) {
#pragma unroll
    for (int i = 0; i < 2; ++i) {
      const int u = t + i * 256;
      const int r = u >> 2;
      const int c8 = (u & 3) << 3;
      const float4* pa =
          reinterpret_cast<const float4*>(X + (size_t)(brow + r) * D + k0 + c8);
      *reinterpret_cast<f16x8*>(&As[r][c8]) = cvt8(pa[0], pa[1]);
      const float4* pb =
          reinterpret_cast<const float4*>(W + (size_t)(bcol + r) * D + k0 + c8);
      *reinterpret_cast<f16x8*>(&Bs[r][c8]) = cvt8(pb[0], pb[1]);
    }
    __syncthreads();
    f16x8 af[4], bf[4];
#pragma unroll
    for (int m = 0; m < 4; ++m)
      af[m] = *reinterpret_cast<const f16x8*>(&As[wr + m * 16 + lr][lk]);
#pragma unroll
    for (int n = 0; n < 4; ++n)
      bf[n] = *reinterpret_cast<const f16x8*>(&Bs[wc + n * 16 + lr][lk]);
#pragma unroll
    for (int m = 0; m < 4; ++m)
#pragma unroll
      for (int n = 0; n < 4; ++n)
        acc[m][n] =
            __builtin_amdgcn_mfma_f32_16x16x32_f16(bf[n], af[m], acc[m][n], 0, 0, 0);
    __syncthreads();
  }

  float4 bv[4];
#pragma unroll
  for (int n = 0; n < 4; ++n)
    bv[n] = *reinterpret_cast<const float4*>(&bias[bcol + wc + n * 16 + g4]);

#pragma unroll
  for (int m = 0; m < 4; ++m) {
    const int row = brow + wr + m * 16 + lr;
    float ss = 0.f;
#pragma unroll
    for (int n = 0; n < 4; ++n) {
      float th[4];
#pragma unroll
      for (int r = 0; r < 4; ++r) {
        th[r] = tanhf(acc[m][n][r] + ((const float*)&bv[n])[r]);
        ss = fmaf(th[r], th[r], ss);
      }
      f16x4 h4;
      h4[0] = (f16)th[0]; h4[1] = (f16)th[1];
      h4[2] = (f16)th[2]; h4[3] = (f16)th[3];
      *reinterpret_cast<f16x4*>(out + (size_t)row * D + bcol + wc + n * 16 + g4) =
          h4;
    }
    ss += __shfl_xor(ss, 16);
    ss += __shfl_xor(ss, 32);
    if (lane < 16) s_ss[wr + m * 16 + lr][wid & 1] = ss;
  }
  __syncthreads();
  if (t < 128) nsqp[(size_t)(brow + t) * 4 + tn] = s_ss[t][0] + s_ss[t][1];
}

// ---------------------------------------------------------------------------
// scores: raw s = dot*(w0 + w1*rq*rk) - w2*sqrt(max(qn2+kn2-2dot,0))
// RAW16: write f16 raw scores -> sraw (half the write traffic).
// else:  write f32 raw scores -> attn.
// + per-(row, col-tile) row MAX -> tmax.
// ---------------------------------------------------------------------------
template <bool RAW16>
__global__ __launch_bounds__(256, 2) void scores_kernel(
    const f16* __restrict__ qh, const f16* __restrict__ kh,
    const float* __restrict__ qnsqp, const float* __restrict__ knsqp,
    const float* __restrict__ sw, float* __restrict__ attn,
    f16* __restrict__ sraw, float* __restrict__ tmax) {
  const int bid = blockIdx.x;
  const int tn = bid & 15;
  const int tm = (bid >> 4) & 15;
  const int b = bid >> 8;
  const int brow = tm * 128, bcol = tn * 128;
  const int t = threadIdx.x;
  const int lane = t & 63;
  const int wid = t >> 6;
  const int wr = (wid >> 1) * 64, wc = (wid & 1) * 64;
  const int lr = lane & 15;
  const int lk = (lane >> 4) << 3;
  const int g4 = (lane >> 4) << 2;

  __shared__ f16 As[128 * 64];
  __shared__ f16 Bs[128 * 64];
  __shared__ float s_m[128][2];

  f32x4 acc[4][4] = {};

  const int srow = lane >> 3;
  const int scol = ((lane & 7) ^ srow) << 4;
  const char* aBase = (const char*)(qh + (size_t)(b * LQ + brow) * D);
  const char* bBase = (const char*)(kh + (size_t)(b * LK + bcol) * D);
  const int swz = (lr & 7) << 4;

  for (int k0 = 0; k0 < D; k0 += 64) {
#pragma unroll
    for (int i = 0; i < 4; ++i) {
      const int chunk = wid * 4 + i;
      const int row = chunk * 8 + srow;
      gload_lds16(aBase + (size_t)row * (D * 2) + k0 * 2 + scol,
                  (char*)As + chunk * 1024);
      gload_lds16(bBase + (size_t)row * (D * 2) + k0 * 2 + scol,
                  (char*)Bs + chunk * 1024);
    }
    __syncthreads();
    f16x8 af[2][4], bf[2][4];
#pragma unroll
    for (int h = 0; h < 2; ++h) {
      const int cb = h * 64 + lk * 2;
#pragma unroll
      for (int m = 0; m < 4; ++m)
        af[h][m] = *(const f16x8*)((const char*)As + (wr + m * 16 + lr) * 128 +
                                   (cb ^ swz));
#pragma unroll
      for (int n = 0; n < 4; ++n)
        bf[h][n] = *(const f16x8*)((const char*)Bs + (wc + n * 16 + lr) * 128 +
                                   (cb ^ swz));
    }
#pragma unroll
    for (int h = 0; h < 2; ++h)
#pragma unroll
      for (int m = 0; m < 4; ++m)
#pragma unroll
        for (int n = 0; n < 4; ++n)
          acc[m][n] = __builtin_amdgcn_mfma_f32_16x16x32_f16(bf[h][n], af[h][m],
                                                             acc[m][n], 0, 0, 0);
    __syncthreads();
  }

  const float s0 = sw[0], s1 = sw[1], s2 = sw[2];
  const float smx = fmaxf(s0, fmaxf(s1, s2));
  float w0 = __expf(s0 - smx), w1 = __expf(s1 - smx), w2 = __expf(s2 - smx);
  const float winv = 1.f / (w0 + w1 + w2);
  w0 *= winv; w1 *= winv; w2 *= winv;

  float qn2_[4], w1rq[4];
#pragma unroll
  for (int m = 0; m < 4; ++m) {
    const float4 qp = *reinterpret_cast<const float4*>(
        &qnsqp[(size_t)(b * LQ + brow + wr + m * 16 + lr) * 4]);
    const float v = (qp.x + qp.y) + (qp.z + qp.w);
    qn2_[m] = v;
    w1rq[m] = w1 * rsqrtf(fmaxf(v, 1e-16f));
  }
  float kn2[4][4], rk[4][4];
#pragma unroll
  for (int n = 0; n < 4; ++n) {
#pragma unroll
    for (int r = 0; r < 4; ++r) {
      const int col = bcol + wc + n * 16 + g4 + r;
      const float4 kp = *reinterpret_cast<const float4*>(
          &knsqp[(size_t)(b * LK + col) * 4]);
      const float v = (kp.x + kp.y) + (kp.z + kp.w);
      kn2[n][r] = v;
      rk[n][r] = rsqrtf(fmaxf(v, 1e-16f));
    }
  }

#pragma unroll
  for (int m = 0; m < 4; ++m) {
    const int row = brow + wr + m * 16 + lr;
    float mx = -3.4e38f;
#pragma unroll
    for (int n = 0; n < 4; ++n) {
      float4 o;
#pragma unroll
      for (int r = 0; r < 4; ++r) {
        const float dot = acc[m][n][r];
        const float qk2 = qn2_[m] + kn2[n][r];
        const float st = sqrtf(fmaxf(qk2 - 2.f * dot, 0.f));
        const float c = fmaf(w1rq[m], rk[n][r], w0);
        const float s = fmaf(dot, c, -w2 * st);
        ((float*)&o)[r] = s;
        mx = fmaxf(mx, s);
      }
      if constexpr (RAW16) {
        f16x4 h4;
        h4[0] = (f16)o.x; h4[1] = (f16)o.y; h4[2] = (f16)o.z; h4[3] = (f16)o.w;
        *reinterpret_cast<f16x4*>(sraw + (size_t)(b * LQ + row) * LK + bcol +
                                  wc + n * 16 + g4) = h4;
      } else {
        *reinterpret_cast<float4*>(attn + (size_t)(b * LQ + row) * LK + bcol +
                                   wc + n * 16 + g4) = o;
      }
    }
    mx = fmaxf(mx, __shfl_xor(mx, 16));
    mx = fmaxf(mx, __shfl_xor(mx, 32));
    if (lane < 16) s_m[wr + m * 16 + lr][wid & 1] = mx;
  }
  __syncthreads();
  if (t < 128)
    tmax[(size_t)(b * LQ + brow + t) * 16 + tn] = fmaxf(s_m[t][0], s_m[t][1]);
}

// ---------------------------------------------------------------------------
// normalize: M = max of 16 tile maxes; e = exp(s-M); L = block reduce;
// RAW16: read f16 raw from sraw; write f32 attn + normalized f16 in-place.
// else:  f32 in-place on attn only.
// ---------------------------------------------------------------------------
template <bool RAW16>
__global__ __launch_bounds__(256) void normalize_kernel(
    float* __restrict__ attn, const float* __restrict__ tmax,
    f16* __restrict__ sraw) {
  const int row = blockIdx.x;
  const int t = threadIdx.x;
  __shared__ float red[4];
  __shared__ float sM;

  float M = (t < 16) ? tmax[(size_t)row * 16 + t] : -3.4e38f;
  M = fmaxf(M, __shfl_xor(M, 8));
  M = fmaxf(M, __shfl_xor(M, 4));
  M = fmaxf(M, __shfl_xor(M, 2));
  M = fmaxf(M, __shfl_xor(M, 1));
  if (t == 0) sM = M;
  __syncthreads();
  M = sM;

  float e[8];
  float* rp = attn + (size_t)row * LK + t * 8;
  f16* hp = sraw + (size_t)row * LK + t * 8;
  if constexpr (RAW16) {
    f16x8 h = *reinterpret_cast<const f16x8*>(hp);
#pragma unroll
    for (int j = 0; j < 8; ++j) e[j] = __expf((float)h[j] - M);
  } else {
    float4 v0 = *reinterpret_cast<const float4*>(rp);
    float4 v1 = *reinterpret_cast<const float4*>(rp + 4);
    e[0] = __expf(v0.x - M); e[1] = __expf(v0.y - M);
    e[2] = __expf(v0.z - M); e[3] = __expf(v0.w - M);
    e[4] = __expf(v1.x - M); e[5] = __expf(v1.y - M);
    e[6] = __expf(v1.z - M); e[7] = __expf(v1.w - M);
  }
  float s = ((e[0] + e[1]) + (e[2] + e[3])) + ((e[4] + e[5]) + (e[6] + e[7]));
#pragma unroll
  for (int off = 32; off; off >>= 1) s += __shfl_xor(s, off);
  if ((t & 63) == 0) red[t >> 6] = s;
  __syncthreads();
  const float L = (red[0] + red[1]) + (red[2] + red[3]);
  const float invL = 1.f / L;
  float4 v0, v1;
  v0.x = e[0] * invL; v0.y = e[1] * invL; v0.z = e[2] * invL; v0.w = e[3] * invL;
  v1.x = e[4] * invL; v1.y = e[5] * invL; v1.z = e[6] * invL; v1.w = e[7] * invL;
  *reinterpret_cast<float4*>(rp) = v0;
  *reinterpret_cast<float4*>(rp + 4) = v1;
  if constexpr (RAW16) {
    *reinterpret_cast<f16x8*>(hp) = cvt8(v0, v1);
  }
}

// ---------------------------------------------------------------------------
// pv: ctx = p @ v. 64x128 tile, BK=64, grid 512.
// A16: p16 = normalized f16 (gload_lds). else: reg-staged f32 attn.
// ---------------------------------------------------------------------------
template <bool A16>
__global__ __launch_bounds__(256, 2) void pv_kernel(
    const float* __restrict__ attnf, const f16* __restrict__ p16,
    const f16* __restrict__ vt, float* __restrict__ ctx) {
  const int bid = blockIdx.x;
  const int tn = bid & 3;          // D/128
  const int tm = (bid >> 2) & 31;  // LQ/64
  const int b = bid >> 7;
  const int brow = tm * 64, bcol = tn * 128;
  const int t = threadIdx.x;
  const int lane = t & 63;
  const int wid = t >> 6;
  const int wr = (wid >> 1) * 32, wc = (wid & 1) * 64;
  const int lr = lane & 15;
  const int lk = (lane >> 4) << 3;
  const int g4 = (lane >> 4) << 2;

  __shared__ f16 As[64 * 64];   // 8 KB
  __shared__ f16 Bs[128 * 64];  // 16 KB

  f32x4 acc[2][4] = {};

  const int srow = lane >> 3;
  const int scol = ((lane & 7) ^ srow) << 4;
  const size_t arow0 = (size_t)(b * LQ + brow);
  const char* bBase = (const char*)(vt + (size_t)(b * D + bcol) * LK);
  const int swz = (lr & 7) << 4;

  for (int k0 = 0; k0 < LK; k0 += 64) {
    if constexpr (A16) {
      const char* aBase = (const char*)(p16 + arow0 * LK);
#pragma unroll
      for (int i = 0; i < 2; ++i) {
        const int chunk = wid * 2 + i;
        const int row = chunk * 8 + srow;
        gload_lds16(aBase + (size_t)row * (LK * 2) + k0 * 2 + scol,
                    (char*)As + chunk * 1024);
      }
    } else {
#pragma unroll
      for (int i = 0; i < 2; ++i) {
        const int u = t + i * 256;
        const int row = u >> 3;
        const int c16 = (u & 7) << 4;
        const int csrc = c16 ^ ((row & 7) << 4);
        const float4* ps = (const float4*)((const char*)attnf +
                                           ((arow0 + row) * LK + k0) * 4 + csrc * 2);
        *(f16x8*)((char*)As + row * 128 + c16) = cvt8(ps[0], ps[1]);
      }
    }
#pragma unroll
    for (int i = 0; i < 4; ++i) {
      const int chunk = wid * 4 + i;
      const int row = chunk * 8 + srow;
      gload_lds16(bBase + (size_t)row * (LK * 2) + k0 * 2 + scol,
                  (char*)Bs + chunk * 1024);
    }
    __syncthreads();
    f16x8 af[2][2], bf[2][4];
#pragma unroll
    for (int h = 0; h < 2; ++h) {
      const int cb = h * 64 + lk * 2;
#pragma unroll
      for (int m = 0; m < 2; ++m)
        af[h][m] = *(const f16x8*)((const char*)As + (wr + m * 16 + lr) * 128 +
                                   (cb ^ swz));
#pragma unroll
      for (int n = 0; n < 4; ++n)
        bf[h][n] = *(const f16x8*)((const char*)Bs + (wc + n * 16 + lr) * 128 +
                                   (cb ^ swz));
    }
#pragma unroll
    for (int h = 0; h < 2; ++h)
#pragma unroll
      for (int m = 0; m < 2; ++m)
#pragma unroll
        for (int n = 0; n < 4; ++n)
          acc[m][n] = __builtin_amdgcn_mfma_f32_16x16x32_f16(bf[h][n], af[h][m],
                                                             acc[m][n], 0, 0, 0);
    __syncthreads();
  }

#pragma unroll
  for (int m = 0; m < 2; ++m) {
    const int row = brow + wr + m * 16 + lr;
    float* rowp = ctx + (size_t)(b * LQ + row) * D + bcol + wc;
#pragma unroll
    for (int n = 0; n < 4; ++n) {
      float4 o;
      o.x = acc[m][n][0]; o.y = acc[m][n][1];
      o.z = acc[m][n][2]; o.w = acc[m][n][3];
      *reinterpret_cast<float4*>(rowp + n * 16 + g4) = o;
    }
  }
}

}  // namespace

extern "C" void kernel_launch(void* const* d_in, const int* in_sizes, int n_in,
                              void* d_out, int out_size, void* d_ws,
                              size_t ws_size, hipStream_t stream) {
  const float* query = (const float*)d_in[0];
  const float* key = (const float*)d_in[1];
  const float* value = (const float*)d_in[2];
  const float* Wq = (const float*)d_in[3];
  const float* bq = (const float*)d_in[4];
  const float* Wk = (const float*)d_in[5];
  const float* bk = (const float*)d_in[6];
  const float* sw = (const float*)d_in[7];

  float* ctx = (float*)d_out;                            // [B,LQ,D]
  float* attn = (float*)d_out + (size_t)BATCH * LQ * D;  // [B,LQ,LK]

  char* ws = (char*)d_ws;
  f16* vt = (f16*)ws;                                    // 8 MiB
  f16* qh = (f16*)(ws + (size_t)(8u << 20));             // 8 MiB
  f16* kh = (f16*)(ws + (size_t)(16u << 20));            // 8 MiB
  float* qnsqp = (float*)(ws + (size_t)(24u << 20));     // 128 KiB
  float* knsqp = qnsqp + (size_t)MQ * 4;                 // 128 KiB
  float* tmax = (float*)(ws + (size_t)(25u << 20));      // 512 KiB
  f16* p16 = (f16*)(ws + (size_t)(26u << 20));           // 32 MiB (raw->norm)
  const size_t ws_needed =
      ((size_t)(26u << 20)) + (size_t)BATCH * LQ * LK * sizeof(f16);
  const bool useA16 = ws_size >= ws_needed;

  prep_kernel<<<1536, 256, 0, stream>>>(query, key, value, Wq, Wk, bq, bk, qh,
                                        kh, qnsqp, knsqp, vt);
  if (useA16) {
    scores_kernel<true><<<1024, 256, 0, stream>>>(qh, kh, qnsqp, knsqp, sw,
                                                  attn, p16, tmax);
    normalize_kernel<true><<<MQ, 256, 0, stream>>>(attn, tmax, p16);
    pv_kernel<true><<<512, 256, 0, stream>>>(attn, p16, vt, ctx);
  } else {
    scores_kernel<false><<<1024, 256, 0, stream>>>(qh, kh, qnsqp, knsqp, sw,
                                                   attn, p16, tmax);
    normalize_kernel<false><<<MQ, 256, 0, stream>>>(attn, tmax, p16);
    pv_kernel<false><<<512, 256, 0, stream>>>(attn, p16, vt, ctx);
  }
}

// Round 7
// 120.110 us; speedup vs baseline: 1.6161x; 1.0460x over previous
//
#include <hip/hip_runtime.h>
#include <cstdint>
#include <cstddef>

namespace {

constexpr int BATCH = 4;
constexpr int LQ = 2048;
constexpr int LK = 2048;
constexpr int D = 512;
constexpr int MQ = BATCH * LQ;

using f16 = _Float16;
typedef _Float16 f16x8 __attribute__((ext_vector_type(8)));
typedef _Float16 f16x4 __attribute__((ext_vector_type(4)));
typedef float f32x4 __attribute__((ext_vector_type(4)));

__device__ __forceinline__ f16x8 cvt8(const float4 a, const float4 b) {
  f16x8 h;
  h[0] = (f16)a.x; h[1] = (f16)a.y; h[2] = (f16)a.z; h[3] = (f16)a.w;
  h[4] = (f16)b.x; h[5] = (f16)b.y; h[6] = (f16)b.z; h[7] = (f16)b.w;
  return h;
}

typedef __attribute__((address_space(1))) const void gas_void;
typedef __attribute__((address_space(3))) void las_void;
__device__ __forceinline__ void gload_lds16(const void* g, void* l) {
  __builtin_amdgcn_global_load_lds((gas_void*)g, (las_void*)l, 16, 0, 0);
}

// ---------------------------------------------------------------------------
// prep: flat-grid fusion of {q-transform, k-transform, v-transpose}.
// ---------------------------------------------------------------------------
__global__ __launch_bounds__(256) void prep_kernel(
    const float* __restrict__ query, const float* __restrict__ keyp,
    const float* __restrict__ value, const float* __restrict__ Wq,
    const float* __restrict__ Wk, const float* __restrict__ bq,
    const float* __restrict__ bk, f16* __restrict__ qh, f16* __restrict__ kh,
    float* __restrict__ qnsqp, float* __restrict__ knsqp,
    f16* __restrict__ vt) {
  __shared__ __align__(16) char smem[21504];
  const int bid0 = blockIdx.x;
  const int t = threadIdx.x;

  if (bid0 >= 512) {
    // ---- v-transpose: 64x64 tile ----
    const int bid = bid0 - 512;
    const int kt = bid & 31;
    const int dt = (bid >> 5) & 7;
    const int b = bid >> 8;
    const int k0 = kt * 64, d0 = dt * 64;
    f16(*T)[72] = reinterpret_cast<f16(*)[72]>(smem);
#pragma unroll
    for (int i = 0; i < 4; ++i) {
      const int u = t + i * 256;
      const int k = u >> 4;
      const int d4 = (u & 15) << 2;
      float4 x = *reinterpret_cast<const float4*>(
          value + (size_t)(b * LK + k0 + k) * D + d0 + d4);
      T[d4 + 0][k] = (f16)x.x;
      T[d4 + 1][k] = (f16)x.y;
      T[d4 + 2][k] = (f16)x.z;
      T[d4 + 3][k] = (f16)x.w;
    }
    __syncthreads();
#pragma unroll
    for (int i = 0; i < 2; ++i) {
      const int u = t + i * 256;
      const int d = u >> 3;
      const int k8 = (u & 7) << 3;
      f16x8 h = *reinterpret_cast<const f16x8*>(&T[d][k8]);
      *reinterpret_cast<f16x8*>(vt + (size_t)(b * D + d0 + d) * LK + k0 + k8) =
          h;
    }
    return;
  }

  // ---- tanh-transform ----
  const int which = bid0 >> 8;
  const float* __restrict__ X = which ? keyp : query;
  const float* __restrict__ W = which ? Wk : Wq;
  const float* __restrict__ bias = which ? bk : bq;
  f16* __restrict__ out = which ? kh : qh;
  float* __restrict__ nsqp = which ? knsqp : qnsqp;

  const int bid = bid0 & 255;
  const int tm = bid & 63;
  const int tn = bid >> 6;
  const int brow = tm * 128, bcol = tn * 128;
  const int lane = t & 63;
  const int wid = t >> 6;
  const int wr = (wid >> 1) * 64, wc = (wid & 1) * 64;
  const int lr = lane & 15;
  const int lk = (lane >> 4) << 3;
  const int g4 = (lane >> 4) << 2;

  f16(*As)[40] = reinterpret_cast<f16(*)[40]>(smem);
  f16(*Bs)[40] = reinterpret_cast<f16(*)[40]>(smem + 10240);
  float(*s_ss)[2] = reinterpret_cast<float(*)[2]>(smem + 20480);

  f32x4 acc[4][4] = {};

  for (int k0 = 0; k0 < D; k0 += 32) {
#pragma unroll
    for (int i = 0; i < 2; ++i) {
      const int u = t + i * 256;
      const int r = u >> 2;
      const int c8 = (u & 3) << 3;
      const float4* pa =
          reinterpret_cast<const float4*>(X + (size_t)(brow + r) * D + k0 + c8);
      *reinterpret_cast<f16x8*>(&As[r][c8]) = cvt8(pa[0], pa[1]);
      const float4* pb =
          reinterpret_cast<const float4*>(W + (size_t)(bcol + r) * D + k0 + c8);
      *reinterpret_cast<f16x8*>(&Bs[r][c8]) = cvt8(pb[0], pb[1]);
    }
    __syncthreads();
    f16x8 af[4], bf[4];
#pragma unroll
    for (int m = 0; m < 4; ++m)
      af[m] = *reinterpret_cast<const f16x8*>(&As[wr + m * 16 + lr][lk]);
#pragma unroll
    for (int n = 0; n < 4; ++n)
      bf[n] = *reinterpret_cast<const f16x8*>(&Bs[wc + n * 16 + lr][lk]);
#pragma unroll
    for (int m = 0; m < 4; ++m)
#pragma unroll
      for (int n = 0; n < 4; ++n)
        acc[m][n] =
            __builtin_amdgcn_mfma_f32_16x16x32_f16(bf[n], af[m], acc[m][n], 0, 0, 0);
    __syncthreads();
  }

  float4 bv[4];
#pragma unroll
  for (int n = 0; n < 4; ++n)
    bv[n] = *reinterpret_cast<const float4*>(&bias[bcol + wc + n * 16 + g4]);

#pragma unroll
  for (int m = 0; m < 4; ++m) {
    const int row = brow + wr + m * 16 + lr;
    float ss = 0.f;
#pragma unroll
    for (int n = 0; n < 4; ++n) {
      float th[4];
#pragma unroll
      for (int r = 0; r < 4; ++r) {
        th[r] = tanhf(acc[m][n][r] + ((const float*)&bv[n])[r]);
        ss = fmaf(th[r], th[r], ss);
      }
      f16x4 h4;
      h4[0] = (f16)th[0]; h4[1] = (f16)th[1];
      h4[2] = (f16)th[2]; h4[3] = (f16)th[3];
      *reinterpret_cast<f16x4*>(out + (size_t)row * D + bcol + wc + n * 16 + g4) =
          h4;
    }
    ss += __shfl_xor(ss, 16);
    ss += __shfl_xor(ss, 32);
    if (lane < 16) s_ss[wr + m * 16 + lr][wid & 1] = ss;
  }
  __syncthreads();
  if (t < 128) nsqp[(size_t)(brow + t) * 4 + tn] = s_ss[t][0] + s_ss[t][1];
}

// ---------------------------------------------------------------------------
// scores: raw s = dot*(w0 + w1*rq*rk) - w2*sqrt(max(qn2+kn2-2dot,0))
// RAW16: f16 raw -> sraw.  else: f32 raw -> attn.
// Epilogue also emits per-(row, col-tile) (max, expsum) -> tstats (float2).
// XCD-swizzled grid (1024 = 8 x 128).
// ---------------------------------------------------------------------------
template <bool RAW16>
__global__ __launch_bounds__(256, 2) void scores_kernel(
    const f16* __restrict__ qh, const f16* __restrict__ kh,
    const float* __restrict__ qnsqp, const float* __restrict__ knsqp,
    const float* __restrict__ sw, float* __restrict__ attn,
    f16* __restrict__ sraw, float2* __restrict__ tstats) {
  const int bid0 = blockIdx.x;
  const int bid = (bid0 & 7) * 128 + (bid0 >> 3);  // XCD-contiguous chunks
  const int tn = bid & 15;
  const int tm = (bid >> 4) & 15;
  const int b = bid >> 8;
  const int brow = tm * 128, bcol = tn * 128;
  const int t = threadIdx.x;
  const int lane = t & 63;
  const int wid = t >> 6;
  const int wr = (wid >> 1) * 64, wc = (wid & 1) * 64;
  const int lr = lane & 15;
  const int lk = (lane >> 4) << 3;
  const int g4 = (lane >> 4) << 2;

  __shared__ f16 As[128 * 64];
  __shared__ f16 Bs[128 * 64];
  __shared__ float s_m[128][2];
  __shared__ float s_l[128][2];

  f32x4 acc[4][4] = {};

  const int srow = lane >> 3;
  const int scol = ((lane & 7) ^ srow) << 4;
  const char* aBase = (const char*)(qh + (size_t)(b * LQ + brow) * D);
  const char* bBase = (const char*)(kh + (size_t)(b * LK + bcol) * D);
  const int swz = (lr & 7) << 4;

  for (int k0 = 0; k0 < D; k0 += 64) {
#pragma unroll
    for (int i = 0; i < 4; ++i) {
      const int chunk = wid * 4 + i;
      const int row = chunk * 8 + srow;
      gload_lds16(aBase + (size_t)row * (D * 2) + k0 * 2 + scol,
                  (char*)As + chunk * 1024);
      gload_lds16(bBase + (size_t)row * (D * 2) + k0 * 2 + scol,
                  (char*)Bs + chunk * 1024);
    }
    __syncthreads();
    f16x8 af[2][4], bf[2][4];
#pragma unroll
    for (int h = 0; h < 2; ++h) {
      const int cb = h * 64 + lk * 2;
#pragma unroll
      for (int m = 0; m < 4; ++m)
        af[h][m] = *(const f16x8*)((const char*)As + (wr + m * 16 + lr) * 128 +
                                   (cb ^ swz));
#pragma unroll
      for (int n = 0; n < 4; ++n)
        bf[h][n] = *(const f16x8*)((const char*)Bs + (wc + n * 16 + lr) * 128 +
                                   (cb ^ swz));
    }
#pragma unroll
    for (int h = 0; h < 2; ++h)
#pragma unroll
      for (int m = 0; m < 4; ++m)
#pragma unroll
        for (int n = 0; n < 4; ++n)
          acc[m][n] = __builtin_amdgcn_mfma_f32_16x16x32_f16(bf[h][n], af[h][m],
                                                             acc[m][n], 0, 0, 0);
    __syncthreads();
  }

  const float s0 = sw[0], s1 = sw[1], s2 = sw[2];
  const float smx = fmaxf(s0, fmaxf(s1, s2));
  float w0 = __expf(s0 - smx), w1 = __expf(s1 - smx), w2 = __expf(s2 - smx);
  const float winv = 1.f / (w0 + w1 + w2);
  w0 *= winv; w1 *= winv; w2 *= winv;

  float qn2_[4], w1rq[4];
#pragma unroll
  for (int m = 0; m < 4; ++m) {
    const float4 qp = *reinterpret_cast<const float4*>(
        &qnsqp[(size_t)(b * LQ + brow + wr + m * 16 + lr) * 4]);
    const float v = (qp.x + qp.y) + (qp.z + qp.w);
    qn2_[m] = v;
    w1rq[m] = w1 * rsqrtf(fmaxf(v, 1e-16f));
  }
  float kn2[4][4], rk[4][4];
#pragma unroll
  for (int n = 0; n < 4; ++n) {
#pragma unroll
    for (int r = 0; r < 4; ++r) {
      const int col = bcol + wc + n * 16 + g4 + r;
      const float4 kp = *reinterpret_cast<const float4*>(
          &knsqp[(size_t)(b * LK + col) * 4]);
      const float v = (kp.x + kp.y) + (kp.z + kp.w);
      kn2[n][r] = v;
      rk[n][r] = rsqrtf(fmaxf(v, 1e-16f));
    }
  }

#pragma unroll
  for (int m = 0; m < 4; ++m) {
    const int row = brow + wr + m * 16 + lr;
    float mx = -3.4e38f;
#pragma unroll
    for (int n = 0; n < 4; ++n) {
      float4 o;
#pragma unroll
      for (int r = 0; r < 4; ++r) {
        const float dot = acc[m][n][r];
        const float qk2 = qn2_[m] + kn2[n][r];
        const float st = sqrtf(fmaxf(qk2 - 2.f * dot, 0.f));
        const float c = fmaf(w1rq[m], rk[n][r], w0);
        const float s = fmaf(dot, c, -w2 * st);
        ((float*)&o)[r] = s;
        acc[m][n][r] = s;  // keep for expsum
        mx = fmaxf(mx, s);
      }
      if constexpr (RAW16) {
        f16x4 h4;
        h4[0] = (f16)o.x; h4[1] = (f16)o.y; h4[2] = (f16)o.z; h4[3] = (f16)o.w;
        *reinterpret_cast<f16x4*>(sraw + (size_t)(b * LQ + row) * LK + bcol +
                                  wc + n * 16 + g4) = h4;
      } else {
        *reinterpret_cast<float4*>(attn + (size_t)(b * LQ + row) * LK + bcol +
                                   wc + n * 16 + g4) = o;
      }
    }
    mx = fmaxf(mx, __shfl_xor(mx, 16));
    mx = fmaxf(mx, __shfl_xor(mx, 32));
    float es = 0.f;
#pragma unroll
    for (int n = 0; n < 4; ++n)
#pragma unroll
      for (int r = 0; r < 4; ++r) es += __expf(acc[m][n][r] - mx);
    es += __shfl_xor(es, 16);
    es += __shfl_xor(es, 32);
    if (lane < 16) {
      s_m[wr + m * 16 + lr][wid & 1] = mx;
      s_l[wr + m * 16 + lr][wid & 1] = es;
    }
  }
  __syncthreads();
  if (t < 128) {
    const float m0 = s_m[t][0], m1 = s_m[t][1];
    const float M = fmaxf(m0, m1);
    const float L = s_l[t][0] * __expf(m0 - M) + s_l[t][1] * __expf(m1 - M);
    tstats[(size_t)(b * LQ + brow + t) * 16 + tn] = make_float2(M, L);
  }
}

// ---------------------------------------------------------------------------
// normalize (fallback only, !useA16): combine tstats -> M, invL; f32 in-place.
// ---------------------------------------------------------------------------
__global__ __launch_bounds__(256) void normalize_kernel(
    float* __restrict__ attn, const float2* __restrict__ tstats) {
  const int row = blockIdx.x;
  const int t = threadIdx.x;
  __shared__ float sM, sI;
  if (t < 16) {
    float2 st = tstats[(size_t)row * 16 + t];
    float M = st.x;
    M = fmaxf(M, __shfl_xor(M, 8));
    M = fmaxf(M, __shfl_xor(M, 4));
    M = fmaxf(M, __shfl_xor(M, 2));
    M = fmaxf(M, __shfl_xor(M, 1));
    float l = st.y * __expf(st.x - M);
    l += __shfl_xor(l, 8);
    l += __shfl_xor(l, 4);
    l += __shfl_xor(l, 2);
    l += __shfl_xor(l, 1);
    if (t == 0) { sM = M; sI = 1.f / l; }
  }
  __syncthreads();
  const float M = sM, invL = sI;
  float* rp = attn + (size_t)row * LK + t * 8;
  float4 v0 = *reinterpret_cast<const float4*>(rp);
  float4 v1 = *reinterpret_cast<const float4*>(rp + 4);
  v0.x = __expf(v0.x - M) * invL; v0.y = __expf(v0.y - M) * invL;
  v0.z = __expf(v0.z - M) * invL; v0.w = __expf(v0.w - M) * invL;
  v1.x = __expf(v1.x - M) * invL; v1.y = __expf(v1.y - M) * invL;
  v1.z = __expf(v1.z - M) * invL; v1.w = __expf(v1.w - M) * invL;
  *reinterpret_cast<float4*>(rp) = v0;
  *reinterpret_cast<float4*>(rp + 4) = v1;
}

// ---------------------------------------------------------------------------
// pv: ctx = p @ v. 64x128 tile, BK=64, grid 512 (XCD-swizzled).
// NORM: prologue combines tstats -> (M, 1/L) per row; A-staging reads RAW f16
// scores, applies exp(s-M)/L on the fly; tn==0 blocks also store the f32
// normalized attn output. else: reads pre-normalized f32 attn.
// ---------------------------------------------------------------------------
template <bool NORM>
__global__ __launch_bounds__(256, 2) void pv_kernel(
    float* __restrict__ attnf, const f16* __restrict__ sraw,
    const f16* __restrict__ vt, const float2* __restrict__ tstats,
    float* __restrict__ ctx) {
  const int bid0 = blockIdx.x;
  const int bid = (bid0 & 7) * 64 + (bid0 >> 3);  // XCD-contiguous chunks
  const int tn = bid & 3;          // D/128
  const int tm = (bid >> 2) & 31;  // LQ/64
  const int b = bid >> 7;
  const int brow = tm * 64, bcol = tn * 128;
  const int t = threadIdx.x;
  const int lane = t & 63;
  const int wid = t >> 6;
  const int wr = (wid >> 1) * 32, wc = (wid & 1) * 64;
  const int lr = lane & 15;
  const int lk = (lane >> 4) << 3;
  const int g4 = (lane >> 4) << 2;

  __shared__ f16 As[64 * 64];   // 8 KB
  __shared__ f16 Bs[128 * 64];  // 16 KB
  __shared__ float sMl[64], sIl[64];

  f32x4 acc[2][4] = {};

  const int srow = lane >> 3;
  const int scol = ((lane & 7) ^ srow) << 4;
  const size_t arow0 = (size_t)(b * LQ + brow);
  const char* bBase = (const char*)(vt + (size_t)(b * D + bcol) * LK);
  const int swz = (lr & 7) << 4;

  float M0 = 0.f, I0 = 0.f, M1 = 0.f, I1 = 0.f;
  if constexpr (NORM) {
    // prologue: 4 threads per row combine the 16 tile stats
    const int prow = t >> 2;          // 0..63
    const int j4 = (t & 3) * 4;
    const float4* tp = reinterpret_cast<const float4*>(
        &tstats[(arow0 + prow) * 16 + j4]);
    const float4 a = tp[0], c = tp[1];
    float m_ = fmaxf(fmaxf(a.x, a.z), fmaxf(c.x, c.z));
    m_ = fmaxf(m_, __shfl_xor(m_, 1));
    m_ = fmaxf(m_, __shfl_xor(m_, 2));
    float l_ = a.y * __expf(a.x - m_) + a.w * __expf(a.z - m_) +
               c.y * __expf(c.x - m_) + c.w * __expf(c.z - m_);
    l_ += __shfl_xor(l_, 1);
    l_ += __shfl_xor(l_, 2);
    if ((t & 3) == 0) {
      sMl[prow] = m_;
      sIl[prow] = 1.f / l_;
    }
    __syncthreads();
    const int r0 = t >> 3;  // staging rows are fixed per thread
    M0 = sMl[r0]; I0 = sIl[r0];
    M1 = sMl[r0 + 32]; I1 = sIl[r0 + 32];
  }

  for (int k0 = 0; k0 < LK; k0 += 64) {
    if constexpr (NORM) {
#pragma unroll
      for (int i = 0; i < 2; ++i) {
        const int u = t + i * 256;
        const int row = u >> 3;
        const int c16 = (u & 7) << 4;
        const int csrc = c16 ^ ((row & 7) << 4);
        const float Mr = i ? M1 : M0;
        const float Ir = i ? I1 : I0;
        f16x8 h = *(const f16x8*)((const char*)sraw +
                                  ((arow0 + row) * LK + k0) * 2 + csrc);
        float4 e0, e1;
        e0.x = __expf((float)h[0] - Mr) * Ir;
        e0.y = __expf((float)h[1] - Mr) * Ir;
        e0.z = __expf((float)h[2] - Mr) * Ir;
        e0.w = __expf((float)h[3] - Mr) * Ir;
        e1.x = __expf((float)h[4] - Mr) * Ir;
        e1.y = __expf((float)h[5] - Mr) * Ir;
        e1.z = __expf((float)h[6] - Mr) * Ir;
        e1.w = __expf((float)h[7] - Mr) * Ir;
        *(f16x8*)((char*)As + row * 128 + c16) = cvt8(e0, e1);
        if (tn == 0) {
          float* op = attnf + (arow0 + row) * LK + k0 + (csrc >> 1);
          *reinterpret_cast<float4*>(op) = e0;
          *reinterpret_cast<float4*>(op + 4) = e1;
        }
      }
    } else {
#pragma unroll
      for (int i = 0; i < 2; ++i) {
        const int u = t + i * 256;
        const int row = u >> 3;
        const int c16 = (u & 7) << 4;
        const int csrc = c16 ^ ((row & 7) << 4);
        const float4* ps = (const float4*)((const char*)attnf +
                                           ((arow0 + row) * LK + k0) * 4 + csrc * 2);
        *(f16x8*)((char*)As + row * 128 + c16) = cvt8(ps[0], ps[1]);
      }
    }
#pragma unroll
    for (int i = 0; i < 4; ++i) {
      const int chunk = wid * 4 + i;
      const int row = chunk * 8 + srow;
      gload_lds16(bBase + (size_t)row * (LK * 2) + k0 * 2 + scol,
                  (char*)Bs + chunk * 1024);
    }
    __syncthreads();
    f16x8 af[2][2], bf[2][4];
#pragma unroll
    for (int h = 0; h < 2; ++h) {
      const int cb = h * 64 + lk * 2;
#pragma unroll
      for (int m = 0; m < 2; ++m)
        af[h][m] = *(const f16x8*)((const char*)As + (wr + m * 16 + lr) * 128 +
                                   (cb ^ swz));
#pragma unroll
      for (int n = 0; n < 4; ++n)
        bf[h][n] = *(const f16x8*)((const char*)Bs + (wc + n * 16 + lr) * 128 +
                                   (cb ^ swz));
    }
#pragma unroll
    for (int h = 0; h < 2; ++h)
#pragma unroll
      for (int m = 0; m < 2; ++m)
#pragma unroll
        for (int n = 0; n < 4; ++n)
          acc[m][n] = __builtin_amdgcn_mfma_f32_16x16x32_f16(bf[h][n], af[h][m],
                                                             acc[m][n], 0, 0, 0);
    __syncthreads();
  }

#pragma unroll
  for (int m = 0; m < 2; ++m) {
    const int row = brow + wr + m * 16 + lr;
    float* rowp = ctx + (size_t)(b * LQ + row) * D + bcol + wc;
#pragma unroll
    for (int n = 0; n < 4; ++n) {
      float4 o;
      o.x = acc[m][n][0]; o.y = acc[m][n][1];
      o.z = acc[m][n][2]; o.w = acc[m][n][3];
      *reinterpret_cast<float4*>(rowp + n * 16 + g4) = o;
    }
  }
}

}  // namespace

extern "C" void kernel_launch(void* const* d_in, const int* in_sizes, int n_in,
                              void* d_out, int out_size, void* d_ws,
                              size_t ws_size, hipStream_t stream) {
  const float* query = (const float*)d_in[0];
  const float* key = (const float*)d_in[1];
  const float* value = (const float*)d_in[2];
  const float* Wq = (const float*)d_in[3];
  const float* bq = (const float*)d_in[4];
  const float* Wk = (const float*)d_in[5];
  const float* bk = (const float*)d_in[6];
  const float* sw = (const float*)d_in[7];

  float* ctx = (float*)d_out;                            // [B,LQ,D]
  float* attn = (float*)d_out + (size_t)BATCH * LQ * D;  // [B,LQ,LK]

  char* ws = (char*)d_ws;
  f16* vt = (f16*)ws;                                    // 8 MiB
  f16* qh = (f16*)(ws + (size_t)(8u << 20));             // 8 MiB
  f16* kh = (f16*)(ws + (size_t)(16u << 20));            // 8 MiB
  float* qnsqp = (float*)(ws + (size_t)(24u << 20));     // 128 KiB
  float* knsqp = qnsqp + (size_t)MQ * 4;                 // 128 KiB
  float2* tstats = (float2*)(ws + (size_t)(25u << 20));  // 1 MiB
  f16* sraw = (f16*)(ws + (size_t)(26u << 20));          // 32 MiB
  const size_t ws_needed =
      ((size_t)(26u << 20)) + (size_t)BATCH * LQ * LK * sizeof(f16);
  const bool useA16 = ws_size >= ws_needed;

  prep_kernel<<<1536, 256, 0, stream>>>(query, key, value, Wq, Wk, bq, bk, qh,
                                        kh, qnsqp, knsqp, vt);
  if (useA16) {
    scores_kernel<true><<<1024, 256, 0, stream>>>(qh, kh, qnsqp, knsqp, sw,
                                                  attn, sraw, tstats);
    pv_kernel<true><<<512, 256, 0, stream>>>(attn, sraw, vt, tstats, ctx);
  } else {
    scores_kernel<false><<<1024, 256, 0, stream>>>(qh, kh, qnsqp, knsqp, sw,
                                                   attn, sraw, tstats);
    normalize_kernel<<<MQ, 256, 0, stream>>>(attn, tstats);
    pv_kernel<false><<<512, 256, 0, stream>>>(attn, sraw, vt, tstats, ctx);
  }
}

// Round 8
// 108.375 us; speedup vs baseline: 1.7911x; 1.1083x over previous
//
#include <hip/hip_runtime.h>
#include <cstdint>
#include <cstddef>

namespace {

constexpr int BATCH = 4;
constexpr int LQ = 2048;
constexpr int LK = 2048;
constexpr int D = 512;
constexpr int MQ = BATCH * LQ;

using f16 = _Float16;
typedef _Float16 f16x8 __attribute__((ext_vector_type(8)));
typedef _Float16 f16x4 __attribute__((ext_vector_type(4)));
typedef float f32x4 __attribute__((ext_vector_type(4)));

__device__ __forceinline__ f16x8 cvt8(const float4 a, const float4 b) {
  f16x8 h;
  h[0] = (f16)a.x; h[1] = (f16)a.y; h[2] = (f16)a.z; h[3] = (f16)a.w;
  h[4] = (f16)b.x; h[5] = (f16)b.y; h[6] = (f16)b.z; h[7] = (f16)b.w;
  return h;
}

typedef __attribute__((address_space(1))) const void gas_void;
typedef __attribute__((address_space(3))) void las_void;
__device__ __forceinline__ void gload_lds16(const void* g, void* l) {
  __builtin_amdgcn_global_load_lds((gas_void*)g, (las_void*)l, 16, 0, 0);
}

// ---------------------------------------------------------------------------
// prep: flat-grid fusion of {q-transform, k-transform, v-transpose}.
// ---------------------------------------------------------------------------
__global__ __launch_bounds__(256) void prep_kernel(
    const float* __restrict__ query, const float* __restrict__ keyp,
    const float* __restrict__ value, const float* __restrict__ Wq,
    const float* __restrict__ Wk, const float* __restrict__ bq,
    const float* __restrict__ bk, f16* __restrict__ qh, f16* __restrict__ kh,
    float* __restrict__ qnsqp, float* __restrict__ knsqp,
    f16* __restrict__ vt) {
  __shared__ __align__(16) char smem[21504];
  const int bid0 = blockIdx.x;
  const int t = threadIdx.x;

  if (bid0 >= 512) {
    // ---- v-transpose: 64x64 tile ----
    const int bid = bid0 - 512;
    const int kt = bid & 31;
    const int dt = (bid >> 5) & 7;
    const int b = bid >> 8;
    const int k0 = kt * 64, d0 = dt * 64;
    f16(*T)[72] = reinterpret_cast<f16(*)[72]>(smem);
#pragma unroll
    for (int i = 0; i < 4; ++i) {
      const int u = t + i * 256;
      const int k = u >> 4;
      const int d4 = (u & 15) << 2;
      float4 x = *reinterpret_cast<const float4*>(
          value + (size_t)(b * LK + k0 + k) * D + d0 + d4);
      T[d4 + 0][k] = (f16)x.x;
      T[d4 + 1][k] = (f16)x.y;
      T[d4 + 2][k] = (f16)x.z;
      T[d4 + 3][k] = (f16)x.w;
    }
    __syncthreads();
#pragma unroll
    for (int i = 0; i < 2; ++i) {
      const int u = t + i * 256;
      const int d = u >> 3;
      const int k8 = (u & 7) << 3;
      f16x8 h = *reinterpret_cast<const f16x8*>(&T[d][k8]);
      *reinterpret_cast<f16x8*>(vt + (size_t)(b * D + d0 + d) * LK + k0 + k8) =
          h;
    }
    return;
  }

  // ---- tanh-transform ----
  const int which = bid0 >> 8;
  const float* __restrict__ X = which ? keyp : query;
  const float* __restrict__ W = which ? Wk : Wq;
  const float* __restrict__ bias = which ? bk : bq;
  f16* __restrict__ out = which ? kh : qh;
  float* __restrict__ nsqp = which ? knsqp : qnsqp;

  const int bid = bid0 & 255;
  const int tm = bid & 63;
  const int tn = bid >> 6;
  const int brow = tm * 128, bcol = tn * 128;
  const int lane = t & 63;
  const int wid = t >> 6;
  const int wr = (wid >> 1) * 64, wc = (wid & 1) * 64;
  const int lr = lane & 15;
  const int lk = (lane >> 4) << 3;
  const int g4 = (lane >> 4) << 2;

  f16(*As)[40] = reinterpret_cast<f16(*)[40]>(smem);
  f16(*Bs)[40] = reinterpret_cast<f16(*)[40]>(smem + 10240);
  float(*s_ss)[2] = reinterpret_cast<float(*)[2]>(smem + 20480);

  f32x4 acc[4][4] = {};

  for (int k0 = 0; k0 < D; k0 += 32) {
#pragma unroll
    for (int i = 0; i < 2; ++i) {
      const int u = t + i * 256;
      const int r = u >> 2;
      const int c8 = (u & 3) << 3;
      const float4* pa =
          reinterpret_cast<const float4*>(X + (size_t)(brow + r) * D + k0 + c8);
      *reinterpret_cast<f16x8*>(&As[r][c8]) = cvt8(pa[0], pa[1]);
      const float4* pb =
          reinterpret_cast<const float4*>(W + (size_t)(bcol + r) * D + k0 + c8);
      *reinterpret_cast<f16x8*>(&Bs[r][c8]) = cvt8(pb[0], pb[1]);
    }
    __syncthreads();
    f16x8 af[4], bf[4];
#pragma unroll
    for (int m = 0; m < 4; ++m)
      af[m] = *reinterpret_cast<const f16x8*>(&As[wr + m * 16 + lr][lk]);
#pragma unroll
    for (int n = 0; n < 4; ++n)
      bf[n] = *reinterpret_cast<const f16x8*>(&Bs[wc + n * 16 + lr][lk]);
#pragma unroll
    for (int m = 0; m < 4; ++m)
#pragma unroll
      for (int n = 0; n < 4; ++n)
        acc[m][n] =
            __builtin_amdgcn_mfma_f32_16x16x32_f16(bf[n], af[m], acc[m][n], 0, 0, 0);
    __syncthreads();
  }

  float4 bv[4];
#pragma unroll
  for (int n = 0; n < 4; ++n)
    bv[n] = *reinterpret_cast<const float4*>(&bias[bcol + wc + n * 16 + g4]);

#pragma unroll
  for (int m = 0; m < 4; ++m) {
    const int row = brow + wr + m * 16 + lr;
    float ss = 0.f;
#pragma unroll
    for (int n = 0; n < 4; ++n) {
      float th[4];
#pragma unroll
      for (int r = 0; r < 4; ++r) {
        th[r] = tanhf(acc[m][n][r] + ((const float*)&bv[n])[r]);
        ss = fmaf(th[r], th[r], ss);
      }
      f16x4 h4;
      h4[0] = (f16)th[0]; h4[1] = (f16)th[1];
      h4[2] = (f16)th[2]; h4[3] = (f16)th[3];
      *reinterpret_cast<f16x4*>(out + (size_t)row * D + bcol + wc + n * 16 + g4) =
          h4;
    }
    ss += __shfl_xor(ss, 16);
    ss += __shfl_xor(ss, 32);
    if (lane < 16) s_ss[wr + m * 16 + lr][wid & 1] = ss;
  }
  __syncthreads();
  if (t < 128) nsqp[(size_t)(brow + t) * 4 + tn] = s_ss[t][0] + s_ss[t][1];
}

// ---------------------------------------------------------------------------
// scores: raw s = dot*(w0 + w1*rq*rk) - w2*sqrt(max(qn2+kn2-2dot,0))
// RAW16: f16 raw -> sraw.  else: f32 raw -> attn.
// Epilogue also emits per-(row, col-tile) (max, expsum) -> tstats (float2).
// XCD-swizzled grid (1024 = 8 x 128).
// ---------------------------------------------------------------------------
template <bool RAW16>
__global__ __launch_bounds__(256, 2) void scores_kernel(
    const f16* __restrict__ qh, const f16* __restrict__ kh,
    const float* __restrict__ qnsqp, const float* __restrict__ knsqp,
    const float* __restrict__ sw, float* __restrict__ attn,
    f16* __restrict__ sraw, float2* __restrict__ tstats) {
  const int bid0 = blockIdx.x;
  const int bid = (bid0 & 7) * 128 + (bid0 >> 3);  // XCD-contiguous chunks
  const int tn = bid & 15;
  const int tm = (bid >> 4) & 15;
  const int b = bid >> 8;
  const int brow = tm * 128, bcol = tn * 128;
  const int t = threadIdx.x;
  const int lane = t & 63;
  const int wid = t >> 6;
  const int wr = (wid >> 1) * 64, wc = (wid & 1) * 64;
  const int lr = lane & 15;
  const int lk = (lane >> 4) << 3;
  const int g4 = (lane >> 4) << 2;

  __shared__ f16 As[128 * 64];
  __shared__ f16 Bs[128 * 64];
  __shared__ float s_m[128][2];
  __shared__ float s_l[128][2];

  f32x4 acc[4][4] = {};

  const int srow = lane >> 3;
  const int scol = ((lane & 7) ^ srow) << 4;
  const char* aBase = (const char*)(qh + (size_t)(b * LQ + brow) * D);
  const char* bBase = (const char*)(kh + (size_t)(b * LK + bcol) * D);
  const int swz = (lr & 7) << 4;

  for (int k0 = 0; k0 < D; k0 += 64) {
#pragma unroll
    for (int i = 0; i < 4; ++i) {
      const int chunk = wid * 4 + i;
      const int row = chunk * 8 + srow;
      gload_lds16(aBase + (size_t)row * (D * 2) + k0 * 2 + scol,
                  (char*)As + chunk * 1024);
      gload_lds16(bBase + (size_t)row * (D * 2) + k0 * 2 + scol,
                  (char*)Bs + chunk * 1024);
    }
    __syncthreads();
    f16x8 af[2][4], bf[2][4];
#pragma unroll
    for (int h = 0; h < 2; ++h) {
      const int cb = h * 64 + lk * 2;
#pragma unroll
      for (int m = 0; m < 4; ++m)
        af[h][m] = *(const f16x8*)((const char*)As + (wr + m * 16 + lr) * 128 +
                                   (cb ^ swz));
#pragma unroll
      for (int n = 0; n < 4; ++n)
        bf[h][n] = *(const f16x8*)((const char*)Bs + (wc + n * 16 + lr) * 128 +
                                   (cb ^ swz));
    }
#pragma unroll
    for (int h = 0; h < 2; ++h)
#pragma unroll
      for (int m = 0; m < 4; ++m)
#pragma unroll
        for (int n = 0; n < 4; ++n)
          acc[m][n] = __builtin_amdgcn_mfma_f32_16x16x32_f16(bf[h][n], af[h][m],
                                                             acc[m][n], 0, 0, 0);
    __syncthreads();
  }

  const float s0 = sw[0], s1 = sw[1], s2 = sw[2];
  const float smx = fmaxf(s0, fmaxf(s1, s2));
  float w0 = __expf(s0 - smx), w1 = __expf(s1 - smx), w2 = __expf(s2 - smx);
  const float winv = 1.f / (w0 + w1 + w2);
  w0 *= winv; w1 *= winv; w2 *= winv;

  float qn2_[4], w1rq[4];
#pragma unroll
  for (int m = 0; m < 4; ++m) {
    const float4 qp = *reinterpret_cast<const float4*>(
        &qnsqp[(size_t)(b * LQ + brow + wr + m * 16 + lr) * 4]);
    const float v = (qp.x + qp.y) + (qp.z + qp.w);
    qn2_[m] = v;
    w1rq[m] = w1 * rsqrtf(fmaxf(v, 1e-16f));
  }
  float kn2[4][4], rk[4][4];
#pragma unroll
  for (int n = 0; n < 4; ++n) {
#pragma unroll
    for (int r = 0; r < 4; ++r) {
      const int col = bcol + wc + n * 16 + g4 + r;
      const float4 kp = *reinterpret_cast<const float4*>(
          &knsqp[(size_t)(b * LK + col) * 4]);
      const float v = (kp.x + kp.y) + (kp.z + kp.w);
      kn2[n][r] = v;
      rk[n][r] = rsqrtf(fmaxf(v, 1e-16f));
    }
  }

#pragma unroll
  for (int m = 0; m < 4; ++m) {
    const int row = brow + wr + m * 16 + lr;
    float mx = -3.4e38f;
#pragma unroll
    for (int n = 0; n < 4; ++n) {
      float4 o;
#pragma unroll
      for (int r = 0; r < 4; ++r) {
        const float dot = acc[m][n][r];
        const float qk2 = qn2_[m] + kn2[n][r];
        const float st = sqrtf(fmaxf(qk2 - 2.f * dot, 0.f));
        const float c = fmaf(w1rq[m], rk[n][r], w0);
        const float s = fmaf(dot, c, -w2 * st);
        ((float*)&o)[r] = s;
        acc[m][n][r] = s;  // keep for expsum
        mx = fmaxf(mx, s);
      }
      if constexpr (RAW16) {
        f16x4 h4;
        h4[0] = (f16)o.x; h4[1] = (f16)o.y; h4[2] = (f16)o.z; h4[3] = (f16)o.w;
        *reinterpret_cast<f16x4*>(sraw + (size_t)(b * LQ + row) * LK + bcol +
                                  wc + n * 16 + g4) = h4;
      } else {
        *reinterpret_cast<float4*>(attn + (size_t)(b * LQ + row) * LK + bcol +
                                   wc + n * 16 + g4) = o;
      }
    }
    mx = fmaxf(mx, __shfl_xor(mx, 16));
    mx = fmaxf(mx, __shfl_xor(mx, 32));
    float es = 0.f;
#pragma unroll
    for (int n = 0; n < 4; ++n)
#pragma unroll
      for (int r = 0; r < 4; ++r) es += __expf(acc[m][n][r] - mx);
    es += __shfl_xor(es, 16);
    es += __shfl_xor(es, 32);
    if (lane < 16) {
      s_m[wr + m * 16 + lr][wid & 1] = mx;
      s_l[wr + m * 16 + lr][wid & 1] = es;
    }
  }
  __syncthreads();
  if (t < 128) {
    const float m0 = s_m[t][0], m1 = s_m[t][1];
    const float M = fmaxf(m0, m1);
    const float L = s_l[t][0] * __expf(m0 - M) + s_l[t][1] * __expf(m1 - M);
    tstats[(size_t)(b * LQ + brow + t) * 16 + tn] = make_float2(M, L);
  }
}

// ---------------------------------------------------------------------------
// normalize (fallback only, !useA16): combine tstats -> M, invL; f32 in-place.
// ---------------------------------------------------------------------------
__global__ __launch_bounds__(256) void normalize_kernel(
    float* __restrict__ attn, const float2* __restrict__ tstats) {
  const int row = blockIdx.x;
  const int t = threadIdx.x;
  __shared__ float sM, sI;
  if (t < 16) {
    float2 st = tstats[(size_t)row * 16 + t];
    float M = st.x;
    M = fmaxf(M, __shfl_xor(M, 8));
    M = fmaxf(M, __shfl_xor(M, 4));
    M = fmaxf(M, __shfl_xor(M, 2));
    M = fmaxf(M, __shfl_xor(M, 1));
    float l = st.y * __expf(st.x - M);
    l += __shfl_xor(l, 8);
    l += __shfl_xor(l, 4);
    l += __shfl_xor(l, 2);
    l += __shfl_xor(l, 1);
    if (t == 0) { sM = M; sI = 1.f / l; }
  }
  __syncthreads();
  const float M = sM, invL = sI;
  float* rp = attn + (size_t)row * LK + t * 8;
  float4 v0 = *reinterpret_cast<const float4*>(rp);
  float4 v1 = *reinterpret_cast<const float4*>(rp + 4);
  v0.x = __expf(v0.x - M) * invL; v0.y = __expf(v0.y - M) * invL;
  v0.z = __expf(v0.z - M) * invL; v0.w = __expf(v0.w - M) * invL;
  v1.x = __expf(v1.x - M) * invL; v1.y = __expf(v1.y - M) * invL;
  v1.z = __expf(v1.z - M) * invL; v1.w = __expf(v1.w - M) * invL;
  *reinterpret_cast<float4*>(rp) = v0;
  *reinterpret_cast<float4*>(rp + 4) = v1;
}

// ---------------------------------------------------------------------------
// pv: ctx = p @ v. 32x128 tile, BK=64, grid 1024 (4 blocks/CU, XCD-swizzled).
// NORM: combine tstats -> (M,1/L); A-staging reads RAW f16 scores with a
// one-step register prefetch, applies exp on the fly, and block tn stores the
// f32 normalized attn for its column-quarter ((k0>>9)==tn -> balanced).
// ---------------------------------------------------------------------------
template <bool NORM>
__global__ __launch_bounds__(256, 2) void pv_kernel(
    float* __restrict__ attnf, const f16* __restrict__ sraw,
    const f16* __restrict__ vt, const float2* __restrict__ tstats,
    float* __restrict__ ctx) {
  const int bid0 = blockIdx.x;
  const int bid = (bid0 & 7) * 128 + (bid0 >> 3);  // 1024 = 8 x 128
  const int tn = bid & 3;          // D/128
  const int tm = (bid >> 2) & 63;  // LQ/32
  const int b = bid >> 8;
  const int brow = tm * 32, bcol = tn * 128;
  const int t = threadIdx.x;
  const int lane = t & 63;
  const int wid = t >> 6;
  const int wr = (wid >> 1) * 16, wc = (wid & 1) * 64;
  const int lr = lane & 15;
  const int lk = (lane >> 4) << 3;
  const int g4 = (lane >> 4) << 2;

  __shared__ f16 As[32 * 64];   // 4 KB
  __shared__ f16 Bs[128 * 64];  // 16 KB
  __shared__ float sMl[32], sIl[32];

  f32x4 acc[4] = {};

  const int srow = lane >> 3;
  const int scol = ((lane & 7) ^ srow) << 4;
  const size_t arow0 = (size_t)(b * LQ + brow);
  const char* bBase = (const char*)(vt + (size_t)(b * D + bcol) * LK);
  const int swz = (lr & 7) << 4;

  // A staging geometry: one f16x8 per thread per K-step.
  const int arow = t >> 3;              // 0..31
  const int c16 = (t & 7) << 4;         // dest byte col in As row
  const int csrc = c16 ^ ((arow & 7) << 4);  // swizzled source byte col
  const char* aRow =
      (const char*)sraw + (arow0 + arow) * (size_t)LK * 2 + csrc;
  float Mr = 0.f, Ir = 0.f;

  if constexpr (NORM) {
    if (t < 128) {
      const int prow = t >> 2;  // 0..31
      const int j4 = (t & 3) * 4;
      const float4* tp =
          reinterpret_cast<const float4*>(&tstats[(arow0 + prow) * 16 + j4]);
      const float4 a = tp[0], c = tp[1];
      float m_ = fmaxf(fmaxf(a.x, a.z), fmaxf(c.x, c.z));
      m_ = fmaxf(m_, __shfl_xor(m_, 1));
      m_ = fmaxf(m_, __shfl_xor(m_, 2));
      float l_ = a.y * __expf(a.x - m_) + a.w * __expf(a.z - m_) +
                 c.y * __expf(c.x - m_) + c.w * __expf(c.z - m_);
      l_ += __shfl_xor(l_, 1);
      l_ += __shfl_xor(l_, 2);
      if ((t & 3) == 0) {
        sMl[prow] = m_;
        sIl[prow] = 1.f / l_;
      }
    }
    __syncthreads();
    Mr = sMl[arow];
    Ir = sIl[arow];
  }

  f16x8 hcur;
  if constexpr (NORM) hcur = *(const f16x8*)(aRow);

  for (int k0 = 0; k0 < LK; k0 += 64) {
    // B staging: async, issued first so its latency spans the A processing.
#pragma unroll
    for (int i = 0; i < 4; ++i) {
      const int chunk = wid * 4 + i;
      const int row = chunk * 8 + srow;
      gload_lds16(bBase + (size_t)row * (LK * 2) + k0 * 2 + scol,
                  (char*)Bs + chunk * 1024);
    }
    if constexpr (NORM) {
      // prefetch next K-step's raw scores (rides the same vmcnt drain as B)
      f16x8 hnext;
      if (k0 + 64 < LK) hnext = *(const f16x8*)(aRow + (k0 + 64) * 2);
      float4 e0, e1;
      e0.x = __expf((float)hcur[0] - Mr) * Ir;
      e0.y = __expf((float)hcur[1] - Mr) * Ir;
      e0.z = __expf((float)hcur[2] - Mr) * Ir;
      e0.w = __expf((float)hcur[3] - Mr) * Ir;
      e1.x = __expf((float)hcur[4] - Mr) * Ir;
      e1.y = __expf((float)hcur[5] - Mr) * Ir;
      e1.z = __expf((float)hcur[6] - Mr) * Ir;
      e1.w = __expf((float)hcur[7] - Mr) * Ir;
      *(f16x8*)((char*)As + arow * 128 + c16) = cvt8(e0, e1);
      if ((k0 >> 9) == tn) {  // this block's column-quarter: balanced f32 out
        float* op = attnf + (arow0 + arow) * LK + k0 + (csrc >> 1);
        *reinterpret_cast<float4*>(op) = e0;
        *reinterpret_cast<float4*>(op + 4) = e1;
      }
      hcur = hnext;
    } else {
      const int u = t;
      const int row = u >> 3;
      const float4* ps = (const float4*)((const char*)attnf +
                                         ((arow0 + row) * LK + k0) * 4 +
                                         csrc * 2);
      *(f16x8*)((char*)As + row * 128 + c16) = cvt8(ps[0], ps[1]);
    }
    __syncthreads();
    f16x8 af[2], bf[2][4];
#pragma unroll
    for (int h = 0; h < 2; ++h) {
      const int cb = h * 64 + lk * 2;
      af[h] = *(const f16x8*)((const char*)As + (wr + lr) * 128 + (cb ^ swz));
#pragma unroll
      for (int n = 0; n < 4; ++n)
        bf[h][n] = *(const f16x8*)((const char*)Bs + (wc + n * 16 + lr) * 128 +
                                   (cb ^ swz));
    }
#pragma unroll
    for (int h = 0; h < 2; ++h)
#pragma unroll
      for (int n = 0; n < 4; ++n)
        acc[n] = __builtin_amdgcn_mfma_f32_16x16x32_f16(bf[h][n], af[h],
                                                        acc[n], 0, 0, 0);
    __syncthreads();
  }

  const int row = brow + wr + lr;
  float* rowp = ctx + (size_t)(b * LQ + row) * D + bcol + wc;
#pragma unroll
  for (int n = 0; n < 4; ++n) {
    float4 o;
    o.x = acc[n][0]; o.y = acc[n][1];
    o.z = acc[n][2]; o.w = acc[n][3];
    *reinterpret_cast<float4*>(rowp + n * 16 + g4) = o;
  }
}

}  // namespace

extern "C" void kernel_launch(void* const* d_in, const int* in_sizes, int n_in,
                              void* d_out, int out_size, void* d_ws,
                              size_t ws_size, hipStream_t stream) {
  const float* query = (const float*)d_in[0];
  const float* key = (const float*)d_in[1];
  const float* value = (const float*)d_in[2];
  const float* Wq = (const float*)d_in[3];
  const float* bq = (const float*)d_in[4];
  const float* Wk = (const float*)d_in[5];
  const float* bk = (const float*)d_in[6];
  const float* sw = (const float*)d_in[7];

  float* ctx = (float*)d_out;                            // [B,LQ,D]
  float* attn = (float*)d_out + (size_t)BATCH * LQ * D;  // [B,LQ,LK]

  char* ws = (char*)d_ws;
  f16* vt = (f16*)ws;                                    // 8 MiB
  f16* qh = (f16*)(ws + (size_t)(8u << 20));             // 8 MiB
  f16* kh = (f16*)(ws + (size_t)(16u << 20));            // 8 MiB
  float* qnsqp = (float*)(ws + (size_t)(24u << 20));     // 128 KiB
  float* knsqp = qnsqp + (size_t)MQ * 4;                 // 128 KiB
  float2* tstats = (float2*)(ws + (size_t)(25u << 20));  // 1 MiB
  f16* sraw = (f16*)(ws + (size_t)(26u << 20));          // 32 MiB
  const size_t ws_needed =
      ((size_t)(26u << 20)) + (size_t)BATCH * LQ * LK * sizeof(f16);
  const bool useA16 = ws_size >= ws_needed;

  prep_kernel<<<1536, 256, 0, stream>>>(query, key, value, Wq, Wk, bq, bk, qh,
                                        kh, qnsqp, knsqp, vt);
  if (useA16) {
    scores_kernel<true><<<1024, 256, 0, stream>>>(qh, kh, qnsqp, knsqp, sw,
                                                  attn, sraw, tstats);
    pv_kernel<true><<<1024, 256, 0, stream>>>(attn, sraw, vt, tstats, ctx);
  } else {
    scores_kernel<false><<<1024, 256, 0, stream>>>(qh, kh, qnsqp, knsqp, sw,
                                                   attn, sraw, tstats);
    normalize_kernel<<<MQ, 256, 0, stream>>>(attn, tstats);
    pv_kernel<false><<<1024, 256, 0, stream>>>(attn, sraw, vt, tstats, ctx);
  }
}

// Round 9
// 106.035 us; speedup vs baseline: 1.8306x; 1.0221x over previous
//
#include <hip/hip_runtime.h>
#include <cstdint>
#include <cstddef>

namespace {

constexpr int BATCH = 4;
constexpr int LQ = 2048;
constexpr int LK = 2048;
constexpr int D = 512;
constexpr int MQ = BATCH * LQ;

using f16 = _Float16;
typedef _Float16 f16x8 __attribute__((ext_vector_type(8)));
typedef _Float16 f16x4 __attribute__((ext_vector_type(4)));
typedef float f32x4 __attribute__((ext_vector_type(4)));

__device__ __forceinline__ f16x8 cvt8(const float4 a, const float4 b) {
  f16x8 h;
  h[0] = (f16)a.x; h[1] = (f16)a.y; h[2] = (f16)a.z; h[3] = (f16)a.w;
  h[4] = (f16)b.x; h[5] = (f16)b.y; h[6] = (f16)b.z; h[7] = (f16)b.w;
  return h;
}

typedef __attribute__((address_space(1))) const void gas_void;
typedef __attribute__((address_space(3))) void las_void;
__device__ __forceinline__ void gload_lds16(const void* g, void* l) {
  __builtin_amdgcn_global_load_lds((gas_void*)g, (las_void*)l, 16, 0, 0);
}

// ---------------------------------------------------------------------------
// prep: flat-grid fusion of {q-transform, k-transform, v-transpose}.
// ---------------------------------------------------------------------------
__global__ __launch_bounds__(256) void prep_kernel(
    const float* __restrict__ query, const float* __restrict__ keyp,
    const float* __restrict__ value, const float* __restrict__ Wq,
    const float* __restrict__ Wk, const float* __restrict__ bq,
    const float* __restrict__ bk, f16* __restrict__ qh, f16* __restrict__ kh,
    float* __restrict__ qnsqp, float* __restrict__ knsqp,
    f16* __restrict__ vt) {
  __shared__ __align__(16) char smem[21504];
  const int bid0 = blockIdx.x;
  const int t = threadIdx.x;

  if (bid0 >= 512) {
    // ---- v-transpose: 64x64 tile ----
    const int bid = bid0 - 512;
    const int kt = bid & 31;
    const int dt = (bid >> 5) & 7;
    const int b = bid >> 8;
    const int k0 = kt * 64, d0 = dt * 64;
    f16(*T)[72] = reinterpret_cast<f16(*)[72]>(smem);
#pragma unroll
    for (int i = 0; i < 4; ++i) {
      const int u = t + i * 256;
      const int k = u >> 4;
      const int d4 = (u & 15) << 2;
      float4 x = *reinterpret_cast<const float4*>(
          value + (size_t)(b * LK + k0 + k) * D + d0 + d4);
      T[d4 + 0][k] = (f16)x.x;
      T[d4 + 1][k] = (f16)x.y;
      T[d4 + 2][k] = (f16)x.z;
      T[d4 + 3][k] = (f16)x.w;
    }
    __syncthreads();
#pragma unroll
    for (int i = 0; i < 2; ++i) {
      const int u = t + i * 256;
      const int d = u >> 3;
      const int k8 = (u & 7) << 3;
      f16x8 h = *reinterpret_cast<const f16x8*>(&T[d][k8]);
      *reinterpret_cast<f16x8*>(vt + (size_t)(b * D + d0 + d) * LK + k0 + k8) =
          h;
    }
    return;
  }

  // ---- tanh-transform ----
  const int which = bid0 >> 8;
  const float* __restrict__ X = which ? keyp : query;
  const float* __restrict__ W = which ? Wk : Wq;
  const float* __restrict__ bias = which ? bk : bq;
  f16* __restrict__ out = which ? kh : qh;
  float* __restrict__ nsqp = which ? knsqp : qnsqp;

  const int bid = bid0 & 255;
  const int tm = bid & 63;
  const int tn = bid >> 6;
  const int brow = tm * 128, bcol = tn * 128;
  const int lane = t & 63;
  const int wid = t >> 6;
  const int wr = (wid >> 1) * 64, wc = (wid & 1) * 64;
  const int lr = lane & 15;
  const int lk = (lane >> 4) << 3;
  const int g4 = (lane >> 4) << 2;

  f16(*As)[40] = reinterpret_cast<f16(*)[40]>(smem);
  f16(*Bs)[40] = reinterpret_cast<f16(*)[40]>(smem + 10240);
  float(*s_ss)[2] = reinterpret_cast<float(*)[2]>(smem + 20480);

  f32x4 acc[4][4] = {};

  for (int k0 = 0; k0 < D; k0 += 32) {
#pragma unroll
    for (int i = 0; i < 2; ++i) {
      const int u = t + i * 256;
      const int r = u >> 2;
      const int c8 = (u & 3) << 3;
      const float4* pa =
          reinterpret_cast<const float4*>(X + (size_t)(brow + r) * D + k0 + c8);
      *reinterpret_cast<f16x8*>(&As[r][c8]) = cvt8(pa[0], pa[1]);
      const float4* pb =
          reinterpret_cast<const float4*>(W + (size_t)(bcol + r) * D + k0 + c8);
      *reinterpret_cast<f16x8*>(&Bs[r][c8]) = cvt8(pb[0], pb[1]);
    }
    __syncthreads();
    f16x8 af[4], bf[4];
#pragma unroll
    for (int m = 0; m < 4; ++m)
      af[m] = *reinterpret_cast<const f16x8*>(&As[wr + m * 16 + lr][lk]);
#pragma unroll
    for (int n = 0; n < 4; ++n)
      bf[n] = *reinterpret_cast<const f16x8*>(&Bs[wc + n * 16 + lr][lk]);
#pragma unroll
    for (int m = 0; m < 4; ++m)
#pragma unroll
      for (int n = 0; n < 4; ++n)
        acc[m][n] =
            __builtin_amdgcn_mfma_f32_16x16x32_f16(bf[n], af[m], acc[m][n], 0, 0, 0);
    __syncthreads();
  }

  float4 bv[4];
#pragma unroll
  for (int n = 0; n < 4; ++n)
    bv[n] = *reinterpret_cast<const float4*>(&bias[bcol + wc + n * 16 + g4]);

#pragma unroll
  for (int m = 0; m < 4; ++m) {
    const int row = brow + wr + m * 16 + lr;
    float ss = 0.f;
#pragma unroll
    for (int n = 0; n < 4; ++n) {
      float th[4];
#pragma unroll
      for (int r = 0; r < 4; ++r) {
        th[r] = tanhf(acc[m][n][r] + ((const float*)&bv[n])[r]);
        ss = fmaf(th[r], th[r], ss);
      }
      f16x4 h4;
      h4[0] = (f16)th[0]; h4[1] = (f16)th[1];
      h4[2] = (f16)th[2]; h4[3] = (f16)th[3];
      *reinterpret_cast<f16x4*>(out + (size_t)row * D + bcol + wc + n * 16 + g4) =
          h4;
    }
    ss += __shfl_xor(ss, 16);
    ss += __shfl_xor(ss, 32);
    if (lane < 16) s_ss[wr + m * 16 + lr][wid & 1] = ss;
  }
  __syncthreads();
  if (t < 128) nsqp[(size_t)(brow + t) * 4 + tn] = s_ss[t][0] + s_ss[t][1];
}

// ---------------------------------------------------------------------------
// scores: s = dot*(w0 + w1*rq*rk) - w2*sqrt(max(qn2+kn2-2dot,0))
// RAW16: store e = (f16)exp(s - M_tile) -> sraw  (exp was needed for the
//        expsum anyway -> free), tstats[row][tile] = (M_tile, expsum).
// else:  store raw f32 s -> attn, tstats same.
// XCD-swizzled grid (1024 = 8 x 128).
// ---------------------------------------------------------------------------
template <bool RAW16>
__global__ __launch_bounds__(256, 4) void scores_kernel(
    const f16* __restrict__ qh, const f16* __restrict__ kh,
    const float* __restrict__ qnsqp, const float* __restrict__ knsqp,
    const float* __restrict__ sw, float* __restrict__ attn,
    f16* __restrict__ sraw, float2* __restrict__ tstats) {
  const int bid0 = blockIdx.x;
  const int bid = (bid0 & 7) * 128 + (bid0 >> 3);  // XCD-contiguous chunks
  const int tn = bid & 15;
  const int tm = (bid >> 4) & 15;
  const int b = bid >> 8;
  const int brow = tm * 128, bcol = tn * 128;
  const int t = threadIdx.x;
  const int lane = t & 63;
  const int wid = t >> 6;
  const int wr = (wid >> 1) * 64, wc = (wid & 1) * 64;
  const int lr = lane & 15;
  const int lk = (lane >> 4) << 3;
  const int g4 = (lane >> 4) << 2;

  __shared__ f16 As[128 * 64];
  __shared__ f16 Bs[128 * 64];
  __shared__ float s_m[128][2];
  __shared__ float s_l[128][2];

  f32x4 acc[4][4] = {};

  const int srow = lane >> 3;
  const int scol = ((lane & 7) ^ srow) << 4;
  const char* aBase = (const char*)(qh + (size_t)(b * LQ + brow) * D);
  const char* bBase = (const char*)(kh + (size_t)(b * LK + bcol) * D);
  const int swz = (lr & 7) << 4;

  for (int k0 = 0; k0 < D; k0 += 64) {
#pragma unroll
    for (int i = 0; i < 4; ++i) {
      const int chunk = wid * 4 + i;
      const int row = chunk * 8 + srow;
      gload_lds16(aBase + (size_t)row * (D * 2) + k0 * 2 + scol,
                  (char*)As + chunk * 1024);
      gload_lds16(bBase + (size_t)row * (D * 2) + k0 * 2 + scol,
                  (char*)Bs + chunk * 1024);
    }
    __syncthreads();
    f16x8 af[2][4], bf[2][4];
#pragma unroll
    for (int h = 0; h < 2; ++h) {
      const int cb = h * 64 + lk * 2;
#pragma unroll
      for (int m = 0; m < 4; ++m)
        af[h][m] = *(const f16x8*)((const char*)As + (wr + m * 16 + lr) * 128 +
                                   (cb ^ swz));
#pragma unroll
      for (int n = 0; n < 4; ++n)
        bf[h][n] = *(const f16x8*)((const char*)Bs + (wc + n * 16 + lr) * 128 +
                                   (cb ^ swz));
    }
#pragma unroll
    for (int h = 0; h < 2; ++h)
#pragma unroll
      for (int m = 0; m < 4; ++m)
#pragma unroll
        for (int n = 0; n < 4; ++n)
          acc[m][n] = __builtin_amdgcn_mfma_f32_16x16x32_f16(bf[h][n], af[h][m],
                                                             acc[m][n], 0, 0, 0);
    __syncthreads();
  }

  const float s0 = sw[0], s1 = sw[1], s2 = sw[2];
  const float smx = fmaxf(s0, fmaxf(s1, s2));
  float w0 = __expf(s0 - smx), w1 = __expf(s1 - smx), w2 = __expf(s2 - smx);
  const float winv = 1.f / (w0 + w1 + w2);
  w0 *= winv; w1 *= winv; w2 *= winv;

  float qn2_[4], w1rq[4];
#pragma unroll
  for (int m = 0; m < 4; ++m) {
    const float4 qp = *reinterpret_cast<const float4*>(
        &qnsqp[(size_t)(b * LQ + brow + wr + m * 16 + lr) * 4]);
    const float v = (qp.x + qp.y) + (qp.z + qp.w);
    qn2_[m] = v;
    w1rq[m] = w1 * rsqrtf(fmaxf(v, 1e-16f));
  }
  float kn2[4][4], rk[4][4];
#pragma unroll
  for (int n = 0; n < 4; ++n) {
#pragma unroll
    for (int r = 0; r < 4; ++r) {
      const int col = bcol + wc + n * 16 + g4 + r;
      const float4 kp = *reinterpret_cast<const float4*>(
          &knsqp[(size_t)(b * LK + col) * 4]);
      const float v = (kp.x + kp.y) + (kp.z + kp.w);
      kn2[n][r] = v;
      rk[n][r] = rsqrtf(fmaxf(v, 1e-16f));
    }
  }

  // pass 1: scores into acc, per-row half-tile max -> LDS
#pragma unroll
  for (int m = 0; m < 4; ++m) {
    const int rl = wr + m * 16 + lr;
    const int row = brow + rl;
    float mx = -3.4e38f;
#pragma unroll
    for (int n = 0; n < 4; ++n) {
      float4 o;
#pragma unroll
      for (int r = 0; r < 4; ++r) {
        const float dot = acc[m][n][r];
        const float qk2 = qn2_[m] + kn2[n][r];
        const float st = sqrtf(fmaxf(qk2 - 2.f * dot, 0.f));
        const float c = fmaf(w1rq[m], rk[n][r], w0);
        const float s = fmaf(dot, c, -w2 * st);
        ((float*)&o)[r] = s;
        acc[m][n][r] = s;
        mx = fmaxf(mx, s);
      }
      if constexpr (!RAW16) {
        *reinterpret_cast<float4*>(attn + (size_t)(b * LQ + row) * LK + bcol +
                                   wc + n * 16 + g4) = o;
      }
    }
    mx = fmaxf(mx, __shfl_xor(mx, 16));
    mx = fmaxf(mx, __shfl_xor(mx, 32));
    if (lane < 16) s_m[rl][wid & 1] = mx;
  }
  __syncthreads();

  // pass 2: e = exp(s - M_tile) -> f16 store (RAW16) + expsum
#pragma unroll
  for (int m = 0; m < 4; ++m) {
    const int rl = wr + m * 16 + lr;
    const int row = brow + rl;
    const float Mt = fmaxf(s_m[rl][0], s_m[rl][1]);
    float es = 0.f;
#pragma unroll
    for (int n = 0; n < 4; ++n) {
      float e0 = __expf(acc[m][n][0] - Mt);
      float e1 = __expf(acc[m][n][1] - Mt);
      float e2 = __expf(acc[m][n][2] - Mt);
      float e3 = __expf(acc[m][n][3] - Mt);
      es += (e0 + e1) + (e2 + e3);
      if constexpr (RAW16) {
        f16x4 h4;
        h4[0] = (f16)e0; h4[1] = (f16)e1; h4[2] = (f16)e2; h4[3] = (f16)e3;
        *reinterpret_cast<f16x4*>(sraw + (size_t)(b * LQ + row) * LK + bcol +
                                  wc + n * 16 + g4) = h4;
      }
    }
    es += __shfl_xor(es, 16);
    es += __shfl_xor(es, 32);
    if (lane < 16) s_l[rl][wid & 1] = es;
  }
  __syncthreads();
  if (t < 128) {
    tstats[(size_t)(b * LQ + brow + t) * 16 + tn] =
        make_float2(fmaxf(s_m[t][0], s_m[t][1]), s_l[t][0] + s_l[t][1]);
  }
}

// ---------------------------------------------------------------------------
// normalize (fallback only, !useA16): combine tstats -> M, invL; f32 in-place.
// ---------------------------------------------------------------------------
__global__ __launch_bounds__(256) void normalize_kernel(
    float* __restrict__ attn, const float2* __restrict__ tstats) {
  const int row = blockIdx.x;
  const int t = threadIdx.x;
  __shared__ float sM, sI;
  if (t < 16) {
    float2 st = tstats[(size_t)row * 16 + t];
    float M = st.x;
    M = fmaxf(M, __shfl_xor(M, 8));
    M = fmaxf(M, __shfl_xor(M, 4));
    M = fmaxf(M, __shfl_xor(M, 2));
    M = fmaxf(M, __shfl_xor(M, 1));
    float l = st.y * __expf(st.x - M);
    l += __shfl_xor(l, 8);
    l += __shfl_xor(l, 4);
    l += __shfl_xor(l, 2);
    l += __shfl_xor(l, 1);
    if (t == 0) { sM = M; sI = 1.f / l; }
  }
  __syncthreads();
  const float M = sM, invL = sI;
  float* rp = attn + (size_t)row * LK + t * 8;
  float4 v0 = *reinterpret_cast<const float4*>(rp);
  float4 v1 = *reinterpret_cast<const float4*>(rp + 4);
  v0.x = __expf(v0.x - M) * invL; v0.y = __expf(v0.y - M) * invL;
  v0.z = __expf(v0.z - M) * invL; v0.w = __expf(v0.w - M) * invL;
  v1.x = __expf(v1.x - M) * invL; v1.y = __expf(v1.y - M) * invL;
  v1.z = __expf(v1.z - M) * invL; v1.w = __expf(v1.w - M) * invL;
  *reinterpret_cast<float4*>(rp) = v0;
  *reinterpret_cast<float4*>(rp + 4) = v1;
}

// ---------------------------------------------------------------------------
// pv: ctx = p @ v. 32x128 tile, BK=64, grid 1024 (4 blocks/CU, XCD-swizzled).
// NORM: prologue computes per-(row, tile) scale = exp(m_t - M)/L (sScale LDS);
// A-staging = prefetched e16 load * scale (pk_mul, NO exp) -> LDS; block tn
// also stores f32 normalized attn for its column-quarter (balanced).
// ---------------------------------------------------------------------------
template <bool NORM>
__global__ __launch_bounds__(256, 4) void pv_kernel(
    float* __restrict__ attnf, const f16* __restrict__ sraw,
    const f16* __restrict__ vt, const float2* __restrict__ tstats,
    float* __restrict__ ctx) {
  const int bid0 = blockIdx.x;
  const int bid = (bid0 & 7) * 128 + (bid0 >> 3);  // 1024 = 8 x 128
  const int tn = bid & 3;          // D/128
  const int tm = (bid >> 2) & 63;  // LQ/32
  const int b = bid >> 8;
  const int brow = tm * 32, bcol = tn * 128;
  const int t = threadIdx.x;
  const int lane = t & 63;
  const int wid = t >> 6;
  const int wr = (wid >> 1) * 16, wc = (wid & 1) * 64;
  const int lr = lane & 15;
  const int lk = (lane >> 4) << 3;
  const int g4 = (lane >> 4) << 2;

  __shared__ f16 As[32 * 64];   // 4 KB
  __shared__ f16 Bs[128 * 64];  // 16 KB
  __shared__ float sScale[32][17];  // per-(row, col-tile) combined scale

  f32x4 acc[4] = {};

  const int srow = lane >> 3;
  const int scol = ((lane & 7) ^ srow) << 4;
  const size_t arow0 = (size_t)(b * LQ + brow);
  const char* bBase = (const char*)(vt + (size_t)(b * D + bcol) * LK);
  const int swz = (lr & 7) << 4;

  // A staging geometry: one f16x8 per thread per K-step.
  const int arow = t >> 3;                   // 0..31
  const int c16 = (t & 7) << 4;              // dest byte col in As row
  const int csrc = c16 ^ ((arow & 7) << 4);  // swizzled source byte col
  const char* aRow =
      (const char*)sraw + (arow0 + arow) * (size_t)LK * 2 + csrc;

  if constexpr (NORM) {
    if (t < 128) {
      const int prow = t >> 2;  // 0..31
      const int j4 = (t & 3) * 4;
      const float4* tp =
          reinterpret_cast<const float4*>(&tstats[(arow0 + prow) * 16 + j4]);
      const float4 a = tp[0], c = tp[1];
      float m_ = fmaxf(fmaxf(a.x, a.z), fmaxf(c.x, c.z));
      m_ = fmaxf(m_, __shfl_xor(m_, 1));
      m_ = fmaxf(m_, __shfl_xor(m_, 2));
      float l_ = a.y * __expf(a.x - m_) + a.w * __expf(a.z - m_) +
                 c.y * __expf(c.x - m_) + c.w * __expf(c.z - m_);
      l_ += __shfl_xor(l_, 1);
      l_ += __shfl_xor(l_, 2);
      const float invL = 1.f / l_;
      sScale[prow][j4 + 0] = __expf(a.x - m_) * invL;
      sScale[prow][j4 + 1] = __expf(a.z - m_) * invL;
      sScale[prow][j4 + 2] = __expf(c.x - m_) * invL;
      sScale[prow][j4 + 3] = __expf(c.z - m_) * invL;
    }
    __syncthreads();
  }

  f16x8 hcur;
  if constexpr (NORM) hcur = *(const f16x8*)(aRow);

  for (int k0 = 0; k0 < LK; k0 += 64) {
    // B staging: async, issued first so its latency spans the A processing.
#pragma unroll
    for (int i = 0; i < 4; ++i) {
      const int chunk = wid * 4 + i;
      const int row = chunk * 8 + srow;
      gload_lds16(bBase + (size_t)row * (LK * 2) + k0 * 2 + scol,
                  (char*)Bs + chunk * 1024);
    }
    if constexpr (NORM) {
      // prefetch next K-step's e-values (rides the same vmcnt drain as B)
      f16x8 hnext;
      if (k0 + 64 < LK) hnext = *(const f16x8*)(aRow + (k0 + 64) * 2);
      const float sc = sScale[arow][k0 >> 7];
      const f16 sch = (f16)sc;
      const f16x8 scv = {sch, sch, sch, sch, sch, sch, sch, sch};
      const f16x8 hv = hcur * scv;  // p = e * scale  (v_pk_mul_f16, no exp)
      *(f16x8*)((char*)As + arow * 128 + c16) = hv;
      if ((k0 >> 9) == tn) {  // this block's column-quarter: f32 attn out
        float4 e0, e1;
        e0.x = (float)hv[0]; e0.y = (float)hv[1];
        e0.z = (float)hv[2]; e0.w = (float)hv[3];
        e1.x = (float)hv[4]; e1.y = (float)hv[5];
        e1.z = (float)hv[6]; e1.w = (float)hv[7];
        float* op = attnf + (arow0 + arow) * LK + k0 + (csrc >> 1);
        *reinterpret_cast<float4*>(op) = e0;
        *reinterpret_cast<float4*>(op + 4) = e1;
      }
      hcur = hnext;
    } else {
      const float4* ps = (const float4*)((const char*)attnf +
                                         ((arow0 + arow) * LK + k0) * 4 +
                                         csrc * 2);
      *(f16x8*)((char*)As + arow * 128 + c16) = cvt8(ps[0], ps[1]);
    }
    __syncthreads();
    f16x8 af[2], bf[2][4];
#pragma unroll
    for (int h = 0; h < 2; ++h) {
      const int cb = h * 64 + lk * 2;
      af[h] = *(const f16x8*)((const char*)As + (wr + lr) * 128 + (cb ^ swz));
#pragma unroll
      for (int n = 0; n < 4; ++n)
        bf[h][n] = *(const f16x8*)((const char*)Bs + (wc + n * 16 + lr) * 128 +
                                   (cb ^ swz));
    }
#pragma unroll
    for (int h = 0; h < 2; ++h)
#pragma unroll
      for (int n = 0; n < 4; ++n)
        acc[n] = __builtin_amdgcn_mfma_f32_16x16x32_f16(bf[h][n], af[h],
                                                        acc[n], 0, 0, 0);
    __syncthreads();
  }

  const int row = brow + wr + lr;
  float* rowp = ctx + (size_t)(b * LQ + row) * D + bcol + wc;
#pragma unroll
  for (int n = 0; n < 4; ++n) {
    float4 o;
    o.x = acc[n][0]; o.y = acc[n][1];
    o.z = acc[n][2]; o.w = acc[n][3];
    *reinterpret_cast<float4*>(rowp + n * 16 + g4) = o;
  }
}

}  // namespace

extern "C" void kernel_launch(void* const* d_in, const int* in_sizes, int n_in,
                              void* d_out, int out_size, void* d_ws,
                              size_t ws_size, hipStream_t stream) {
  const float* query = (const float*)d_in[0];
  const float* key = (const float*)d_in[1];
  const float* value = (const float*)d_in[2];
  const float* Wq = (const float*)d_in[3];
  const float* bq = (const float*)d_in[4];
  const float* Wk = (const float*)d_in[5];
  const float* bk = (const float*)d_in[6];
  const float* sw = (const float*)d_in[7];

  float* ctx = (float*)d_out;                            // [B,LQ,D]
  float* attn = (float*)d_out + (size_t)BATCH * LQ * D;  // [B,LQ,LK]

  char* ws = (char*)d_ws;
  f16* vt = (f16*)ws;                                    // 8 MiB
  f16* qh = (f16*)(ws + (size_t)(8u << 20));             // 8 MiB
  f16* kh = (f16*)(ws + (size_t)(16u << 20));            // 8 MiB
  float* qnsqp = (float*)(ws + (size_t)(24u << 20));     // 128 KiB
  float* knsqp = qnsqp + (size_t)MQ * 4;                 // 128 KiB
  float2* tstats = (float2*)(ws + (size_t)(25u << 20));  // 1 MiB
  f16* sraw = (f16*)(ws + (size_t)(26u << 20));          // 32 MiB
  const size_t ws_needed =
      ((size_t)(26u << 20)) + (size_t)BATCH * LQ * LK * sizeof(f16);
  const bool useA16 = ws_size >= ws_needed;

  prep_kernel<<<1536, 256, 0, stream>>>(query, key, value, Wq, Wk, bq, bk, qh,
                                        kh, qnsqp, knsqp, vt);
  if (useA16) {
    scores_kernel<true><<<1024, 256, 0, stream>>>(qh, kh, qnsqp, knsqp, sw,
                                                  attn, sraw, tstats);
    pv_kernel<true><<<1024, 256, 0, stream>>>(attn, sraw, vt, tstats, ctx);
  } else {
    scores_kernel<false><<<1024, 256, 0, stream>>>(qh, kh, qnsqp, knsqp, sw,
                                                   attn, sraw, tstats);
    normalize_kernel<<<MQ, 256, 0, stream>>>(attn, tstats);
    pv_kernel<false><<<1024, 256, 0, stream>>>(attn, sraw, vt, tstats, ctx);
  }
}

// Round 10
// 101.938 us; speedup vs baseline: 1.9042x; 1.0402x over previous
//
#include <hip/hip_runtime.h>
#include <cstdint>
#include <cstddef>

namespace {

constexpr int BATCH = 4;
constexpr int LQ = 2048;
constexpr int LK = 2048;
constexpr int D = 512;
constexpr int MQ = BATCH * LQ;

using f16 = _Float16;
typedef _Float16 f16x8 __attribute__((ext_vector_type(8)));
typedef _Float16 f16x4 __attribute__((ext_vector_type(4)));
typedef float f32x4 __attribute__((ext_vector_type(4)));

__device__ __forceinline__ f16x8 cvt8(const float4 a, const float4 b) {
  f16x8 h;
  h[0] = (f16)a.x; h[1] = (f16)a.y; h[2] = (f16)a.z; h[3] = (f16)a.w;
  h[4] = (f16)b.x; h[5] = (f16)b.y; h[6] = (f16)b.z; h[7] = (f16)b.w;
  return h;
}

typedef __attribute__((address_space(1))) const void gas_void;
typedef __attribute__((address_space(3))) void las_void;
__device__ __forceinline__ void gload_lds16(const void* g, void* l) {
  __builtin_amdgcn_global_load_lds((gas_void*)g, (las_void*)l, 16, 0, 0);
}

// ---------------------------------------------------------------------------
// prep: flat-grid fusion of {q-transform, k-transform, v-transpose}.
// ---------------------------------------------------------------------------
__global__ __launch_bounds__(256) void prep_kernel(
    const float* __restrict__ query, const float* __restrict__ keyp,
    const float* __restrict__ value, const float* __restrict__ Wq,
    const float* __restrict__ Wk, const float* __restrict__ bq,
    const float* __restrict__ bk, f16* __restrict__ qh, f16* __restrict__ kh,
    float* __restrict__ qnsqp, float* __restrict__ knsqp,
    f16* __restrict__ vt) {
  __shared__ __align__(16) char smem[21504];
  const int bid0 = blockIdx.x;
  const int t = threadIdx.x;

  if (bid0 >= 512) {
    // ---- v-transpose: 64x64 tile ----
    const int bid = bid0 - 512;
    const int kt = bid & 31;
    const int dt = (bid >> 5) & 7;
    const int b = bid >> 8;
    const int k0 = kt * 64, d0 = dt * 64;
    f16(*T)[72] = reinterpret_cast<f16(*)[72]>(smem);
#pragma unroll
    for (int i = 0; i < 4; ++i) {
      const int u = t + i * 256;
      const int k = u >> 4;
      const int d4 = (u & 15) << 2;
      float4 x = *reinterpret_cast<const float4*>(
          value + (size_t)(b * LK + k0 + k) * D + d0 + d4);
      T[d4 + 0][k] = (f16)x.x;
      T[d4 + 1][k] = (f16)x.y;
      T[d4 + 2][k] = (f16)x.z;
      T[d4 + 3][k] = (f16)x.w;
    }
    __syncthreads();
#pragma unroll
    for (int i = 0; i < 2; ++i) {
      const int u = t + i * 256;
      const int d = u >> 3;
      const int k8 = (u & 7) << 3;
      f16x8 h = *reinterpret_cast<const f16x8*>(&T[d][k8]);
      *reinterpret_cast<f16x8*>(vt + (size_t)(b * D + d0 + d) * LK + k0 + k8) =
          h;
    }
    return;
  }

  // ---- tanh-transform ----
  const int which = bid0 >> 8;
  const float* __restrict__ X = which ? keyp : query;
  const float* __restrict__ W = which ? Wk : Wq;
  const float* __restrict__ bias = which ? bk : bq;
  f16* __restrict__ out = which ? kh : qh;
  float* __restrict__ nsqp = which ? knsqp : qnsqp;

  const int bid = bid0 & 255;
  const int tm = bid & 63;
  const int tn = bid >> 6;
  const int brow = tm * 128, bcol = tn * 128;
  const int lane = t & 63;
  const int wid = t >> 6;
  const int wr = (wid >> 1) * 64, wc = (wid & 1) * 64;
  const int lr = lane & 15;
  const int lk = (lane >> 4) << 3;
  const int g4 = (lane >> 4) << 2;

  f16(*As)[40] = reinterpret_cast<f16(*)[40]>(smem);
  f16(*Bs)[40] = reinterpret_cast<f16(*)[40]>(smem + 10240);
  float(*s_ss)[2] = reinterpret_cast<float(*)[2]>(smem + 20480);

  f32x4 acc[4][4] = {};

  for (int k0 = 0; k0 < D; k0 += 32) {
#pragma unroll
    for (int i = 0; i < 2; ++i) {
      const int u = t + i * 256;
      const int r = u >> 2;
      const int c8 = (u & 3) << 3;
      const float4* pa =
          reinterpret_cast<const float4*>(X + (size_t)(brow + r) * D + k0 + c8);
      *reinterpret_cast<f16x8*>(&As[r][c8]) = cvt8(pa[0], pa[1]);
      const float4* pb =
          reinterpret_cast<const float4*>(W + (size_t)(bcol + r) * D + k0 + c8);
      *reinterpret_cast<f16x8*>(&Bs[r][c8]) = cvt8(pb[0], pb[1]);
    }
    __syncthreads();
    f16x8 af[4], bf[4];
#pragma unroll
    for (int m = 0; m < 4; ++m)
      af[m] = *reinterpret_cast<const f16x8*>(&As[wr + m * 16 + lr][lk]);
#pragma unroll
    for (int n = 0; n < 4; ++n)
      bf[n] = *reinterpret_cast<const f16x8*>(&Bs[wc + n * 16 + lr][lk]);
#pragma unroll
    for (int m = 0; m < 4; ++m)
#pragma unroll
      for (int n = 0; n < 4; ++n)
        acc[m][n] =
            __builtin_amdgcn_mfma_f32_16x16x32_f16(bf[n], af[m], acc[m][n], 0, 0, 0);
    __syncthreads();
  }

  float4 bv[4];
#pragma unroll
  for (int n = 0; n < 4; ++n)
    bv[n] = *reinterpret_cast<const float4*>(&bias[bcol + wc + n * 16 + g4]);

#pragma unroll
  for (int m = 0; m < 4; ++m) {
    const int row = brow + wr + m * 16 + lr;
    float ss = 0.f;
#pragma unroll
    for (int n = 0; n < 4; ++n) {
      float th[4];
#pragma unroll
      for (int r = 0; r < 4; ++r) {
        th[r] = tanhf(acc[m][n][r] + ((const float*)&bv[n])[r]);
        ss = fmaf(th[r], th[r], ss);
      }
      f16x4 h4;
      h4[0] = (f16)th[0]; h4[1] = (f16)th[1];
      h4[2] = (f16)th[2]; h4[3] = (f16)th[3];
      *reinterpret_cast<f16x4*>(out + (size_t)row * D + bcol + wc + n * 16 + g4) =
          h4;
    }
    ss += __shfl_xor(ss, 16);
    ss += __shfl_xor(ss, 32);
    if (lane < 16) s_ss[wr + m * 16 + lr][wid & 1] = ss;
  }
  __syncthreads();
  if (t < 128) nsqp[(size_t)(brow + t) * 4 + tn] = s_ss[t][0] + s_ss[t][1];
}

// ---------------------------------------------------------------------------
// scores: s = dot*(w0 + w1*rq*rk) - w2*sqrt(max(qn2+kn2-2dot,0))
// RAW16: store e = (f16)exp(s - M_tile) -> sraw; tstats = (M_tile, expsum).
// else:  store raw f32 s -> attn, tstats same.
// XCD-swizzled grid (1024 = 8 x 128).
// ---------------------------------------------------------------------------
template <bool RAW16>
__global__ __launch_bounds__(256, 4) void scores_kernel(
    const f16* __restrict__ qh, const f16* __restrict__ kh,
    const float* __restrict__ qnsqp, const float* __restrict__ knsqp,
    const float* __restrict__ sw, float* __restrict__ attn,
    f16* __restrict__ sraw, float2* __restrict__ tstats) {
  const int bid0 = blockIdx.x;
  const int bid = (bid0 & 7) * 128 + (bid0 >> 3);  // XCD-contiguous chunks
  const int tn = bid & 15;
  const int tm = (bid >> 4) & 15;
  const int b = bid >> 8;
  const int brow = tm * 128, bcol = tn * 128;
  const int t = threadIdx.x;
  const int lane = t & 63;
  const int wid = t >> 6;
  const int wr = (wid >> 1) * 64, wc = (wid & 1) * 64;
  const int lr = lane & 15;
  const int lk = (lane >> 4) << 3;
  const int g4 = (lane >> 4) << 2;

  __shared__ f16 As[128 * 64];
  __shared__ f16 Bs[128 * 64];
  __shared__ float s_m[128][2];
  __shared__ float s_l[128][2];

  f32x4 acc[4][4] = {};

  const int srow = lane >> 3;
  const int scol = ((lane & 7) ^ srow) << 4;
  const char* aBase = (const char*)(qh + (size_t)(b * LQ + brow) * D);
  const char* bBase = (const char*)(kh + (size_t)(b * LK + bcol) * D);
  const int swz = (lr & 7) << 4;

  for (int k0 = 0; k0 < D; k0 += 64) {
#pragma unroll
    for (int i = 0; i < 4; ++i) {
      const int chunk = wid * 4 + i;
      const int row = chunk * 8 + srow;
      gload_lds16(aBase + (size_t)row * (D * 2) + k0 * 2 + scol,
                  (char*)As + chunk * 1024);
      gload_lds16(bBase + (size_t)row * (D * 2) + k0 * 2 + scol,
                  (char*)Bs + chunk * 1024);
    }
    __syncthreads();
    f16x8 af[2][4], bf[2][4];
#pragma unroll
    for (int h = 0; h < 2; ++h) {
      const int cb = h * 64 + lk * 2;
#pragma unroll
      for (int m = 0; m < 4; ++m)
        af[h][m] = *(const f16x8*)((const char*)As + (wr + m * 16 + lr) * 128 +
                                   (cb ^ swz));
#pragma unroll
      for (int n = 0; n < 4; ++n)
        bf[h][n] = *(const f16x8*)((const char*)Bs + (wc + n * 16 + lr) * 128 +
                                   (cb ^ swz));
    }
#pragma unroll
    for (int h = 0; h < 2; ++h)
#pragma unroll
      for (int m = 0; m < 4; ++m)
#pragma unroll
        for (int n = 0; n < 4; ++n)
          acc[m][n] = __builtin_amdgcn_mfma_f32_16x16x32_f16(bf[h][n], af[h][m],
                                                             acc[m][n], 0, 0, 0);
    __syncthreads();
  }

  const float s0 = sw[0], s1 = sw[1], s2 = sw[2];
  const float smx = fmaxf(s0, fmaxf(s1, s2));
  float w0 = __expf(s0 - smx), w1 = __expf(s1 - smx), w2 = __expf(s2 - smx);
  const float winv = 1.f / (w0 + w1 + w2);
  w0 *= winv; w1 *= winv; w2 *= winv;

  float qn2_[4], w1rq[4];
#pragma unroll
  for (int m = 0; m < 4; ++m) {
    const float4 qp = *reinterpret_cast<const float4*>(
        &qnsqp[(size_t)(b * LQ + brow + wr + m * 16 + lr) * 4]);
    const float v = (qp.x + qp.y) + (qp.z + qp.w);
    qn2_[m] = v;
    w1rq[m] = w1 * rsqrtf(fmaxf(v, 1e-16f));
  }
  float kn2[4][4], rk[4][4];
#pragma unroll
  for (int n = 0; n < 4; ++n) {
#pragma unroll
    for (int r = 0; r < 4; ++r) {
      const int col = bcol + wc + n * 16 + g4 + r;
      const float4 kp = *reinterpret_cast<const float4*>(
          &knsqp[(size_t)(b * LK + col) * 4]);
      const float v = (kp.x + kp.y) + (kp.z + kp.w);
      kn2[n][r] = v;
      rk[n][r] = rsqrtf(fmaxf(v, 1e-16f));
    }
  }

  // pass 1: scores into acc, per-row half-tile max -> LDS
#pragma unroll
  for (int m = 0; m < 4; ++m) {
    const int rl = wr + m * 16 + lr;
    const int row = brow + rl;
    float mx = -3.4e38f;
#pragma unroll
    for (int n = 0; n < 4; ++n) {
      float4 o;
#pragma unroll
      for (int r = 0; r < 4; ++r) {
        const float dot = acc[m][n][r];
        const float qk2 = qn2_[m] + kn2[n][r];
        const float st = sqrtf(fmaxf(qk2 - 2.f * dot, 0.f));
        const float c = fmaf(w1rq[m], rk[n][r], w0);
        const float s = fmaf(dot, c, -w2 * st);
        ((float*)&o)[r] = s;
        acc[m][n][r] = s;
        mx = fmaxf(mx, s);
      }
      if constexpr (!RAW16) {
        *reinterpret_cast<float4*>(attn + (size_t)(b * LQ + row) * LK + bcol +
                                   wc + n * 16 + g4) = o;
      }
    }
    mx = fmaxf(mx, __shfl_xor(mx, 16));
    mx = fmaxf(mx, __shfl_xor(mx, 32));
    if (lane < 16) s_m[rl][wid & 1] = mx;
  }
  __syncthreads();

  // pass 2: e = exp(s - M_tile) -> f16 store (RAW16) + expsum
#pragma unroll
  for (int m = 0; m < 4; ++m) {
    const int rl = wr + m * 16 + lr;
    const int row = brow + rl;
    const float Mt = fmaxf(s_m[rl][0], s_m[rl][1]);
    float es = 0.f;
#pragma unroll
    for (int n = 0; n < 4; ++n) {
      float e0 = __expf(acc[m][n][0] - Mt);
      float e1 = __expf(acc[m][n][1] - Mt);
      float e2 = __expf(acc[m][n][2] - Mt);
      float e3 = __expf(acc[m][n][3] - Mt);
      es += (e0 + e1) + (e2 + e3);
      if constexpr (RAW16) {
        f16x4 h4;
        h4[0] = (f16)e0; h4[1] = (f16)e1; h4[2] = (f16)e2; h4[3] = (f16)e3;
        *reinterpret_cast<f16x4*>(sraw + (size_t)(b * LQ + row) * LK + bcol +
                                  wc + n * 16 + g4) = h4;
      }
    }
    es += __shfl_xor(es, 16);
    es += __shfl_xor(es, 32);
    if (lane < 16) s_l[rl][wid & 1] = es;
  }
  __syncthreads();
  if (t < 128) {
    tstats[(size_t)(b * LQ + brow + t) * 16 + tn] =
        make_float2(fmaxf(s_m[t][0], s_m[t][1]), s_l[t][0] + s_l[t][1]);
  }
}

// ---------------------------------------------------------------------------
// normalize (fallback only, !useA16): combine tstats -> M, invL; f32 in-place.
// ---------------------------------------------------------------------------
__global__ __launch_bounds__(256) void normalize_kernel(
    float* __restrict__ attn, const float2* __restrict__ tstats) {
  const int row = blockIdx.x;
  const int t = threadIdx.x;
  __shared__ float sM, sI;
  if (t < 16) {
    float2 st = tstats[(size_t)row * 16 + t];
    float M = st.x;
    M = fmaxf(M, __shfl_xor(M, 8));
    M = fmaxf(M, __shfl_xor(M, 4));
    M = fmaxf(M, __shfl_xor(M, 2));
    M = fmaxf(M, __shfl_xor(M, 1));
    float l = st.y * __expf(st.x - M);
    l += __shfl_xor(l, 8);
    l += __shfl_xor(l, 4);
    l += __shfl_xor(l, 2);
    l += __shfl_xor(l, 1);
    if (t == 0) { sM = M; sI = 1.f / l; }
  }
  __syncthreads();
  const float M = sM, invL = sI;
  float* rp = attn + (size_t)row * LK + t * 8;
  float4 v0 = *reinterpret_cast<const float4*>(rp);
  float4 v1 = *reinterpret_cast<const float4*>(rp + 4);
  v0.x = __expf(v0.x - M) * invL; v0.y = __expf(v0.y - M) * invL;
  v0.z = __expf(v0.z - M) * invL; v0.w = __expf(v0.w - M) * invL;
  v1.x = __expf(v1.x - M) * invL; v1.y = __expf(v1.y - M) * invL;
  v1.z = __expf(v1.z - M) * invL; v1.w = __expf(v1.w - M) * invL;
  *reinterpret_cast<float4*>(rp) = v0;
  *reinterpret_cast<float4*>(rp + 4) = v1;
}

// ---------------------------------------------------------------------------
// pv: ctx = p @ v. 64x128 tile, BK=64, 512 threads (8 waves), grid 512
// (2 blocks/CU = 16 waves/CU, XCD-swizzled). B-staging traffic depends only
// on BM -> BM=64 halves it vs BM=32.
// NORM: prologue computes per-(row, tile) scale = exp(m_t - M)/L (sScale);
// A-staging = prefetched e16 load * scale (pk_mul) -> LDS; block tn also
// stores f32 normalized attn for its column-quarter (balanced).
// ---------------------------------------------------------------------------
template <bool NORM>
__global__ __launch_bounds__(512, 4) void pv_kernel(
    float* __restrict__ attnf, const f16* __restrict__ sraw,
    const f16* __restrict__ vt, const float2* __restrict__ tstats,
    float* __restrict__ ctx) {
  const int bid0 = blockIdx.x;
  const int bid = (bid0 & 7) * 64 + (bid0 >> 3);  // 512 = 8 x 64
  const int tn = bid & 3;          // D/128
  const int tm = (bid >> 2) & 31;  // LQ/64
  const int b = bid >> 7;
  const int brow = tm * 64, bcol = tn * 128;
  const int t = threadIdx.x;
  const int lane = t & 63;
  const int wid = t >> 6;                       // 0..7
  const int wr = (wid >> 1) * 16, wc = (wid & 1) * 64;
  const int lr = lane & 15;
  const int lk = (lane >> 4) << 3;
  const int g4 = (lane >> 4) << 2;

  __shared__ f16 As[64 * 64];       // 8 KB
  __shared__ f16 Bs[128 * 64];      // 16 KB
  __shared__ float sScale[64][17];  // per-(row, col-tile) combined scale

  f32x4 acc[4] = {};

  const int srow = lane >> 3;
  const int scol = ((lane & 7) ^ srow) << 4;
  const size_t arow0 = (size_t)(b * LQ + brow);
  const char* bBase = (const char*)(vt + (size_t)(b * D + bcol) * LK);
  const int swz = (lr & 7) << 4;

  // A staging geometry: one f16x8 per thread per K-step (64 rows x 64 cols).
  const int arow = t >> 3;                   // 0..63
  const int c16 = (t & 7) << 4;              // dest byte col in As row
  const int csrc = c16 ^ ((arow & 7) << 4);  // swizzled source byte col
  const char* aRow =
      (const char*)sraw + (arow0 + arow) * (size_t)LK * 2 + csrc;

  if constexpr (NORM) {
    if (t < 256) {
      const int prow = t >> 2;  // 0..63
      const int j4 = (t & 3) * 4;
      const float4* tp =
          reinterpret_cast<const float4*>(&tstats[(arow0 + prow) * 16 + j4]);
      const float4 a = tp[0], c = tp[1];
      float m_ = fmaxf(fmaxf(a.x, a.z), fmaxf(c.x, c.z));
      m_ = fmaxf(m_, __shfl_xor(m_, 1));
      m_ = fmaxf(m_, __shfl_xor(m_, 2));
      float l_ = a.y * __expf(a.x - m_) + a.w * __expf(a.z - m_) +
                 c.y * __expf(c.x - m_) + c.w * __expf(c.z - m_);
      l_ += __shfl_xor(l_, 1);
      l_ += __shfl_xor(l_, 2);
      const float invL = 1.f / l_;
      sScale[prow][j4 + 0] = __expf(a.x - m_) * invL;
      sScale[prow][j4 + 1] = __expf(a.z - m_) * invL;
      sScale[prow][j4 + 2] = __expf(c.x - m_) * invL;
      sScale[prow][j4 + 3] = __expf(c.z - m_) * invL;
    }
    __syncthreads();
  }

  f16x8 hcur;
  if constexpr (NORM) hcur = *(const f16x8*)(aRow);

  for (int k0 = 0; k0 < LK; k0 += 64) {
    // B staging: async, issued first so its latency spans the A processing.
#pragma unroll
    for (int i = 0; i < 2; ++i) {
      const int chunk = wid * 2 + i;  // 16 chunks of 8 rows
      const int row = chunk * 8 + srow;
      gload_lds16(bBase + (size_t)row * (LK * 2) + k0 * 2 + scol,
                  (char*)Bs + chunk * 1024);
    }
    if constexpr (NORM) {
      // prefetch next K-step's e-values (rides the same vmcnt drain as B)
      f16x8 hnext;
      if (k0 + 64 < LK) hnext = *(const f16x8*)(aRow + (k0 + 64) * 2);
      const float sc = sScale[arow][k0 >> 7];
      const f16 sch = (f16)sc;
      const f16x8 scv = {sch, sch, sch, sch, sch, sch, sch, sch};
      const f16x8 hv = hcur * scv;  // p = e * scale  (v_pk_mul_f16, no exp)
      *(f16x8*)((char*)As + arow * 128 + c16) = hv;
      if ((k0 >> 9) == tn) {  // this block's column-quarter: f32 attn out
        float4 e0, e1;
        e0.x = (float)hv[0]; e0.y = (float)hv[1];
        e0.z = (float)hv[2]; e0.w = (float)hv[3];
        e1.x = (float)hv[4]; e1.y = (float)hv[5];
        e1.z = (float)hv[6]; e1.w = (float)hv[7];
        float* op = attnf + (arow0 + arow) * LK + k0 + (csrc >> 1);
        *reinterpret_cast<float4*>(op) = e0;
        *reinterpret_cast<float4*>(op + 4) = e1;
      }
      hcur = hnext;
    } else {
      const float4* ps = (const float4*)((const char*)attnf +
                                         ((arow0 + arow) * LK + k0) * 4 +
                                         csrc * 2);
      *(f16x8*)((char*)As + arow * 128 + c16) = cvt8(ps[0], ps[1]);
    }
    __syncthreads();
    f16x8 af[2], bf[2][4];
#pragma unroll
    for (int h = 0; h < 2; ++h) {
      const int cb = h * 64 + lk * 2;
      af[h] = *(const f16x8*)((const char*)As + (wr + lr) * 128 + (cb ^ swz));
#pragma unroll
      for (int n = 0; n < 4; ++n)
        bf[h][n] = *(const f16x8*)((const char*)Bs + (wc + n * 16 + lr) * 128 +
                                   (cb ^ swz));
    }
#pragma unroll
    for (int h = 0; h < 2; ++h)
#pragma unroll
      for (int n = 0; n < 4; ++n)
        acc[n] = __builtin_amdgcn_mfma_f32_16x16x32_f16(bf[h][n], af[h],
                                                        acc[n], 0, 0, 0);
    __syncthreads();
  }

  const int row = brow + wr + lr;
  float* rowp = ctx + (size_t)(b * LQ + row) * D + bcol + wc;
#pragma unroll
  for (int n = 0; n < 4; ++n) {
    float4 o;
    o.x = acc[n][0]; o.y = acc[n][1];
    o.z = acc[n][2]; o.w = acc[n][3];
    *reinterpret_cast<float4*>(rowp + n * 16 + g4) = o;
  }
}

}  // namespace

extern "C" void kernel_launch(void* const* d_in, const int* in_sizes, int n_in,
                              void* d_out, int out_size, void* d_ws,
                              size_t ws_size, hipStream_t stream) {
  const float* query = (const float*)d_in[0];
  const float* key = (const float*)d_in[1];
  const float* value = (const float*)d_in[2];
  const float* Wq = (const float*)d_in[3];
  const float* bq = (const float*)d_in[4];
  const float* Wk = (const float*)d_in[5];
  const float* bk = (const float*)d_in[6];
  const float* sw = (const float*)d_in[7];

  float* ctx = (float*)d_out;                            // [B,LQ,D]
  float* attn = (float*)d_out + (size_t)BATCH * LQ * D;  // [B,LQ,LK]

  char* ws = (char*)d_ws;
  f16* vt = (f16*)ws;                                    // 8 MiB
  f16* qh = (f16*)(ws + (size_t)(8u << 20));             // 8 MiB
  f16* kh = (f16*)(ws + (size_t)(16u << 20));            // 8 MiB
  float* qnsqp = (float*)(ws + (size_t)(24u << 20));     // 128 KiB
  float* knsqp = qnsqp + (size_t)MQ * 4;                 // 128 KiB
  float2* tstats = (float2*)(ws + (size_t)(25u << 20));  // 1 MiB
  f16* sraw = (f16*)(ws + (size_t)(26u << 20));          // 32 MiB
  const size_t ws_needed =
      ((size_t)(26u << 20)) + (size_t)BATCH * LQ * LK * sizeof(f16);
  const bool useA16 = ws_size >= ws_needed;

  prep_kernel<<<1536, 256, 0, stream>>>(query, key, value, Wq, Wk, bq, bk, qh,
                                        kh, qnsqp, knsqp, vt);
  if (useA16) {
    scores_kernel<true><<<1024, 256, 0, stream>>>(qh, kh, qnsqp, knsqp, sw,
                                                  attn, sraw, tstats);
    pv_kernel<true><<<512, 512, 0, stream>>>(attn, sraw, vt, tstats, ctx);
  } else {
    scores_kernel<false><<<1024, 256, 0, stream>>>(qh, kh, qnsqp, knsqp, sw,
                                                   attn, sraw, tstats);
    normalize_kernel<<<MQ, 256, 0, stream>>>(attn, tstats);
    pv_kernel<false><<<512, 512, 0, stream>>>(attn, sraw, vt, tstats, ctx);
  }
}